// Round 15
// baseline (1064.444 us; speedup 1.0000x reference)
//
#include <hip/hip_runtime.h>
#include <hip/hip_bf16.h>

typedef _Float16 hf;
typedef short    s8v  __attribute__((ext_vector_type(8)));
typedef _Float16 h8v  __attribute__((ext_vector_type(8)));
typedef float    f32x4 __attribute__((ext_vector_type(4)));

#define DEVINL __device__ __forceinline__

DEVINL unsigned short f2h_bits(float f) { return __builtin_bit_cast(unsigned short, (hf)f); }
DEVINL float h2f_bits(unsigned short u) { return (float)__builtin_bit_cast(hf, u); }

// ---------------------------------------------------------------- arena
static constexpr size_t OFF_SA    = 0;           // f1 packed  [2][4096][32] hf
static constexpr size_t OFF_F2S   = 524288;      // f2 sampled [162][4096][32] hf
static constexpr size_t OFF_E1    = 42991616;    // e1out [162][4096][48]
static constexpr size_t OFF_E2    = 106692608;   // e2out [162][4096][64]
static constexpr size_t OFF_E3    = 42991616;    // e3out [162][4096][32] (reuse E1)
static constexpr size_t OFF_X1    = 85458944;    // x1 [162][4096][96]
static constexpr size_t OFF_X2    = 524288;      // x2 [162][1024][128]
static constexpr size_t OFF_X3    = 85458944;    // x3 [162][1024][128]
static constexpr size_t OFF_X4    = 524288;      // x4 [162][1024][64]
static constexpr size_t OFF_XD    = 127926272;   // xd [162][4096][32]
static constexpr size_t OFF_SCORE = 524288;      // f32 [2][81][4096]
static constexpr size_t OFF_STATS = 212860928;   // f32 2560
static constexpr size_t OFF_WC1   = 212871168;
static constexpr size_t OFF_WC2   = 212981760;
static constexpr size_t OFF_WC3   = 213202944;
static constexpr size_t OFF_WC4   = 213497856;
static constexpr size_t OFF_WDC   = 213645312;
static constexpr size_t OFF_WE1   = 213720064;
static constexpr size_t OFF_WE2   = 213726208;
static constexpr size_t OFF_WE3   = 213734400;
static constexpr size_t OFF_DT1   = 213738496;
static constexpr size_t OFF_DTE   = 213745408;
static constexpr size_t OFF_F2CLF = 213746048;   // f2 packed [2][4096][32] f32 (1 MB)

// ---------------------------------------------------------------- prepack
__global__ void prepack(const float* __restrict__ src, hf* __restrict__ dst,
                        int COr, int COP, int CINr, int CINsrc, int KP, int TAPS) {
  const int idx = blockIdx.x * 256 + threadIdx.x;
  const int total = TAPS * COP * KP;
  if (idx >= total) return;
  const int k = idx % KP;
  const int r = idx / KP;
  const int co = r % COP;
  const int t = r / COP;
  float v = 0.f;
  if (co < COr && k < CINr) v = src[((size_t)co * CINsrc + k) * TAPS + t];
  dst[idx] = (hf)v;
}

// dense layout: dst[t][ks][co][32] ; src = w[(co*CIN + ks*32 + kk)*9 + t]
__global__ void prepack2(const float* __restrict__ src, hf* __restrict__ dst,
                         int COP, int CIN, int NCHn) {
  const int idx = blockIdx.x * 256 + threadIdx.x;
  const int total = 9 * NCHn * COP * 32;
  if (idx >= total) return;
  const int kk = idx & 31;
  const int r = idx >> 5;
  const int co = r % COP;
  const int r2 = r / COP;
  const int ks = r2 % NCHn;
  const int t = r2 / NCHn;
  dst[idx] = (hf)src[((size_t)co * CIN + ks * 32 + kk) * 9 + t];
}

__global__ void dtab1_kernel(const float* __restrict__ w1, float* __restrict__ dtab) {
  const int idx = blockIdx.x * 256 + threadIdx.x;  // 96*9*2
  if (idx >= 96 * 9 * 2) return;
  const int c = idx & 1;
  const int r = idx >> 1;
  const int pat = r % 9;
  const int co = r / 9;
  const int rc = pat / 3, cc = pat % 3;
  const int kh0 = (rc == 0) ? 1 : 0, kh1 = (rc == 2) ? 1 : 2;
  const int kw0 = (cc == 0) ? 1 : 0, kw1 = (cc == 2) ? 1 : 2;
  float s = 0.f;
  for (int kh = kh0; kh <= kh1; ++kh)
    for (int kw = kw0; kw <= kw1; ++kw)
      s += w1[((size_t)(co * 66 + 64 + c) * 3 + kh) * 3 + kw];
  dtab[(co * 9 + pat) * 2 + c] = s;
}

__global__ void dtabE_kernel(const float* __restrict__ e1w, float* __restrict__ dtE) {
  const int co = threadIdx.x;
  if (co < 48) {
    dtE[co * 2 + 0] = e1w[co * 66 + 64];
    dtE[co * 2 + 1] = e1w[co * 66 + 65];
  }
}

// ---------------------------------------------------------------- input builders
__global__ __launch_bounds__(256) void packf1(const float* __restrict__ f1, hf* __restrict__ sA) {
  const int gid = blockIdx.x * 256 + threadIdx.x;  // 2*4096
  const int b = gid >> 12, pix = gid & 4095;
  unsigned words[16];
#pragma unroll
  for (int c = 0; c < 32; c += 2) {
    const float v0 = f1[((size_t)(b * 32 + c)) * 4096 + pix];
    const float v1 = f1[((size_t)(b * 32 + c + 1)) * 4096 + pix];
    words[c >> 1] = (unsigned)f2h_bits(v0) | ((unsigned)f2h_bits(v1) << 16);
  }
  uint4* dst = (uint4*)(sA + (size_t)gid * 32);
#pragma unroll
  for (int i = 0; i < 4; ++i)
    dst[i] = make_uint4(words[4 * i], words[4 * i + 1], words[4 * i + 2], words[4 * i + 3]);
}

__global__ __launch_bounds__(256) void packf2f32(const float* __restrict__ f2,
                                                 float* __restrict__ dst) {
  const int gid = blockIdx.x * 256 + threadIdx.x;  // 2*4096
  const int b = gid >> 12, pix = gid & 4095;
  float* op = dst + (size_t)gid * 32;
#pragma unroll
  for (int c = 0; c < 32; c += 4) {
    float4 v;
    v.x = f2[((size_t)(b * 32 + c + 0)) * 4096 + pix];
    v.y = f2[((size_t)(b * 32 + c + 1)) * 4096 + pix];
    v.z = f2[((size_t)(b * 32 + c + 2)) * 4096 + pix];
    v.w = f2[((size_t)(b * 32 + c + 3)) * 4096 + pix];
    *(float4*)(op + c) = v;
  }
}

__global__ __launch_bounds__(256) void sample2(const float* __restrict__ f2clf,
                                               const float* __restrict__ coords,
                                               hf* __restrict__ f2s) {
  const int gid = blockIdx.x * 256 + threadIdx.x;  // 162*4096
  const int n = gid >> 12, pix = gid & 4095;
  const int b = n / 81, ij = n - b * 81;
  const float di = (float)(ij / 9) - 4.f, dj = (float)(ij % 9) - 4.f;
  const float x = coords[((size_t)(b * 2 + 0)) * 4096 + pix] + di;
  const float y = coords[((size_t)(b * 2 + 1)) * 4096 + pix] + dj;
  const float x0f = floorf(x), y0f = floorf(y);
  const int x0 = (int)x0f, y0 = (int)y0f;
  const float wx1 = x - x0f, wx0 = 1.f - wx1;
  const float wy1 = y - y0f, wy0 = 1.f - wy1;
  const bool vx0 = (unsigned)x0 < 64u, vx1 = (unsigned)(x0 + 1) < 64u;
  const bool vy0 = (unsigned)y0 < 64u, vy1 = (unsigned)(y0 + 1) < 64u;
  const int x0c = min(max(x0, 0), 63), x1c = min(max(x0 + 1, 0), 63);
  const int y0c = min(max(y0, 0), 63), y1c = min(max(y0 + 1, 0), 63);
  const float w00 = (vy0 && vx0) ? wy0 * wx0 : 0.f;
  const float w01 = (vy0 && vx1) ? wy0 * wx1 : 0.f;
  const float w10 = (vy1 && vx0) ? wy1 * wx0 : 0.f;
  const float w11 = (vy1 && vx1) ? wy1 * wx1 : 0.f;
  const float* fb = f2clf + (size_t)b * 4096 * 32;
  const float* p00 = fb + (size_t)(y0c * 64 + x0c) * 32;
  const float* p01 = fb + (size_t)(y0c * 64 + x1c) * 32;
  const float* p10 = fb + (size_t)(y1c * 64 + x0c) * 32;
  const float* p11 = fb + (size_t)(y1c * 64 + x1c) * 32;
  unsigned words[16];
#pragma unroll
  for (int ch = 0; ch < 16; ++ch) {
    const float2 a  = *(const float2*)(p00 + ch * 2);
    const float2 bb = *(const float2*)(p01 + ch * 2);
    const float2 c  = *(const float2*)(p10 + ch * 2);
    const float2 d  = *(const float2*)(p11 + ch * 2);
    const float v0 = w00 * a.x + w01 * bb.x + w10 * c.x + w11 * d.x;
    const float v1 = w00 * a.y + w01 * bb.y + w10 * c.y + w11 * d.y;
    words[ch] = (unsigned)f2h_bits(v0) | ((unsigned)f2h_bits(v1) << 16);
  }
  uint4* dst = (uint4*)(f2s + (size_t)gid * 32);
#pragma unroll
  for (int i = 0; i < 4; ++i)
    dst[i] = make_uint4(words[4 * i], words[4 * i + 1], words[4 * i + 2], words[4 * i + 3]);
}

// ---------------------------------------------------------------- MFMA conv template (round-11 path)
// GEOM: 0 = 3x3 s1 | 1 = 3x3 s2 (64->32) | 2 = deconv parity | 3 = 1x1 (DIRECT, no LDS)
// EPI : 0 = raw store + BN stats | 1 = bias+relu | 2 = bias
template <int GEOM, int EPI, bool DUAL, int G, int KP, int COP, int COB, int MFR,
          int IMGO, int IMGI, int PIXROWS, int WPIX, bool DELTA>
__global__ __launch_bounds__(256) void mconv(
    const hf* __restrict__ src1, const hf* __restrict__ src0,
    const hf* __restrict__ wp, const float* __restrict__ bias,
    const float* __restrict__ dtab, float* __restrict__ statL,
    hf* __restrict__ outB, float* __restrict__ outF) {
  constexpr bool DIRECT = (GEOM == 3);
  constexpr int TAPS  = (GEOM == 2) ? 4 : (GEOM == 3) ? 1 : 9;
  constexpr int TR    = (GEOM == 1) ? (2 * PIXROWS + 1) : (GEOM == 3) ? 1 : (PIXROWS + 2);
  constexpr int TC    = (GEOM == 1) ? 65 : (GEOM == 3) ? 1 : (IMGI + 2);
  constexpr int NSLOT = TR * TC;
  constexpr int PSTR  = NSLOT + 1;
  constexpr int NCH   = KP / 32;
  constexpr int NPIXI = IMGI * IMGI;
  constexpr int NPIXO = (GEOM == 2) ? 4096 : IMGO * IMGO;
  constexpr int NCHUNK = NSLOT * 4;
  constexpr int CPT   = (NCHUNK + 255) / 256;
  constexpr int LDSE  = DIRECT ? 64 : 4 * PSTR * 8;

  __shared__ __align__(16) hf lds[LDSE];

  const int tid = threadIdx.x;
  const int wid = tid >> 6, lane = tid & 63, lg = lane >> 4, ln = lane & 15;
  const int n = blockIdx.z, b = n / 81, ij = n - b * 81;
  const int r0 = blockIdx.x * PIXROWS;
  const int qq = (GEOM == 2) ? (int)(blockIdx.y >> 1) : 0;
  const int pp = (GEOM == 2) ? (int)(blockIdx.y & 1) : 0;
  const int co0 = (GEOM == 2) ? 0 : (int)blockIdx.y * (MFR * 16);

  f32x4 acc[MFR][WPIX];
#pragma unroll
  for (int mf = 0; mf < MFR; ++mf)
#pragma unroll
    for (int pf = 0; pf < WPIX; ++pf) acc[mf][pf] = (f32x4){0.f, 0.f, 0.f, 0.f};

  if constexpr (DIRECT) {
#pragma unroll
    for (int ch = 0; ch < NCH; ++ch) {
      const int k0 = ch * 32;
      h8v afr[MFR];
#pragma unroll
      for (int mf = 0; mf < MFR; ++mf)
        afr[mf] = *(const h8v*)(wp + ((size_t)(co0 + mf * 16 + ln)) * KP + k0 + lg * 8);
#pragma unroll
      for (int pf = 0; pf < WPIX; ++pf) {
        const int pix = r0 * IMGO + wid * (WPIX * 16) + pf * 16 + ln;
        h8v bfr = (h8v){0, 0, 0, 0, 0, 0, 0, 0};
        if (DUAL) {
          bfr = (ch == 0)
              ? *(const h8v*)(src0 + (((size_t)b * NPIXI + pix) * 32 + lg * 8))
              : *(const h8v*)(src1 + (((size_t)n * NPIXI + pix) * 32 + lg * 8));
        } else {
          const int gci = k0 + lg * 8;
          if (gci < G)
            bfr = *(const h8v*)(src1 + (((size_t)n * NPIXI + pix) * G + gci));
        }
#pragma unroll
        for (int mf = 0; mf < MFR; ++mf)
          acc[mf][pf] = __builtin_amdgcn_mfma_f32_16x16x32_f16(afr[mf], bfr, acc[mf][pf], 0, 0, 0);
      }
    }
  } else {
    s8v rbuf[CPT];
    auto stage_load = [&](int k0) {
#pragma unroll
      for (int j = 0; j < CPT; ++j) {
        const int cidx = tid + j * 256;
        s8v v = (s8v){0, 0, 0, 0, 0, 0, 0, 0};
        if (cidx < NCHUNK) {
          const int s = cidx >> 2, p = cidx & 3;
          const int rs = s / TC, cs = s - rs * TC;
          int ir, ic;
          if (GEOM == 1) { ir = 2 * r0 - 1 + rs; ic = (cs < 32) ? 2 * cs : 2 * (cs - 32) - 1; }
          else           { ir = r0 - 1 + rs;     ic = cs - 1; }
          const int gci = k0 + p * 8;
          if (((unsigned)ir < (unsigned)IMGI) && ((unsigned)ic < (unsigned)IMGI)) {
            const int ipix = ir * IMGI + ic;
            if (DUAL) {
              if (gci < 32)
                v = *(const s8v*)(src0 + (((size_t)b * NPIXI + ipix) * 32 + gci));
              else
                v = *(const s8v*)(src1 + (((size_t)n * NPIXI + ipix) * 32 + (gci - 32)));
            } else if (gci < G) {
              v = *(const s8v*)(src1 + (((size_t)n * NPIXI + ipix) * G + gci));
            }
          }
        }
        rbuf[j] = v;
      }
    };
    auto stage_write = [&]() {
#pragma unroll
      for (int j = 0; j < CPT; ++j) {
        const int cidx = tid + j * 256;
        if (cidx < NCHUNK) {
          const int s = cidx >> 2, p = cidx & 3;
          *(s8v*)(&lds[(size_t)(p * PSTR + s) * 8]) = rbuf[j];
        }
      }
    };

    stage_load(0);
#pragma unroll
    for (int ch = 0; ch < NCH; ++ch) {
      if (ch > 0) __syncthreads();
      stage_write();
      __syncthreads();
      if (ch + 1 < NCH) stage_load((ch + 1) * 32);
      const int k0 = ch * 32;
#pragma unroll
      for (int t = 0; t < TAPS; ++t) {
        int dh, dw, wt, kh = 0, kw = 0;
        if (GEOM == 2) {
          dh = qq + (t >> 1) - 1; dw = pp + (t & 1) - 1;
          wt = (qq + 2 * (t >> 1)) * 4 + (pp + 2 * (t & 1));
        } else { kh = t / 3; kw = t % 3; dh = kh - 1; dw = kw - 1; wt = t; }
        h8v afr[MFR];
#pragma unroll
        for (int mf = 0; mf < MFR; ++mf)
          afr[mf] = *(const h8v*)(wp + ((size_t)(wt * COP + co0 + mf * 16 + ln)) * KP + k0 + lg * 8);
#pragma unroll
        for (int pf = 0; pf < WPIX; ++pf) {
          const int pl = wid * (WPIX * 16) + pf * 16 + ln;
          const int rL = pl / IMGO, c = pl - rL * IMGO;
          int slot;
          if (GEOM == 1) slot = (2 * rL + kh) * 65 + ((kw == 1) ? c : (32 + c + (kw >> 1)));
          else           slot = (rL + dh + 1) * TC + (c + dw + 1);
          const h8v bfr = *(const h8v*)(&lds[(size_t)(lg * PSTR + slot) * 8]);
#pragma unroll
          for (int mf = 0; mf < MFR; ++mf)
            acc[mf][pf] = __builtin_amdgcn_mfma_f32_16x16x32_f16(afr[mf], bfr, acc[mf][pf], 0, 0, 0);
        }
      }
    }
  }

  const float di = (float)(ij / 9) - 4.f, dj = (float)(ij % 9) - 4.f;

  {
#pragma unroll
    for (int mf = 0; mf < MFR; ++mf) {
#pragma unroll
      for (int pf = 0; pf < WPIX; ++pf) {
        const int pl = wid * (WPIX * 16) + pf * 16 + ln;
        const int rL = pl / IMGO, c = pl - rL * IMGO;
        int opix;
        if constexpr (GEOM == 2) opix = (2 * (r0 + rL) + qq) * 64 + 2 * c + pp;
        else opix = (r0 + rL) * IMGO + c;
        if constexpr (DELTA && EPI == 0) {
          const int oh = r0 + rL;
          const int rc = (oh == 0) ? 0 : ((oh == IMGO - 1) ? 2 : 1);
          const int cc = (c == 0) ? 0 : ((c == IMGO - 1) ? 2 : 1);
#pragma unroll
          for (int rg = 0; rg < 4; ++rg) {
            const int co = co0 + mf * 16 + lg * 4 + rg;
            acc[mf][pf][rg] += di * dtab[(co * 9 + rc * 3 + cc) * 2 + 0] +
                               dj * dtab[(co * 9 + rc * 3 + cc) * 2 + 1];
          }
        }
        if constexpr (DELTA && EPI == 1) {
#pragma unroll
          for (int rg = 0; rg < 4; ++rg) {
            const int co = co0 + mf * 16 + lg * 4 + rg;
            acc[mf][pf][rg] += di * dtab[co * 2] + dj * dtab[co * 2 + 1];
          }
        }
        if constexpr (EPI == 1 || EPI == 2) {
          const float4 bv = *(const float4*)(bias + co0 + mf * 16 + lg * 4);
          acc[mf][pf][0] += bv.x; acc[mf][pf][1] += bv.y;
          acc[mf][pf][2] += bv.z; acc[mf][pf][3] += bv.w;
          if constexpr (EPI == 1) {
#pragma unroll
            for (int rg = 0; rg < 4; ++rg) acc[mf][pf][rg] = fmaxf(acc[mf][pf][rg], 0.f);
          }
        }
        ushort4 st;
        st.x = f2h_bits(acc[mf][pf][0]); st.y = f2h_bits(acc[mf][pf][1]);
        st.z = f2h_bits(acc[mf][pf][2]); st.w = f2h_bits(acc[mf][pf][3]);
        *reinterpret_cast<ushort4*>(outB + ((size_t)n * NPIXO + opix) * COB + co0 + mf * 16 + lg * 4) = st;
      }
    }
    if constexpr (EPI == 0) {
      __syncthreads();
      float* sl = (float*)lds;
#pragma unroll
      for (int mf = 0; mf < MFR; ++mf) {
#pragma unroll
        for (int rg = 0; rg < 4; ++rg) {
          float s = 0.f, q2 = 0.f;
#pragma unroll
          for (int pf = 0; pf < WPIX; ++pf) {
            const float v = acc[mf][pf][rg];
            s += v; q2 += v * v;
          }
#pragma unroll
          for (int o = 1; o < 16; o <<= 1) { s += __shfl_xor(s, o); q2 += __shfl_xor(q2, o); }
          if (ln == 0) {
            const int cl = mf * 16 + lg * 4 + rg;
            sl[(wid * MFR * 16 + cl) * 2 + 0] = s;
            sl[(wid * MFR * 16 + cl) * 2 + 1] = q2;
          }
        }
      }
      __syncthreads();
      for (int i = tid; i < MFR * 16 * 2; i += 256) {
        const int cl = i >> 1, stt = i & 1;
        float tot = 0.f;
#pragma unroll
        for (int w = 0; w < 4; ++w) tot += sl[(w * MFR * 16 + cl) * 2 + stt];
        atomicAdd(&statL[2 * (co0 + cl) + stt], tot);
      }
    }
  }
  (void)outF;
}

// ---------------------------------------------------------------- mconv2 (round-11/14 exact)
// 3x3 s1, 32x32 image, weights staged in LDS per slab from dense [t][ks][co][32] layout.
// COT must be 64 (MFR=4).
template <int G, int COP, int MFR, int PIXROWS, int WPIX>
__global__ __launch_bounds__(256) void mconv2(
    const hf* __restrict__ src1, const hf* __restrict__ wp,
    float* __restrict__ statL, hf* __restrict__ outB) {
  constexpr int IMG = 32;
  constexpr int TAPS = 9;
  constexpr int TC = IMG + 2;
  constexpr int TR = PIXROWS + 2;
  constexpr int NSLOT = TR * TC;
  constexpr int PSTR = NSLOT + 1;
  constexpr int NCH = G / 32;
  constexpr int NPIX = IMG * IMG;
  constexpr int NCHUNK = NSLOT * 4;
  constexpr int COT = MFR * 16;      // 64
  constexpr int WPLANE = TAPS * COT;
  constexpr int WPSTR  = WPLANE + 1;
  constexpr int WCHUNK = WPLANE * 4;

  __shared__ __align__(16) hf alds[4 * PSTR * 8];
  __shared__ __align__(16) hf wlds[4 * WPSTR * 8];

  const int tid = threadIdx.x;
  const int wid = tid >> 6, lane = tid & 63, lg = lane >> 4, ln = lane & 15;
  const int n = blockIdx.z;
  const int r0 = blockIdx.x * PIXROWS;
  const int co0 = blockIdx.y * COT;

  f32x4 acc[MFR][WPIX];
#pragma unroll
  for (int mf = 0; mf < MFR; ++mf)
#pragma unroll
    for (int pf = 0; pf < WPIX; ++pf) acc[mf][pf] = (f32x4){0.f, 0.f, 0.f, 0.f};

  for (int ks = 0; ks < NCH; ++ks) {
    __syncthreads();
    for (int cidx = tid; cidx < NCHUNK; cidx += 256) {
      const int s = cidx >> 2, p = cidx & 3;
      const int rs = s / TC, cs = s - rs * TC;
      const int ir = r0 - 1 + rs, ic = cs - 1;
      s8v v = (s8v){0, 0, 0, 0, 0, 0, 0, 0};
      if (((unsigned)ir < (unsigned)IMG) && ((unsigned)ic < (unsigned)IMG)) {
        const int ipix = ir * IMG + ic;
        v = *(const s8v*)(src1 + (((size_t)n * NPIX + ipix) * G + ks * 32 + p * 8));
      }
      *(s8v*)(&alds[(size_t)(p * PSTR + s) * 8]) = v;
    }
    for (int widx = tid; widx < WCHUNK; widx += 256) {
      const int p = widx & 3;
      const int r = widx >> 2;
      const int co = r & (COT - 1);
      const int t = r >> 6;
      const s8v wv = *(const s8v*)(wp + (((size_t)(t * NCH + ks) * COP + co0 + co) * 32 + p * 8));
      *(s8v*)(&wlds[(size_t)(p * WPSTR + r) * 8]) = wv;
    }
    __syncthreads();
#pragma unroll
    for (int t = 0; t < TAPS; ++t) {
      const int kh = t / 3, kw = t % 3;
      const int dh = kh - 1, dw = kw - 1;
      h8v afr[MFR];
#pragma unroll
      for (int mf = 0; mf < MFR; ++mf)
        afr[mf] = *(const h8v*)(&wlds[(size_t)(lg * WPSTR + t * COT + mf * 16 + ln) * 8]);
#pragma unroll
      for (int pf = 0; pf < WPIX; ++pf) {
        const int pl = wid * (WPIX * 16) + pf * 16 + ln;
        const int rL = pl / IMG, c = pl - rL * IMG;
        const int slot = (rL + dh + 1) * TC + (c + dw + 1);
        const h8v bfr = *(const h8v*)(&alds[(size_t)(lg * PSTR + slot) * 8]);
#pragma unroll
        for (int mf = 0; mf < MFR; ++mf)
          acc[mf][pf] = __builtin_amdgcn_mfma_f32_16x16x32_f16(afr[mf], bfr, acc[mf][pf], 0, 0, 0);
      }
    }
  }

#pragma unroll
  for (int mf = 0; mf < MFR; ++mf) {
#pragma unroll
    for (int pf = 0; pf < WPIX; ++pf) {
      const int pl = wid * (WPIX * 16) + pf * 16 + ln;
      const int rL = pl / IMG, c = pl - rL * IMG;
      const int opix = (r0 + rL) * IMG + c;
      ushort4 st;
      st.x = f2h_bits(acc[mf][pf][0]); st.y = f2h_bits(acc[mf][pf][1]);
      st.z = f2h_bits(acc[mf][pf][2]); st.w = f2h_bits(acc[mf][pf][3]);
      *reinterpret_cast<ushort4*>(outB + ((size_t)n * NPIX + opix) * COP + co0 + mf * 16 + lg * 4) = st;
    }
  }
  __syncthreads();
  float* sl = (float*)alds;
#pragma unroll
  for (int mf = 0; mf < MFR; ++mf) {
#pragma unroll
    for (int rg = 0; rg < 4; ++rg) {
      float s = 0.f, q2 = 0.f;
#pragma unroll
      for (int pf = 0; pf < WPIX; ++pf) {
        const float v = acc[mf][pf][rg];
        s += v; q2 += v * v;
      }
#pragma unroll
      for (int o = 1; o < 16; o <<= 1) { s += __shfl_xor(s, o); q2 += __shfl_xor(q2, o); }
      if (ln == 0) {
        const int cl = mf * 16 + lg * 4 + rg;
        sl[(wid * MFR * 16 + cl) * 2 + 0] = s;
        sl[(wid * MFR * 16 + cl) * 2 + 1] = q2;
      }
    }
  }
  __syncthreads();
  for (int i = tid; i < MFR * 16 * 2; i += 256) {
    const int cl = i >> 1, stt = i & 1;
    float tot = 0.f;
#pragma unroll
    for (int w = 0; w < 4; ++w) tot += sl[(w * MFR * 16 + cl) * 2 + stt];
    atomicAdd(&statL[2 * (co0 + cl) + stt], tot);
  }
}

// ---------------------------------------------------------------- mconv2s: stride-2 weight-LDS path
// 3x3 s2 (in 64 -> out 32). Staging/tap addressing copied from mconv GEOM==1.
// Weight machinery verbatim from mconv2 (COT=64, dense [t][ks][co][32]).
// PIXROWS output rows per block (PIXROWS=2 -> TR=5).
template <int G, int COP, int MFR, int PIXROWS, int WPIX>
__global__ __launch_bounds__(256) void mconv2s(
    const hf* __restrict__ src1, const hf* __restrict__ wp,
    float* __restrict__ statL, hf* __restrict__ outB) {
  constexpr int IMGI = 64, IMGO = 32;
  constexpr int TAPS = 9;
  constexpr int TR = 2 * PIXROWS + 1;
  constexpr int TC = 65;
  constexpr int NSLOT = TR * TC;
  constexpr int PSTR = NSLOT + 1;
  constexpr int NCH = G / 32;
  constexpr int NPIXI = IMGI * IMGI;
  constexpr int NPIXO = IMGO * IMGO;
  constexpr int NCHUNK = NSLOT * 4;
  constexpr int COT = MFR * 16;      // 64
  constexpr int WPLANE = TAPS * COT;
  constexpr int WPSTR  = WPLANE + 1;
  constexpr int WCHUNK = WPLANE * 4;

  __shared__ __align__(16) hf alds[4 * PSTR * 8];
  __shared__ __align__(16) hf wlds[4 * WPSTR * 8];

  const int tid = threadIdx.x;
  const int wid = tid >> 6, lane = tid & 63, lg = lane >> 4, ln = lane & 15;
  const int n = blockIdx.z;
  const int r0 = blockIdx.x * PIXROWS;
  const int co0 = blockIdx.y * COT;

  f32x4 acc[MFR][WPIX];
#pragma unroll
  for (int mf = 0; mf < MFR; ++mf)
#pragma unroll
    for (int pf = 0; pf < WPIX; ++pf) acc[mf][pf] = (f32x4){0.f, 0.f, 0.f, 0.f};

  for (int ks = 0; ks < NCH; ++ks) {
    __syncthreads();
    // activation staging (identical addressing to mconv GEOM==1)
    for (int cidx = tid; cidx < NCHUNK; cidx += 256) {
      const int s = cidx >> 2, p = cidx & 3;
      const int rs = s / TC, cs = s - rs * TC;
      const int ir = 2 * r0 - 1 + rs;
      const int ic = (cs < 32) ? 2 * cs : 2 * (cs - 32) - 1;
      s8v v = (s8v){0, 0, 0, 0, 0, 0, 0, 0};
      if (((unsigned)ir < (unsigned)IMGI) && ((unsigned)ic < (unsigned)IMGI)) {
        const int ipix = ir * IMGI + ic;
        v = *(const s8v*)(src1 + (((size_t)n * NPIXI + ipix) * G + ks * 32 + p * 8));
      }
      *(s8v*)(&alds[(size_t)(p * PSTR + s) * 8]) = v;
    }
    // weight staging (verbatim mconv2 machinery)
    for (int widx = tid; widx < WCHUNK; widx += 256) {
      const int p = widx & 3;
      const int r = widx >> 2;
      const int co = r & (COT - 1);
      const int t = r >> 6;
      const s8v wv = *(const s8v*)(wp + (((size_t)(t * NCH + ks) * COP + co0 + co) * 32 + p * 8));
      *(s8v*)(&wlds[(size_t)(p * WPSTR + r) * 8]) = wv;
    }
    __syncthreads();
#pragma unroll
    for (int t = 0; t < TAPS; ++t) {
      const int kh = t / 3, kw = t % 3;
      h8v afr[MFR];
#pragma unroll
      for (int mf = 0; mf < MFR; ++mf)
        afr[mf] = *(const h8v*)(&wlds[(size_t)(lg * WPSTR + t * COT + mf * 16 + ln) * 8]);
#pragma unroll
      for (int pf = 0; pf < WPIX; ++pf) {
        const int pl = wid * (WPIX * 16) + pf * 16 + ln;
        const int rL = pl / IMGO, c = pl - rL * IMGO;
        const int slot = (2 * rL + kh) * 65 + ((kw == 1) ? c : (32 + c + (kw >> 1)));
        const h8v bfr = *(const h8v*)(&alds[(size_t)(lg * PSTR + slot) * 8]);
#pragma unroll
        for (int mf = 0; mf < MFR; ++mf)
          acc[mf][pf] = __builtin_amdgcn_mfma_f32_16x16x32_f16(afr[mf], bfr, acc[mf][pf], 0, 0, 0);
      }
    }
  }

#pragma unroll
  for (int mf = 0; mf < MFR; ++mf) {
#pragma unroll
    for (int pf = 0; pf < WPIX; ++pf) {
      const int pl = wid * (WPIX * 16) + pf * 16 + ln;
      const int rL = pl / IMGO, c = pl - rL * IMGO;
      const int opix = (r0 + rL) * IMGO + c;
      ushort4 st;
      st.x = f2h_bits(acc[mf][pf][0]); st.y = f2h_bits(acc[mf][pf][1]);
      st.z = f2h_bits(acc[mf][pf][2]); st.w = f2h_bits(acc[mf][pf][3]);
      *reinterpret_cast<ushort4*>(outB + ((size_t)n * NPIXO + opix) * COP + co0 + mf * 16 + lg * 4) = st;
    }
  }
  __syncthreads();
  float* sl = (float*)alds;
#pragma unroll
  for (int mf = 0; mf < MFR; ++mf) {
#pragma unroll
    for (int rg = 0; rg < 4; ++rg) {
      float s = 0.f, q2 = 0.f;
#pragma unroll
      for (int pf = 0; pf < WPIX; ++pf) {
        const float v = acc[mf][pf][rg];
        s += v; q2 += v * v;
      }
#pragma unroll
      for (int o = 1; o < 16; o <<= 1) { s += __shfl_xor(s, o); q2 += __shfl_xor(q2, o); }
      if (ln == 0) {
        const int cl = mf * 16 + lg * 4 + rg;
        sl[(wid * MFR * 16 + cl) * 2 + 0] = s;
        sl[(wid * MFR * 16 + cl) * 2 + 1] = q2;
      }
    }
  }
  __syncthreads();
  for (int i = tid; i < MFR * 16 * 2; i += 256) {
    const int cl = i >> 1, stt = i & 1;
    float tot = 0.f;
#pragma unroll
    for (int w = 0; w < 4; ++w) tot += sl[(w * MFR * 16 + cl) * 2 + stt];
    atomicAdd(&statL[2 * (co0 + cl) + stt], tot);
  }
}

// ---------------------------------------------------------------- BN finalize
__global__ void bnfin_kernel(float* __restrict__ statL, const float* __restrict__ g,
                             const float* __restrict__ bt, int C, float invCnt) {
  const int c = threadIdx.x;
  if (c < C) {
    const float m = statL[2 * c] * invCnt;
    const float var = statL[2 * c + 1] * invCnt - m * m;
    const float sc = g[c] * rsqrtf(var + 1e-5f);
    statL[256 + c] = sc;
    statL[384 + c] = bt[c] - m * sc;
  }
}

// ---------------------------------------------------------------- in-place BN+ReLU
template <int G8>
__global__ __launch_bounds__(256) void norm_ip(hf* __restrict__ x,
                                               const float* __restrict__ statL, long nch) {
  for (long i = (long)blockIdx.x * 256 + threadIdx.x; i < nch; i += (long)gridDim.x * 256) {
    const int ci8 = (int)(i % G8);
    s8v v = *(s8v*)(x + i * 8);
    const f32x4 scA = *(const f32x4*)(statL + 256 + ci8 * 8);
    const f32x4 scB = *(const f32x4*)(statL + 256 + ci8 * 8 + 4);
    const f32x4 shA = *(const f32x4*)(statL + 384 + ci8 * 8);
    const f32x4 shB = *(const f32x4*)(statL + 384 + ci8 * 8 + 4);
    s8v o;
#pragma unroll
    for (int j = 0; j < 8; ++j) {
      const float sc = (j < 4) ? scA[j] : scB[j - 4];
      const float sh = (j < 4) ? shA[j] : shB[j - 4];
      const float f = fmaxf(h2f_bits((unsigned short)v[j]) * sc + sh, 0.f);
      o[j] = (short)f2h_bits(f);
    }
    *(s8v*)(x + i * 8) = o;
  }
}

// ---------------------------------------------------------------- conv5 (CO=1) on VALU
__global__ __launch_bounds__(256) void conv5_kernel(
    const hf* __restrict__ xd, const float* __restrict__ w5, const float* __restrict__ b5,
    float* __restrict__ outp) {
  const int gid = blockIdx.x * 256 + threadIdx.x;  // 162*4096
  const int n = gid >> 12, pix = gid & 4095;
  const int b = n / 81, ij = n - b * 81;
  const int oh = pix >> 6, ow = pix & 63;
  float acc = b5[0];
#pragma unroll
  for (int kh = 0; kh < 3; ++kh) {
    const int ih = oh + kh - 1;
#pragma unroll
    for (int kw = 0; kw < 3; ++kw) {
      const int iw = ow + kw - 1;
      if (((unsigned)ih < 64u) && ((unsigned)iw < 64u)) {
        const hf* xp = xd + ((size_t)n * 4096 + ih * 64 + iw) * 32;
#pragma unroll
        for (int cq = 0; cq < 4; ++cq) {
          const h8v v = *(const h8v*)(xp + cq * 8);
#pragma unroll
          for (int j = 0; j < 8; ++j)
            acc += (float)v[j] * w5[(cq * 8 + j) * 9 + kh * 3 + kw];
        }
      }
    }
  }
  outp[((size_t)(b * 113 + ij)) * 4096 + pix] = acc;
}

// ---------------------------------------------------------------- DAP softmax
__global__ __launch_bounds__(64) void softmax_kernel(
    const float* __restrict__ outp, const float* __restrict__ dapw, float* __restrict__ score) {
  __shared__ float cb[64 * 81];
  __shared__ float sb[64 * 81];
  const int t = threadIdx.x;
  const int gid = blockIdx.x * 64 + t;
  const int b = gid >> 12, hw = gid & 4095;
  for (int d = 0; d < 81; ++d)
    cb[t * 81 + d] = outp[((size_t)(b * 113 + d)) * 4096 + hw];
  float smax = -1e30f;
  for (int o = 0; o < 81; ++o) {
    float s = 0.f;
    const float* dr = dapw + o * 81;
    for (int d = 0; d < 81; ++d) s += dr[d] * cb[t * 81 + d];
    sb[t * 81 + o] = s;
    smax = fmaxf(smax, s);
  }
  float sum = 0.f;
  for (int o = 0; o < 81; ++o) {
    const float e = __expf(sb[t * 81 + o] - smax);
    sb[t * 81 + o] = e;
    sum += e;
  }
  const float inv = 1.f / sum;
  for (int o = 0; o < 81; ++o)
    score[((size_t)(b * 81 + o)) * 4096 + hw] = sb[t * 81 + o] * inv;
}

// ---------------------------------------------------------------- emb reduce
__global__ __launch_bounds__(256) void emb_kernel(
    const float* __restrict__ score, const hf* __restrict__ e3, float* __restrict__ outp) {
  const int idx = blockIdx.x * 256 + threadIdx.x;  // 2*32*4096
  const int b = idx >> 17, r = idx & 131071, m = r >> 12, hw = r & 4095;
  float acc = 0.f;
  for (int d = 0; d < 81; ++d) {
    const float sc = score[((size_t)(b * 81 + d)) * 4096 + hw];
    acc += sc * (float)e3[(((size_t)(b * 81 + d)) * 4096 + hw) * 32 + m];
  }
  outp[((size_t)(b * 113 + 81 + m)) * 4096 + hw] = acc;
}

// ======================================================================
extern "C" void kernel_launch(void* const* d_in, const int* in_sizes, int n_in,
                              void* d_out, int out_size, void* d_ws, size_t ws_size,
                              hipStream_t stream) {
  const float* f1     = (const float*)d_in[0];
  const float* f2     = (const float*)d_in[1];
  const float* coords = (const float*)d_in[2];
  const float* w1     = (const float*)d_in[3];
  const float* g1     = (const float*)d_in[4];
  const float* bb1    = (const float*)d_in[5];
  const float* w2     = (const float*)d_in[6];
  const float* g2     = (const float*)d_in[7];
  const float* bb2    = (const float*)d_in[8];
  const float* w3     = (const float*)d_in[9];
  const float* g3     = (const float*)d_in[10];
  const float* bb3    = (const float*)d_in[11];
  const float* w4     = (const float*)d_in[12];
  const float* g4     = (const float*)d_in[13];
  const float* bb4    = (const float*)d_in[14];
  const float* wdcv   = (const float*)d_in[15];
  const float* gd     = (const float*)d_in[16];
  const float* bbd    = (const float*)d_in[17];
  const float* w5     = (const float*)d_in[18];
  const float* b5     = (const float*)d_in[19];
  const float* e1w    = (const float*)d_in[20];
  const float* e1bi   = (const float*)d_in[21];
  const float* e2w    = (const float*)d_in[22];
  const float* e2bi   = (const float*)d_in[23];
  const float* e3w    = (const float*)d_in[24];
  const float* e3bi   = (const float*)d_in[25];
  const float* dapw   = (const float*)d_in[26];
  float* out = (float*)d_out;
  char* ws = (char*)d_ws;

  hf* sA  = (hf*)(ws + OFF_SA);
  hf* f2s = (hf*)(ws + OFF_F2S);
  hf* be1 = (hf*)(ws + OFF_E1);
  hf* be2 = (hf*)(ws + OFF_E2);
  hf* be3 = (hf*)(ws + OFF_E3);
  hf* x1  = (hf*)(ws + OFF_X1);
  hf* x2  = (hf*)(ws + OFF_X2);
  hf* x3  = (hf*)(ws + OFF_X3);
  hf* x4  = (hf*)(ws + OFF_X4);
  hf* xd  = (hf*)(ws + OFF_XD);
  float* score = (float*)(ws + OFF_SCORE);
  float* stats = (float*)(ws + OFF_STATS);
  hf* wc1 = (hf*)(ws + OFF_WC1);
  hf* wc2 = (hf*)(ws + OFF_WC2);
  hf* wc3 = (hf*)(ws + OFF_WC3);
  hf* wc4 = (hf*)(ws + OFF_WC4);
  hf* wdc = (hf*)(ws + OFF_WDC);
  hf* we1 = (hf*)(ws + OFF_WE1);
  hf* we2 = (hf*)(ws + OFF_WE2);
  hf* we3 = (hf*)(ws + OFF_WE3);
  float* dt1 = (float*)(ws + OFF_DT1);
  float* dtE = (float*)(ws + OFF_DTE);
  float* f2clf = (float*)(ws + OFF_F2CLF);

  hipMemsetAsync(stats, 0, 2560 * sizeof(float), stream);

  // weight prepacks (round-14 + ONE change: wc2 now dense for mconv2s)
  prepack<<<216, 256, 0, stream>>>(w1,   wc1, 96, 96, 64, 66, 64, 9);
  prepack2<<<432, 256, 0, stream>>>(w2,  wc2, 128, 96, 3);
  prepack2<<<576, 256, 0, stream>>>(w3,  wc3, 128, 128, 4);
  prepack2<<<288, 256, 0, stream>>>(w4,  wc4, 64, 128, 4);
  prepack<<<128, 256, 0, stream>>>(wdcv, wdc, 32, 32, 64, 64, 64, 16);
  prepack<<<12,  256, 0, stream>>>(e1w,  we1, 48, 48, 64, 66, 64, 1);
  prepack<<<16,  256, 0, stream>>>(e2w,  we2, 64, 64, 48, 48, 64, 1);
  prepack<<<8,   256, 0, stream>>>(e3w,  we3, 32, 32, 64, 64, 64, 1);
  dtab1_kernel<<<7, 256, 0, stream>>>(w1, dt1);
  dtabE_kernel<<<1, 96, 0, stream>>>(e1w, dtE);

  // inputs (f2 interpolated in fp32)
  packf1<<<32, 256, 0, stream>>>(f1, sA);
  packf2f32<<<32, 256, 0, stream>>>(f2, f2clf);
  sample2<<<2592, 256, 0, stream>>>(f2clf, coords, f2s);

  // embedding branch (DIRECT 1x1 convs)
  mconv<3, 1, true, 32, 64, 48, 48, 3, 64, 64, 4, 4, true>
      <<<dim3(16, 1, 162), 256, 0, stream>>>(f2s, sA, we1, e1bi, dtE, nullptr, be1, nullptr);
  mconv<3, 1, false, 48, 64, 64, 64, 4, 64, 64, 4, 4, false>
      <<<dim3(16, 1, 162), 256, 0, stream>>>(be1, nullptr, we2, e2bi, nullptr, nullptr, be2, nullptr);
  mconv<3, 2, false, 64, 64, 32, 32, 2, 64, 64, 4, 4, false>
      <<<dim3(16, 1, 162), 256, 0, stream>>>(be2, nullptr, we3, e3bi, nullptr, nullptr, be3, nullptr);

  // conv1: round-11 path (old mconv)
  mconv<0, 0, true, 32, 64, 96, 96, 3, 64, 64, 4, 4, true>
      <<<dim3(16, 2, 162), 256, 0, stream>>>(f2s, sA, wc1, nullptr, dt1, stats + 0, x1, nullptr);
  bnfin_kernel<<<1, 128, 0, stream>>>(stats + 0, g1, bb1, 96, 1.f / 663552.f);
  norm_ip<12><<<2048, 256, 0, stream>>>(x1, stats + 0, 7962624L);

  // conv2: THE single new change — stride-2 weight-LDS path
  mconv2s<96, 128, 4, 2, 1>
      <<<dim3(16, 2, 162), 256, 0, stream>>>(x1, wc2, stats + 512, x2);
  bnfin_kernel<<<1, 128, 0, stream>>>(stats + 512, g2, bb2, 128, 1.f / 165888.f);
  norm_ip<16><<<2048, 256, 0, stream>>>(x2, stats + 512, 2654208L);

  // conv3: proven weight-LDS path
  mconv2<128, 128, 4, 4, 2>
      <<<dim3(8, 2, 162), 256, 0, stream>>>(x2, wc3, stats + 1024, x3);
  bnfin_kernel<<<1, 128, 0, stream>>>(stats + 1024, g3, bb3, 128, 1.f / 165888.f);
  norm_ip<16><<<2048, 256, 0, stream>>>(x3, stats + 1024, 2654208L);

  // conv4: proven weight-LDS path (COP=64)
  mconv2<128, 64, 4, 4, 2>
      <<<dim3(8, 1, 162), 256, 0, stream>>>(x3, wc4, stats + 1536, x4);
  bnfin_kernel<<<1, 128, 0, stream>>>(stats + 1536, g4, bb4, 64, 1.f / 165888.f);
  norm_ip<8><<<2048, 256, 0, stream>>>(x4, stats + 1536, 1327104L);

  // deconv: round-11 path
  mconv<2, 0, false, 64, 64, 32, 32, 2, 32, 32, 8, 4, false>
      <<<dim3(4, 4, 162), 256, 0, stream>>>(x4, nullptr, wdc, nullptr, nullptr, stats + 2048, xd, nullptr);
  bnfin_kernel<<<1, 128, 0, stream>>>(stats + 2048, gd, bbd, 32, 1.f / 663552.f);
  norm_ip<4><<<2048, 256, 0, stream>>>(xd, stats + 2048, 2654208L);

  // conv5 on VALU (reads normalized xd, fp32 weights) -> cost planes of out
  conv5_kernel<<<2592, 256, 0, stream>>>(xd, w5, b5, out);

  // DAP softmax + embedding reduction
  softmax_kernel<<<128, 64, 0, stream>>>(out, dapw, score);
  emb_kernel<<<1024, 256, 0, stream>>>(score, be3, out);

  (void)in_sizes; (void)n_in; (void)out_size; (void)ws_size;
}

// Round 17
// 984.417 us; speedup vs baseline: 1.0813x; 1.0813x over previous
//
#include <hip/hip_runtime.h>
#include <hip/hip_bf16.h>

typedef _Float16 hf;
typedef short    s8v  __attribute__((ext_vector_type(8)));
typedef _Float16 h8v  __attribute__((ext_vector_type(8)));
typedef float    f32x4 __attribute__((ext_vector_type(4)));

#define DEVINL __device__ __forceinline__

DEVINL unsigned short f2h_bits(float f) { return __builtin_bit_cast(unsigned short, (hf)f); }
DEVINL float h2f_bits(unsigned short u) { return (float)__builtin_bit_cast(hf, u); }

// ---------------------------------------------------------------- arena
static constexpr size_t OFF_SA    = 0;           // f1 packed  [2][4096][32] hf
static constexpr size_t OFF_F2S   = 524288;      // f2 sampled [162][4096][32] hf
static constexpr size_t OFF_E1    = 42991616;    // e1out [162][4096][48]
static constexpr size_t OFF_E2    = 106692608;   // e2out [162][4096][64]
static constexpr size_t OFF_E3    = 42991616;    // e3out [162][4096][32] (reuse E1)
static constexpr size_t OFF_X1    = 85458944;    // x1 [162][4096][96]
static constexpr size_t OFF_X2    = 524288;      // x2 [162][1024][128]
static constexpr size_t OFF_X3    = 85458944;    // x3 [162][1024][128]
static constexpr size_t OFF_X4    = 524288;      // x4 [162][1024][64]
static constexpr size_t OFF_XD    = 127926272;   // xd [162][4096][32]
static constexpr size_t OFF_SCORE = 524288;      // f32 [2][81][4096]
static constexpr size_t OFF_STATS = 212860928;   // f32 2560
static constexpr size_t OFF_WC1   = 212871168;
static constexpr size_t OFF_WC2   = 212981760;
static constexpr size_t OFF_WC3   = 213202944;
static constexpr size_t OFF_WC4   = 213497856;
static constexpr size_t OFF_WDC   = 213645312;
static constexpr size_t OFF_WE1   = 213720064;
static constexpr size_t OFF_WE2   = 213726208;
static constexpr size_t OFF_WE3   = 213734400;
static constexpr size_t OFF_DT1   = 213738496;
static constexpr size_t OFF_DTE   = 213745408;
static constexpr size_t OFF_F2CLF = 213746048;   // f2 packed [2][4096][32] f32 (1 MB)

// ---------------------------------------------------------------- prepack (old [t][co][KP])
__global__ void prepack(const float* __restrict__ src, hf* __restrict__ dst,
                        int COr, int COP, int CINr, int CINsrc, int KP, int TAPS) {
  const int idx = blockIdx.x * 256 + threadIdx.x;
  const int total = TAPS * COP * KP;
  if (idx >= total) return;
  const int k = idx % KP;
  const int r = idx / KP;
  const int co = r % COP;
  const int t = r / COP;
  float v = 0.f;
  if (co < COr && k < CINr) v = src[((size_t)co * CINsrc + k) * TAPS + t];
  dst[idx] = (hf)v;
}

// dense layout: dst[t][ks][co][32] ; src = w[(co*CIN + ks*32 + kk)*9 + t]
__global__ void prepack2(const float* __restrict__ src, hf* __restrict__ dst,
                         int COP, int CIN, int NCHn) {
  const int idx = blockIdx.x * 256 + threadIdx.x;
  const int total = 9 * NCHn * COP * 32;
  if (idx >= total) return;
  const int kk = idx & 31;
  const int r = idx >> 5;
  const int co = r % COP;
  const int r2 = r / COP;
  const int ks = r2 % NCHn;
  const int t = r2 / NCHn;
  dst[idx] = (hf)src[((size_t)co * CIN + ks * 32 + kk) * 9 + t];
}

// deconv parity-major dense: dst[par][tt][ks][co][32], par=qq*2+pp, tt=a*2+b,
// src = wd[((co*64 + ks*32+kk)*4 + (qq+2a))*4 + (pp+2b)]
__global__ void prepack2d(const float* __restrict__ src, hf* __restrict__ dst) {
  const int idx = blockIdx.x * 256 + threadIdx.x;  // 4*4*2*32*32 = 32768
  if (idx >= 32768) return;
  const int kk = idx & 31;
  const int co = (idx >> 5) & 31;
  const int ks = (idx >> 10) & 1;
  const int tt = (idx >> 11) & 3;
  const int par = idx >> 13;
  const int qq = par >> 1, pp = par & 1;
  const int a = tt >> 1, b = tt & 1;
  dst[idx] = (hf)src[(((size_t)co * 64 + ks * 32 + kk) * 4 + (qq + 2 * a)) * 4 + (pp + 2 * b)];
}

__global__ void dtab1_kernel(const float* __restrict__ w1, float* __restrict__ dtab) {
  const int idx = blockIdx.x * 256 + threadIdx.x;  // 96*9*2
  if (idx >= 96 * 9 * 2) return;
  const int c = idx & 1;
  const int r = idx >> 1;
  const int pat = r % 9;
  const int co = r / 9;
  const int rc = pat / 3, cc = pat % 3;
  const int kh0 = (rc == 0) ? 1 : 0, kh1 = (rc == 2) ? 1 : 2;
  const int kw0 = (cc == 0) ? 1 : 0, kw1 = (cc == 2) ? 1 : 2;
  float s = 0.f;
  for (int kh = kh0; kh <= kh1; ++kh)
    for (int kw = kw0; kw <= kw1; ++kw)
      s += w1[((size_t)(co * 66 + 64 + c) * 3 + kh) * 3 + kw];
  dtab[(co * 9 + pat) * 2 + c] = s;
}

__global__ void dtabE_kernel(const float* __restrict__ e1w, float* __restrict__ dtE) {
  const int co = threadIdx.x;
  if (co < 48) {
    dtE[co * 2 + 0] = e1w[co * 66 + 64];
    dtE[co * 2 + 1] = e1w[co * 66 + 65];
  }
}

// ---------------------------------------------------------------- input builders
__global__ __launch_bounds__(256) void packf1(const float* __restrict__ f1, hf* __restrict__ sA) {
  const int gid = blockIdx.x * 256 + threadIdx.x;  // 2*4096
  const int b = gid >> 12, pix = gid & 4095;
  unsigned words[16];
#pragma unroll
  for (int c = 0; c < 32; c += 2) {
    const float v0 = f1[((size_t)(b * 32 + c)) * 4096 + pix];
    const float v1 = f1[((size_t)(b * 32 + c + 1)) * 4096 + pix];
    words[c >> 1] = (unsigned)f2h_bits(v0) | ((unsigned)f2h_bits(v1) << 16);
  }
  uint4* dst = (uint4*)(sA + (size_t)gid * 32);
#pragma unroll
  for (int i = 0; i < 4; ++i)
    dst[i] = make_uint4(words[4 * i], words[4 * i + 1], words[4 * i + 2], words[4 * i + 3]);
}

__global__ __launch_bounds__(256) void packf2f32(const float* __restrict__ f2,
                                                 float* __restrict__ dst) {
  const int gid = blockIdx.x * 256 + threadIdx.x;  // 2*4096
  const int b = gid >> 12, pix = gid & 4095;
  float* op = dst + (size_t)gid * 32;
#pragma unroll
  for (int c = 0; c < 32; c += 4) {
    float4 v;
    v.x = f2[((size_t)(b * 32 + c + 0)) * 4096 + pix];
    v.y = f2[((size_t)(b * 32 + c + 1)) * 4096 + pix];
    v.z = f2[((size_t)(b * 32 + c + 2)) * 4096 + pix];
    v.w = f2[((size_t)(b * 32 + c + 3)) * 4096 + pix];
    *(float4*)(op + c) = v;
  }
}

__global__ __launch_bounds__(256) void sample2(const float* __restrict__ f2clf,
                                               const float* __restrict__ coords,
                                               hf* __restrict__ f2s) {
  const int gid = blockIdx.x * 256 + threadIdx.x;  // 162*4096
  const int n = gid >> 12, pix = gid & 4095;
  const int b = n / 81, ij = n - b * 81;
  const float di = (float)(ij / 9) - 4.f, dj = (float)(ij % 9) - 4.f;
  const float x = coords[((size_t)(b * 2 + 0)) * 4096 + pix] + di;
  const float y = coords[((size_t)(b * 2 + 1)) * 4096 + pix] + dj;
  const float x0f = floorf(x), y0f = floorf(y);
  const int x0 = (int)x0f, y0 = (int)y0f;
  const float wx1 = x - x0f, wx0 = 1.f - wx1;
  const float wy1 = y - y0f, wy0 = 1.f - wy1;
  const bool vx0 = (unsigned)x0 < 64u, vx1 = (unsigned)(x0 + 1) < 64u;
  const bool vy0 = (unsigned)y0 < 64u, vy1 = (unsigned)(y0 + 1) < 64u;
  const int x0c = min(max(x0, 0), 63), x1c = min(max(x0 + 1, 0), 63);
  const int y0c = min(max(y0, 0), 63), y1c = min(max(y0 + 1, 0), 63);
  const float w00 = (vy0 && vx0) ? wy0 * wx0 : 0.f;
  const float w01 = (vy0 && vx1) ? wy0 * wx1 : 0.f;
  const float w10 = (vy1 && vx0) ? wy1 * wx0 : 0.f;
  const float w11 = (vy1 && vx1) ? wy1 * wx1 : 0.f;
  const float* fb = f2clf + (size_t)b * 4096 * 32;
  const float* p00 = fb + (size_t)(y0c * 64 + x0c) * 32;
  const float* p01 = fb + (size_t)(y0c * 64 + x1c) * 32;
  const float* p10 = fb + (size_t)(y1c * 64 + x0c) * 32;
  const float* p11 = fb + (size_t)(y1c * 64 + x1c) * 32;
  unsigned words[16];
#pragma unroll
  for (int ch = 0; ch < 16; ++ch) {
    const float2 a  = *(const float2*)(p00 + ch * 2);
    const float2 bb = *(const float2*)(p01 + ch * 2);
    const float2 c  = *(const float2*)(p10 + ch * 2);
    const float2 d  = *(const float2*)(p11 + ch * 2);
    const float v0 = w00 * a.x + w01 * bb.x + w10 * c.x + w11 * d.x;
    const float v1 = w00 * a.y + w01 * bb.y + w10 * c.y + w11 * d.y;
    words[ch] = (unsigned)f2h_bits(v0) | ((unsigned)f2h_bits(v1) << 16);
  }
  uint4* dst = (uint4*)(f2s + (size_t)gid * 32);
#pragma unroll
  for (int i = 0; i < 4; ++i)
    dst[i] = make_uint4(words[4 * i], words[4 * i + 1], words[4 * i + 2], words[4 * i + 3]);
}

// ---------------------------------------------------------------- MFMA conv template (round-11 path)
template <int GEOM, int EPI, bool DUAL, int G, int KP, int COP, int COB, int MFR,
          int IMGO, int IMGI, int PIXROWS, int WPIX, bool DELTA>
__global__ __launch_bounds__(256) void mconv(
    const hf* __restrict__ src1, const hf* __restrict__ src0,
    const hf* __restrict__ wp, const float* __restrict__ bias,
    const float* __restrict__ dtab, float* __restrict__ statL,
    hf* __restrict__ outB, float* __restrict__ outF) {
  constexpr bool DIRECT = (GEOM == 3);
  constexpr int TAPS  = (GEOM == 2) ? 4 : (GEOM == 3) ? 1 : 9;
  constexpr int TR    = (GEOM == 1) ? (2 * PIXROWS + 1) : (GEOM == 3) ? 1 : (PIXROWS + 2);
  constexpr int TC    = (GEOM == 1) ? 65 : (GEOM == 3) ? 1 : (IMGI + 2);
  constexpr int NSLOT = TR * TC;
  constexpr int PSTR  = NSLOT + 1;
  constexpr int NCH   = KP / 32;
  constexpr int NPIXI = IMGI * IMGI;
  constexpr int NPIXO = (GEOM == 2) ? 4096 : IMGO * IMGO;
  constexpr int NCHUNK = NSLOT * 4;
  constexpr int CPT   = (NCHUNK + 255) / 256;
  constexpr int LDSE  = DIRECT ? 64 : 4 * PSTR * 8;

  __shared__ __align__(16) hf lds[LDSE];

  const int tid = threadIdx.x;
  const int wid = tid >> 6, lane = tid & 63, lg = lane >> 4, ln = lane & 15;
  const int n = blockIdx.z, b = n / 81, ij = n - b * 81;
  const int r0 = blockIdx.x * PIXROWS;
  const int qq = (GEOM == 2) ? (int)(blockIdx.y >> 1) : 0;
  const int pp = (GEOM == 2) ? (int)(blockIdx.y & 1) : 0;
  const int co0 = (GEOM == 2) ? 0 : (int)blockIdx.y * (MFR * 16);

  f32x4 acc[MFR][WPIX];
#pragma unroll
  for (int mf = 0; mf < MFR; ++mf)
#pragma unroll
    for (int pf = 0; pf < WPIX; ++pf) acc[mf][pf] = (f32x4){0.f, 0.f, 0.f, 0.f};

  if constexpr (DIRECT) {
#pragma unroll
    for (int ch = 0; ch < NCH; ++ch) {
      const int k0 = ch * 32;
      h8v afr[MFR];
#pragma unroll
      for (int mf = 0; mf < MFR; ++mf)
        afr[mf] = *(const h8v*)(wp + ((size_t)(co0 + mf * 16 + ln)) * KP + k0 + lg * 8);
#pragma unroll
      for (int pf = 0; pf < WPIX; ++pf) {
        const int pix = r0 * IMGO + wid * (WPIX * 16) + pf * 16 + ln;
        h8v bfr = (h8v){0, 0, 0, 0, 0, 0, 0, 0};
        if (DUAL) {
          bfr = (ch == 0)
              ? *(const h8v*)(src0 + (((size_t)b * NPIXI + pix) * 32 + lg * 8))
              : *(const h8v*)(src1 + (((size_t)n * NPIXI + pix) * 32 + lg * 8));
        } else {
          const int gci = k0 + lg * 8;
          if (gci < G)
            bfr = *(const h8v*)(src1 + (((size_t)n * NPIXI + pix) * G + gci));
        }
#pragma unroll
        for (int mf = 0; mf < MFR; ++mf)
          acc[mf][pf] = __builtin_amdgcn_mfma_f32_16x16x32_f16(afr[mf], bfr, acc[mf][pf], 0, 0, 0);
      }
    }
  } else {
    s8v rbuf[CPT];
    auto stage_load = [&](int k0) {
#pragma unroll
      for (int j = 0; j < CPT; ++j) {
        const int cidx = tid + j * 256;
        s8v v = (s8v){0, 0, 0, 0, 0, 0, 0, 0};
        if (cidx < NCHUNK) {
          const int s = cidx >> 2, p = cidx & 3;
          const int rs = s / TC, cs = s - rs * TC;
          int ir, ic;
          if (GEOM == 1) { ir = 2 * r0 - 1 + rs; ic = (cs < 32) ? 2 * cs : 2 * (cs - 32) - 1; }
          else           { ir = r0 - 1 + rs;     ic = cs - 1; }
          const int gci = k0 + p * 8;
          if (((unsigned)ir < (unsigned)IMGI) && ((unsigned)ic < (unsigned)IMGI)) {
            const int ipix = ir * IMGI + ic;
            if (DUAL) {
              if (gci < 32)
                v = *(const s8v*)(src0 + (((size_t)b * NPIXI + ipix) * 32 + gci));
              else
                v = *(const s8v*)(src1 + (((size_t)n * NPIXI + ipix) * 32 + (gci - 32)));
            } else if (gci < G) {
              v = *(const s8v*)(src1 + (((size_t)n * NPIXI + ipix) * G + gci));
            }
          }
        }
        rbuf[j] = v;
      }
    };
    auto stage_write = [&]() {
#pragma unroll
      for (int j = 0; j < CPT; ++j) {
        const int cidx = tid + j * 256;
        if (cidx < NCHUNK) {
          const int s = cidx >> 2, p = cidx & 3;
          *(s8v*)(&lds[(size_t)(p * PSTR + s) * 8]) = rbuf[j];
        }
      }
    };

    stage_load(0);
#pragma unroll
    for (int ch = 0; ch < NCH; ++ch) {
      if (ch > 0) __syncthreads();
      stage_write();
      __syncthreads();
      if (ch + 1 < NCH) stage_load((ch + 1) * 32);
      const int k0 = ch * 32;
#pragma unroll
      for (int t = 0; t < TAPS; ++t) {
        int dh, dw, wt, kh = 0, kw = 0;
        if (GEOM == 2) {
          dh = qq + (t >> 1) - 1; dw = pp + (t & 1) - 1;
          wt = (qq + 2 * (t >> 1)) * 4 + (pp + 2 * (t & 1));
        } else { kh = t / 3; kw = t % 3; dh = kh - 1; dw = kw - 1; wt = t; }
        h8v afr[MFR];
#pragma unroll
        for (int mf = 0; mf < MFR; ++mf)
          afr[mf] = *(const h8v*)(wp + ((size_t)(wt * COP + co0 + mf * 16 + ln)) * KP + k0 + lg * 8);
#pragma unroll
        for (int pf = 0; pf < WPIX; ++pf) {
          const int pl = wid * (WPIX * 16) + pf * 16 + ln;
          const int rL = pl / IMGO, c = pl - rL * IMGO;
          int slot;
          if (GEOM == 1) slot = (2 * rL + kh) * 65 + ((kw == 1) ? c : (32 + c + (kw >> 1)));
          else           slot = (rL + dh + 1) * TC + (c + dw + 1);
          const h8v bfr = *(const h8v*)(&lds[(size_t)(lg * PSTR + slot) * 8]);
#pragma unroll
          for (int mf = 0; mf < MFR; ++mf)
            acc[mf][pf] = __builtin_amdgcn_mfma_f32_16x16x32_f16(afr[mf], bfr, acc[mf][pf], 0, 0, 0);
        }
      }
    }
  }

  const float di = (float)(ij / 9) - 4.f, dj = (float)(ij % 9) - 4.f;

  {
#pragma unroll
    for (int mf = 0; mf < MFR; ++mf) {
#pragma unroll
      for (int pf = 0; pf < WPIX; ++pf) {
        const int pl = wid * (WPIX * 16) + pf * 16 + ln;
        const int rL = pl / IMGO, c = pl - rL * IMGO;
        int opix;
        if constexpr (GEOM == 2) opix = (2 * (r0 + rL) + qq) * 64 + 2 * c + pp;
        else opix = (r0 + rL) * IMGO + c;
        if constexpr (DELTA && EPI == 0) {
          const int oh = r0 + rL;
          const int rc = (oh == 0) ? 0 : ((oh == IMGO - 1) ? 2 : 1);
          const int cc = (c == 0) ? 0 : ((c == IMGO - 1) ? 2 : 1);
#pragma unroll
          for (int rg = 0; rg < 4; ++rg) {
            const int co = co0 + mf * 16 + lg * 4 + rg;
            acc[mf][pf][rg] += di * dtab[(co * 9 + rc * 3 + cc) * 2 + 0] +
                               dj * dtab[(co * 9 + rc * 3 + cc) * 2 + 1];
          }
        }
        if constexpr (DELTA && EPI == 1) {
#pragma unroll
          for (int rg = 0; rg < 4; ++rg) {
            const int co = co0 + mf * 16 + lg * 4 + rg;
            acc[mf][pf][rg] += di * dtab[co * 2] + dj * dtab[co * 2 + 1];
          }
        }
        if constexpr (EPI == 1 || EPI == 2) {
          const float4 bv = *(const float4*)(bias + co0 + mf * 16 + lg * 4);
          acc[mf][pf][0] += bv.x; acc[mf][pf][1] += bv.y;
          acc[mf][pf][2] += bv.z; acc[mf][pf][3] += bv.w;
          if constexpr (EPI == 1) {
#pragma unroll
            for (int rg = 0; rg < 4; ++rg) acc[mf][pf][rg] = fmaxf(acc[mf][pf][rg], 0.f);
          }
        }
        ushort4 st;
        st.x = f2h_bits(acc[mf][pf][0]); st.y = f2h_bits(acc[mf][pf][1]);
        st.z = f2h_bits(acc[mf][pf][2]); st.w = f2h_bits(acc[mf][pf][3]);
        *reinterpret_cast<ushort4*>(outB + ((size_t)n * NPIXO + opix) * COB + co0 + mf * 16 + lg * 4) = st;
      }
    }
    if constexpr (EPI == 0) {
      __syncthreads();
      float* sl = (float*)lds;
#pragma unroll
      for (int mf = 0; mf < MFR; ++mf) {
#pragma unroll
        for (int rg = 0; rg < 4; ++rg) {
          float s = 0.f, q2 = 0.f;
#pragma unroll
          for (int pf = 0; pf < WPIX; ++pf) {
            const float v = acc[mf][pf][rg];
            s += v; q2 += v * v;
          }
#pragma unroll
          for (int o = 1; o < 16; o <<= 1) { s += __shfl_xor(s, o); q2 += __shfl_xor(q2, o); }
          if (ln == 0) {
            const int cl = mf * 16 + lg * 4 + rg;
            sl[(wid * MFR * 16 + cl) * 2 + 0] = s;
            sl[(wid * MFR * 16 + cl) * 2 + 1] = q2;
          }
        }
      }
      __syncthreads();
      for (int i = tid; i < MFR * 16 * 2; i += 256) {
        const int cl = i >> 1, stt = i & 1;
        float tot = 0.f;
#pragma unroll
        for (int w = 0; w < 4; ++w) tot += sl[(w * MFR * 16 + cl) * 2 + stt];
        atomicAdd(&statL[2 * (co0 + cl) + stt], tot);
      }
    }
  }
  (void)outF;
}

// ---------------------------------------------------------------- mconv2 (proven)
// 3x3 s1, IMG=32, COT=64 (MFR=4), dense weights [t][ks][co][32].
template <int G, int COP, int MFR, int PIXROWS, int WPIX>
__global__ __launch_bounds__(256) void mconv2(
    const hf* __restrict__ src1, const hf* __restrict__ wp,
    float* __restrict__ statL, hf* __restrict__ outB) {
  constexpr int IMG = 32;
  constexpr int TAPS = 9;
  constexpr int TC = IMG + 2;
  constexpr int TR = PIXROWS + 2;
  constexpr int NSLOT = TR * TC;
  constexpr int PSTR = NSLOT + 1;
  constexpr int NCH = G / 32;
  constexpr int NPIX = IMG * IMG;
  constexpr int NCHUNK = NSLOT * 4;
  constexpr int COT = MFR * 16;      // 64
  constexpr int WPLANE = TAPS * COT;
  constexpr int WPSTR  = WPLANE + 1;
  constexpr int WCHUNK = WPLANE * 4;

  __shared__ __align__(16) hf alds[4 * PSTR * 8];
  __shared__ __align__(16) hf wlds[4 * WPSTR * 8];

  const int tid = threadIdx.x;
  const int wid = tid >> 6, lane = tid & 63, lg = lane >> 4, ln = lane & 15;
  const int n = blockIdx.z;
  const int r0 = blockIdx.x * PIXROWS;
  const int co0 = blockIdx.y * COT;

  f32x4 acc[MFR][WPIX];
#pragma unroll
  for (int mf = 0; mf < MFR; ++mf)
#pragma unroll
    for (int pf = 0; pf < WPIX; ++pf) acc[mf][pf] = (f32x4){0.f, 0.f, 0.f, 0.f};

  for (int ks = 0; ks < NCH; ++ks) {
    __syncthreads();
    for (int cidx = tid; cidx < NCHUNK; cidx += 256) {
      const int s = cidx >> 2, p = cidx & 3;
      const int rs = s / TC, cs = s - rs * TC;
      const int ir = r0 - 1 + rs, ic = cs - 1;
      s8v v = (s8v){0, 0, 0, 0, 0, 0, 0, 0};
      if (((unsigned)ir < (unsigned)IMG) && ((unsigned)ic < (unsigned)IMG)) {
        const int ipix = ir * IMG + ic;
        v = *(const s8v*)(src1 + (((size_t)n * NPIX + ipix) * G + ks * 32 + p * 8));
      }
      *(s8v*)(&alds[(size_t)(p * PSTR + s) * 8]) = v;
    }
    for (int widx = tid; widx < WCHUNK; widx += 256) {
      const int p = widx & 3;
      const int r = widx >> 2;
      const int co = r & (COT - 1);
      const int t = r >> 6;
      const s8v wv = *(const s8v*)(wp + (((size_t)(t * NCH + ks) * COP + co0 + co) * 32 + p * 8));
      *(s8v*)(&wlds[(size_t)(p * WPSTR + r) * 8]) = wv;
    }
    __syncthreads();
#pragma unroll
    for (int t = 0; t < TAPS; ++t) {
      const int kh = t / 3, kw = t % 3;
      const int dh = kh - 1, dw = kw - 1;
      h8v afr[MFR];
#pragma unroll
      for (int mf = 0; mf < MFR; ++mf)
        afr[mf] = *(const h8v*)(&wlds[(size_t)(lg * WPSTR + t * COT + mf * 16 + ln) * 8]);
#pragma unroll
      for (int pf = 0; pf < WPIX; ++pf) {
        const int pl = wid * (WPIX * 16) + pf * 16 + ln;
        const int rL = pl / IMG, c = pl - rL * IMG;
        const int slot = (rL + dh + 1) * TC + (c + dw + 1);
        const h8v bfr = *(const h8v*)(&alds[(size_t)(lg * PSTR + slot) * 8]);
#pragma unroll
        for (int mf = 0; mf < MFR; ++mf)
          acc[mf][pf] = __builtin_amdgcn_mfma_f32_16x16x32_f16(afr[mf], bfr, acc[mf][pf], 0, 0, 0);
      }
    }
  }

#pragma unroll
  for (int mf = 0; mf < MFR; ++mf) {
#pragma unroll
    for (int pf = 0; pf < WPIX; ++pf) {
      const int pl = wid * (WPIX * 16) + pf * 16 + ln;
      const int rL = pl / IMG, c = pl - rL * IMG;
      const int opix = (r0 + rL) * IMG + c;
      ushort4 st;
      st.x = f2h_bits(acc[mf][pf][0]); st.y = f2h_bits(acc[mf][pf][1]);
      st.z = f2h_bits(acc[mf][pf][2]); st.w = f2h_bits(acc[mf][pf][3]);
      *reinterpret_cast<ushort4*>(outB + ((size_t)n * NPIX + opix) * COP + co0 + mf * 16 + lg * 4) = st;
    }
  }
  __syncthreads();
  float* sl = (float*)alds;
#pragma unroll
  for (int mf = 0; mf < MFR; ++mf) {
#pragma unroll
    for (int rg = 0; rg < 4; ++rg) {
      float s = 0.f, q2 = 0.f;
#pragma unroll
      for (int pf = 0; pf < WPIX; ++pf) {
        const float v = acc[mf][pf][rg];
        s += v; q2 += v * v;
      }
#pragma unroll
      for (int o = 1; o < 16; o <<= 1) { s += __shfl_xor(s, o); q2 += __shfl_xor(q2, o); }
      if (ln == 0) {
        const int cl = mf * 16 + lg * 4 + rg;
        sl[(wid * MFR * 16 + cl) * 2 + 0] = s;
        sl[(wid * MFR * 16 + cl) * 2 + 1] = q2;
      }
    }
  }
  __syncthreads();
  for (int i = tid; i < MFR * 16 * 2; i += 256) {
    const int cl = i >> 1, stt = i & 1;
    float tot = 0.f;
#pragma unroll
    for (int w = 0; w < 4; ++w) tot += sl[(w * MFR * 16 + cl) * 2 + stt];
    atomicAdd(&statL[2 * (co0 + cl) + stt], tot);
  }
}

// ---------------------------------------------------------------- mconv2d: deconv weight-LDS
// k4 s2 p1 as 4 parity 2x2 convs; blockIdx.y = par. Single-source, no DELTA.
// Weights dense [par][tt][ks][co][32]; COT=32 (MFR=2) mask/shift machinery (proven).
__global__ __launch_bounds__(256) void mconv2d(
    const hf* __restrict__ src1, const hf* __restrict__ wp,
    float* __restrict__ statL, hf* __restrict__ outB) {
  constexpr int IMG = 32;
  constexpr int TAPS = 4;
  constexpr int PIXROWS = 8;
  constexpr int WPIX = 4;
  constexpr int MFR = 2;
  constexpr int TC = IMG + 2;        // 34
  constexpr int TR = PIXROWS + 2;    // 10
  constexpr int NSLOT = TR * TC;     // 340
  constexpr int PSTR = NSLOT + 1;    // 341
  constexpr int NCH = 2;             // K = 64
  constexpr int NPIX = IMG * IMG;    // 1024
  constexpr int NCHUNK = NSLOT * 4;  // 1360
  constexpr int COT = MFR * 16;      // 32
  constexpr int WPLANE = TAPS * COT; // 128
  constexpr int WPSTR  = WPLANE + 1; // 129
  constexpr int WCHUNK = WPLANE * 4; // 512
  constexpr int G = 64;

  __shared__ __align__(16) hf alds[4 * PSTR * 8];
  __shared__ __align__(16) hf wlds[4 * WPSTR * 8];

  const int tid = threadIdx.x;
  const int wid = tid >> 6, lane = tid & 63, lg = lane >> 4, ln = lane & 15;
  const int n = blockIdx.z;
  const int r0 = blockIdx.x * PIXROWS;
  const int par = blockIdx.y;
  const int qq = par >> 1, pp = par & 1;
  const hf* wbase = wp + (size_t)par * (TAPS * NCH * COT * 32);   // 8192 per parity

  f32x4 acc[MFR][WPIX];
#pragma unroll
  for (int mf = 0; mf < MFR; ++mf)
#pragma unroll
    for (int pf = 0; pf < WPIX; ++pf) acc[mf][pf] = (f32x4){0.f, 0.f, 0.f, 0.f};

  for (int ks = 0; ks < NCH; ++ks) {
    __syncthreads();
    const int k0 = ks * 32;
    // activation staging (identical addressing to old mconv GEOM==2/else branch)
    for (int cidx = tid; cidx < NCHUNK; cidx += 256) {
      const int s = cidx >> 2, p = cidx & 3;
      const int rs = s / TC, cs = s - rs * TC;
      const int ir = r0 - 1 + rs, ic = cs - 1;
      s8v v = (s8v){0, 0, 0, 0, 0, 0, 0, 0};
      if (((unsigned)ir < (unsigned)IMG) && ((unsigned)ic < (unsigned)IMG)) {
        const int ipix = ir * IMG + ic;
        v = *(const s8v*)(src1 + (((size_t)n * NPIX + ipix) * G + k0 + p * 8));
      }
      *(s8v*)(&alds[(size_t)(p * PSTR + s) * 8]) = v;
    }
    // weight staging (proven mask/shift machinery, COT=32)
    for (int widx = tid; widx < WCHUNK; widx += 256) {
      const int p = widx & 3;
      const int r = widx >> 2;            // r = t*COT + co
      const int co = r & (COT - 1);
      const int t = r >> 5;               // COT == 32
      const s8v wv = *(const s8v*)(wbase + (((size_t)(t * NCH + ks) * COT + co) * 32 + p * 8));
      *(s8v*)(&wlds[(size_t)(p * WPSTR + r) * 8]) = wv;
    }
    __syncthreads();
#pragma unroll
    for (int t = 0; t < TAPS; ++t) {
      const int dh = qq + (t >> 1) - 1;
      const int dw = pp + (t & 1) - 1;
      h8v afr[MFR];
#pragma unroll
      for (int mf = 0; mf < MFR; ++mf)
        afr[mf] = *(const h8v*)(&wlds[(size_t)(lg * WPSTR + t * COT + mf * 16 + ln) * 8]);
#pragma unroll
      for (int pf = 0; pf < WPIX; ++pf) {
        const int pl = wid * (WPIX * 16) + pf * 16 + ln;
        const int rL = pl / IMG, c = pl - rL * IMG;
        const int slot = (rL + dh + 1) * TC + (c + dw + 1);
        const h8v bfr = *(const h8v*)(&alds[(size_t)(lg * PSTR + slot) * 8]);
#pragma unroll
        for (int mf = 0; mf < MFR; ++mf)
          acc[mf][pf] = __builtin_amdgcn_mfma_f32_16x16x32_f16(afr[mf], bfr, acc[mf][pf], 0, 0, 0);
      }
    }
  }

  // epilogue: raw store (parity-interleaved 64x64 output) + BN stats
#pragma unroll
  for (int mf = 0; mf < MFR; ++mf) {
#pragma unroll
    for (int pf = 0; pf < WPIX; ++pf) {
      const int pl = wid * (WPIX * 16) + pf * 16 + ln;
      const int rL = pl / IMG, c = pl - rL * IMG;
      const int opix = (2 * (r0 + rL) + qq) * 64 + 2 * c + pp;
      ushort4 st;
      st.x = f2h_bits(acc[mf][pf][0]); st.y = f2h_bits(acc[mf][pf][1]);
      st.z = f2h_bits(acc[mf][pf][2]); st.w = f2h_bits(acc[mf][pf][3]);
      *reinterpret_cast<ushort4*>(outB + ((size_t)n * 4096 + opix) * 32 + mf * 16 + lg * 4) = st;
    }
  }
  __syncthreads();
  float* sl = (float*)alds;
#pragma unroll
  for (int mf = 0; mf < MFR; ++mf) {
#pragma unroll
    for (int rg = 0; rg < 4; ++rg) {
      float s = 0.f, q2 = 0.f;
#pragma unroll
      for (int pf = 0; pf < WPIX; ++pf) {
        const float v = acc[mf][pf][rg];
        s += v; q2 += v * v;
      }
#pragma unroll
      for (int o = 1; o < 16; o <<= 1) { s += __shfl_xor(s, o); q2 += __shfl_xor(q2, o); }
      if (ln == 0) {
        const int cl = mf * 16 + lg * 4 + rg;
        sl[(wid * MFR * 16 + cl) * 2 + 0] = s;
        sl[(wid * MFR * 16 + cl) * 2 + 1] = q2;
      }
    }
  }
  __syncthreads();
  for (int i = tid; i < MFR * 16 * 2; i += 256) {
    const int cl = i >> 1, stt = i & 1;
    float tot = 0.f;
#pragma unroll
    for (int w = 0; w < 4; ++w) tot += sl[(w * MFR * 16 + cl) * 2 + stt];
    atomicAdd(&statL[2 * cl + stt], tot);
  }
}

// ---------------------------------------------------------------- BN finalize
__global__ void bnfin_kernel(float* __restrict__ statL, const float* __restrict__ g,
                             const float* __restrict__ bt, int C, float invCnt) {
  const int c = threadIdx.x;
  if (c < C) {
    const float m = statL[2 * c] * invCnt;
    const float var = statL[2 * c + 1] * invCnt - m * m;
    const float sc = g[c] * rsqrtf(var + 1e-5f);
    statL[256 + c] = sc;
    statL[384 + c] = bt[c] - m * sc;
  }
}

// ---------------------------------------------------------------- in-place BN+ReLU
template <int G8>
__global__ __launch_bounds__(256) void norm_ip(hf* __restrict__ x,
                                               const float* __restrict__ statL, long nch) {
  for (long i = (long)blockIdx.x * 256 + threadIdx.x; i < nch; i += (long)gridDim.x * 256) {
    const int ci8 = (int)(i % G8);
    s8v v = *(s8v*)(x + i * 8);
    const f32x4 scA = *(const f32x4*)(statL + 256 + ci8 * 8);
    const f32x4 scB = *(const f32x4*)(statL + 256 + ci8 * 8 + 4);
    const f32x4 shA = *(const f32x4*)(statL + 384 + ci8 * 8);
    const f32x4 shB = *(const f32x4*)(statL + 384 + ci8 * 8 + 4);
    s8v o;
#pragma unroll
    for (int j = 0; j < 8; ++j) {
      const float sc = (j < 4) ? scA[j] : scB[j - 4];
      const float sh = (j < 4) ? shA[j] : shB[j - 4];
      const float f = fmaxf(h2f_bits((unsigned short)v[j]) * sc + sh, 0.f);
      o[j] = (short)f2h_bits(f);
    }
    *(s8v*)(x + i * 8) = o;
  }
}

// ---------------------------------------------------------------- conv5 (CO=1) on VALU
__global__ __launch_bounds__(256) void conv5_kernel(
    const hf* __restrict__ xd, const float* __restrict__ w5, const float* __restrict__ b5,
    float* __restrict__ outp) {
  const int gid = blockIdx.x * 256 + threadIdx.x;  // 162*4096
  const int n = gid >> 12, pix = gid & 4095;
  const int b = n / 81, ij = n - b * 81;
  const int oh = pix >> 6, ow = pix & 63;
  float acc = b5[0];
#pragma unroll
  for (int kh = 0; kh < 3; ++kh) {
    const int ih = oh + kh - 1;
#pragma unroll
    for (int kw = 0; kw < 3; ++kw) {
      const int iw = ow + kw - 1;
      if (((unsigned)ih < 64u) && ((unsigned)iw < 64u)) {
        const hf* xp = xd + ((size_t)n * 4096 + ih * 64 + iw) * 32;
#pragma unroll
        for (int cq = 0; cq < 4; ++cq) {
          const h8v v = *(const h8v*)(xp + cq * 8);
#pragma unroll
          for (int j = 0; j < 8; ++j)
            acc += (float)v[j] * w5[(cq * 8 + j) * 9 + kh * 3 + kw];
        }
      }
    }
  }
  outp[((size_t)(b * 113 + ij)) * 4096 + pix] = acc;
}

// ---------------------------------------------------------------- DAP softmax
__global__ __launch_bounds__(64) void softmax_kernel(
    const float* __restrict__ outp, const float* __restrict__ dapw, float* __restrict__ score) {
  __shared__ float cb[64 * 81];
  __shared__ float sb[64 * 81];
  const int t = threadIdx.x;
  const int gid = blockIdx.x * 64 + t;
  const int b = gid >> 12, hw = gid & 4095;
  for (int d = 0; d < 81; ++d)
    cb[t * 81 + d] = outp[((size_t)(b * 113 + d)) * 4096 + hw];
  float smax = -1e30f;
  for (int o = 0; o < 81; ++o) {
    float s = 0.f;
    const float* dr = dapw + o * 81;
    for (int d = 0; d < 81; ++d) s += dr[d] * cb[t * 81 + d];
    sb[t * 81 + o] = s;
    smax = fmaxf(smax, s);
  }
  float sum = 0.f;
  for (int o = 0; o < 81; ++o) {
    const float e = __expf(sb[t * 81 + o] - smax);
    sb[t * 81 + o] = e;
    sum += e;
  }
  const float inv = 1.f / sum;
  for (int o = 0; o < 81; ++o)
    score[((size_t)(b * 81 + o)) * 4096 + hw] = sb[t * 81 + o] * inv;
}

// ---------------------------------------------------------------- emb reduce
__global__ __launch_bounds__(256) void emb_kernel(
    const float* __restrict__ score, const hf* __restrict__ e3, float* __restrict__ outp) {
  const int idx = blockIdx.x * 256 + threadIdx.x;  // 2*32*4096
  const int b = idx >> 17, r = idx & 131071, m = r >> 12, hw = r & 4095;
  float acc = 0.f;
  for (int d = 0; d < 81; ++d) {
    const float sc = score[((size_t)(b * 81 + d)) * 4096 + hw];
    acc += sc * (float)e3[(((size_t)(b * 81 + d)) * 4096 + hw) * 32 + m];
  }
  outp[((size_t)(b * 113 + 81 + m)) * 4096 + hw] = acc;
}

// ======================================================================
extern "C" void kernel_launch(void* const* d_in, const int* in_sizes, int n_in,
                              void* d_out, int out_size, void* d_ws, size_t ws_size,
                              hipStream_t stream) {
  const float* f1     = (const float*)d_in[0];
  const float* f2     = (const float*)d_in[1];
  const float* coords = (const float*)d_in[2];
  const float* w1     = (const float*)d_in[3];
  const float* g1     = (const float*)d_in[4];
  const float* bb1    = (const float*)d_in[5];
  const float* w2     = (const float*)d_in[6];
  const float* g2     = (const float*)d_in[7];
  const float* bb2    = (const float*)d_in[8];
  const float* w3     = (const float*)d_in[9];
  const float* g3     = (const float*)d_in[10];
  const float* bb3    = (const float*)d_in[11];
  const float* w4     = (const float*)d_in[12];
  const float* g4     = (const float*)d_in[13];
  const float* bb4    = (const float*)d_in[14];
  const float* wdcv   = (const float*)d_in[15];
  const float* gd     = (const float*)d_in[16];
  const float* bbd    = (const float*)d_in[17];
  const float* w5     = (const float*)d_in[18];
  const float* b5     = (const float*)d_in[19];
  const float* e1w    = (const float*)d_in[20];
  const float* e1bi   = (const float*)d_in[21];
  const float* e2w    = (const float*)d_in[22];
  const float* e2bi   = (const float*)d_in[23];
  const float* e3w    = (const float*)d_in[24];
  const float* e3bi   = (const float*)d_in[25];
  const float* dapw   = (const float*)d_in[26];
  float* out = (float*)d_out;
  char* ws = (char*)d_ws;

  hf* sA  = (hf*)(ws + OFF_SA);
  hf* f2s = (hf*)(ws + OFF_F2S);
  hf* be1 = (hf*)(ws + OFF_E1);
  hf* be2 = (hf*)(ws + OFF_E2);
  hf* be3 = (hf*)(ws + OFF_E3);
  hf* x1  = (hf*)(ws + OFF_X1);
  hf* x2  = (hf*)(ws + OFF_X2);
  hf* x3  = (hf*)(ws + OFF_X3);
  hf* x4  = (hf*)(ws + OFF_X4);
  hf* xd  = (hf*)(ws + OFF_XD);
  float* score = (float*)(ws + OFF_SCORE);
  float* stats = (float*)(ws + OFF_STATS);
  hf* wc1 = (hf*)(ws + OFF_WC1);
  hf* wc2 = (hf*)(ws + OFF_WC2);
  hf* wc3 = (hf*)(ws + OFF_WC3);
  hf* wc4 = (hf*)(ws + OFF_WC4);
  hf* wdc = (hf*)(ws + OFF_WDC);
  hf* we1 = (hf*)(ws + OFF_WE1);
  hf* we2 = (hf*)(ws + OFF_WE2);
  hf* we3 = (hf*)(ws + OFF_WE3);
  float* dt1 = (float*)(ws + OFF_DT1);
  float* dtE = (float*)(ws + OFF_DTE);
  float* f2clf = (float*)(ws + OFF_F2CLF);

  hipMemsetAsync(stats, 0, 2560 * sizeof(float), stream);

  // weight prepacks (round-14 anchor + ONE change: wdc now parity-major dense)
  prepack<<<216, 256, 0, stream>>>(w1,   wc1, 96, 96, 64, 66, 64, 9);
  prepack<<<432, 256, 0, stream>>>(w2,   wc2, 128, 128, 96, 96, 96, 9);
  prepack2<<<576, 256, 0, stream>>>(w3,  wc3, 128, 128, 4);
  prepack2<<<288, 256, 0, stream>>>(w4,  wc4, 64, 128, 4);
  prepack2d<<<128, 256, 0, stream>>>(wdcv, wdc);
  prepack<<<12,  256, 0, stream>>>(e1w,  we1, 48, 48, 64, 66, 64, 1);
  prepack<<<16,  256, 0, stream>>>(e2w,  we2, 64, 64, 48, 48, 64, 1);
  prepack<<<8,   256, 0, stream>>>(e3w,  we3, 32, 32, 64, 64, 64, 1);
  dtab1_kernel<<<7, 256, 0, stream>>>(w1, dt1);
  dtabE_kernel<<<1, 96, 0, stream>>>(e1w, dtE);

  // inputs (f2 interpolated in fp32)
  packf1<<<32, 256, 0, stream>>>(f1, sA);
  packf2f32<<<32, 256, 0, stream>>>(f2, f2clf);
  sample2<<<2592, 256, 0, stream>>>(f2clf, coords, f2s);

  // embedding branch (DIRECT 1x1 convs)
  mconv<3, 1, true, 32, 64, 48, 48, 3, 64, 64, 4, 4, true>
      <<<dim3(16, 1, 162), 256, 0, stream>>>(f2s, sA, we1, e1bi, dtE, nullptr, be1, nullptr);
  mconv<3, 1, false, 48, 64, 64, 64, 4, 64, 64, 4, 4, false>
      <<<dim3(16, 1, 162), 256, 0, stream>>>(be1, nullptr, we2, e2bi, nullptr, nullptr, be2, nullptr);
  mconv<3, 2, false, 64, 64, 32, 32, 2, 64, 64, 4, 4, false>
      <<<dim3(16, 1, 162), 256, 0, stream>>>(be2, nullptr, we3, e3bi, nullptr, nullptr, be3, nullptr);

  // conv1: old proven path
  mconv<0, 0, true, 32, 64, 96, 96, 3, 64, 64, 4, 4, true>
      <<<dim3(16, 2, 162), 256, 0, stream>>>(f2s, sA, wc1, nullptr, dt1, stats + 0, x1, nullptr);
  bnfin_kernel<<<1, 128, 0, stream>>>(stats + 0, g1, bb1, 96, 1.f / 663552.f);
  norm_ip<12><<<2048, 256, 0, stream>>>(x1, stats + 0, 7962624L);

  // conv2: old proven path
  mconv<1, 0, false, 96, 96, 128, 128, 4, 32, 64, 4, 2, false>
      <<<dim3(8, 2, 162), 256, 0, stream>>>(x1, nullptr, wc2, nullptr, nullptr, stats + 512, x2, nullptr);
  bnfin_kernel<<<1, 128, 0, stream>>>(stats + 512, g2, bb2, 128, 1.f / 165888.f);
  norm_ip<16><<<2048, 256, 0, stream>>>(x2, stats + 512, 2654208L);

  // conv3: proven weight-LDS path
  mconv2<128, 128, 4, 4, 2>
      <<<dim3(8, 2, 162), 256, 0, stream>>>(x2, wc3, stats + 1024, x3);
  bnfin_kernel<<<1, 128, 0, stream>>>(stats + 1024, g3, bb3, 128, 1.f / 165888.f);
  norm_ip<16><<<2048, 256, 0, stream>>>(x3, stats + 1024, 2654208L);

  // conv4: proven weight-LDS path (COP=64)
  mconv2<128, 64, 4, 4, 2>
      <<<dim3(8, 1, 162), 256, 0, stream>>>(x3, wc4, stats + 1536, x4);
  bnfin_kernel<<<1, 128, 0, stream>>>(stats + 1536, g4, bb4, 64, 1.f / 165888.f);
  norm_ip<8><<<2048, 256, 0, stream>>>(x4, stats + 1536, 1327104L);

  // deconv: THE single new change — weight-LDS (single-source, proven machinery)
  mconv2d<<<dim3(4, 4, 162), 256, 0, stream>>>(x4, wdc, stats + 2048, xd);
  bnfin_kernel<<<1, 128, 0, stream>>>(stats + 2048, gd, bbd, 32, 1.f / 663552.f);
  norm_ip<4><<<2048, 256, 0, stream>>>(xd, stats + 2048, 2654208L);

  // conv5 on VALU (reads normalized xd, fp32 weights) -> cost planes of out
  conv5_kernel<<<2592, 256, 0, stream>>>(xd, w5, b5, out);

  // DAP softmax + embedding reduction
  softmax_kernel<<<128, 64, 0, stream>>>(out, dapw, score);
  emb_kernel<<<1024, 256, 0, stream>>>(score, be3, out);

  (void)in_sizes; (void)n_in; (void)out_size; (void)ws_size;
}

// Round 20
// 951.091 us; speedup vs baseline: 1.1192x; 1.0350x over previous
//
#include <hip/hip_runtime.h>
#include <hip/hip_bf16.h>

typedef _Float16 hf;
typedef short    s8v  __attribute__((ext_vector_type(8)));
typedef _Float16 h8v  __attribute__((ext_vector_type(8)));
typedef float    f32x4 __attribute__((ext_vector_type(4)));

#define DEVINL __device__ __forceinline__

DEVINL unsigned short f2h_bits(float f) { return __builtin_bit_cast(unsigned short, (hf)f); }
DEVINL float h2f_bits(unsigned short u) { return (float)__builtin_bit_cast(hf, u); }

// ---------------------------------------------------------------- arena
static constexpr size_t OFF_SA    = 0;
static constexpr size_t OFF_F2S   = 524288;
static constexpr size_t OFF_E1    = 42991616;
static constexpr size_t OFF_E2    = 106692608;
static constexpr size_t OFF_E3    = 42991616;
static constexpr size_t OFF_X1    = 85458944;
static constexpr size_t OFF_X2    = 524288;
static constexpr size_t OFF_X3    = 85458944;
static constexpr size_t OFF_X4    = 524288;
static constexpr size_t OFF_XD    = 127926272;
static constexpr size_t OFF_SCORE = 524288;
static constexpr size_t OFF_STATS = 212860928;
static constexpr size_t OFF_WC1   = 212871168;
static constexpr size_t OFF_WC2   = 212981760;
static constexpr size_t OFF_WC3   = 213202944;
static constexpr size_t OFF_WC4   = 213497856;
static constexpr size_t OFF_WDC   = 213645312;
static constexpr size_t OFF_WE1   = 213720064;
static constexpr size_t OFF_WE2   = 213726208;
static constexpr size_t OFF_WE3   = 213734400;
static constexpr size_t OFF_DT1   = 213738496;
static constexpr size_t OFF_DTE   = 213745408;
static constexpr size_t OFF_F2CLF = 213746048;

// ---------------------------------------------------------------- prepack (old [t][co][KP])
__global__ void prepack(const float* __restrict__ src, hf* __restrict__ dst,
                        int COr, int COP, int CINr, int CINsrc, int KP, int TAPS) {
  const int idx = blockIdx.x * 256 + threadIdx.x;
  const int total = TAPS * COP * KP;
  if (idx >= total) return;
  const int k = idx % KP;
  const int r = idx / KP;
  const int co = r % COP;
  const int t = r / COP;
  float v = 0.f;
  if (co < COr && k < CINr) v = src[((size_t)co * CINsrc + k) * TAPS + t];
  dst[idx] = (hf)v;
}

// dense layout: dst[t][ks][co][32]
__global__ void prepack2(const float* __restrict__ src, hf* __restrict__ dst,
                         int COP, int CIN, int NCHn) {
  const int idx = blockIdx.x * 256 + threadIdx.x;
  const int total = 9 * NCHn * COP * 32;
  if (idx >= total) return;
  const int kk = idx & 31;
  const int r = idx >> 5;
  const int co = r % COP;
  const int r2 = r / COP;
  const int ks = r2 % NCHn;
  const int t = r2 / NCHn;
  dst[idx] = (hf)src[((size_t)co * CIN + ks * 32 + kk) * 9 + t];
}

// deconv parity-major dense: dst[par][tt][ks][co][32]
__global__ void prepack2d(const float* __restrict__ src, hf* __restrict__ dst) {
  const int idx = blockIdx.x * 256 + threadIdx.x;  // 32768
  if (idx >= 32768) return;
  const int kk = idx & 31;
  const int co = (idx >> 5) & 31;
  const int ks = (idx >> 10) & 1;
  const int tt = (idx >> 11) & 3;
  const int par = idx >> 13;
  const int qq = par >> 1, pp = par & 1;
  const int a = tt >> 1, b = tt & 1;
  dst[idx] = (hf)src[(((size_t)co * 64 + ks * 32 + kk) * 4 + (qq + 2 * a)) * 4 + (pp + 2 * b)];
}

__global__ void dtab1_kernel(const float* __restrict__ w1, float* __restrict__ dtab) {
  const int idx = blockIdx.x * 256 + threadIdx.x;  // 96*9*2
  if (idx >= 96 * 9 * 2) return;
  const int c = idx & 1;
  const int r = idx >> 1;
  const int pat = r % 9;
  const int co = r / 9;
  const int rc = pat / 3, cc = pat % 3;
  const int kh0 = (rc == 0) ? 1 : 0, kh1 = (rc == 2) ? 1 : 2;
  const int kw0 = (cc == 0) ? 1 : 0, kw1 = (cc == 2) ? 1 : 2;
  float s = 0.f;
  for (int kh = kh0; kh <= kh1; ++kh)
    for (int kw = kw0; kw <= kw1; ++kw)
      s += w1[((size_t)(co * 66 + 64 + c) * 3 + kh) * 3 + kw];
  dtab[(co * 9 + pat) * 2 + c] = s;
}

__global__ void dtabE_kernel(const float* __restrict__ e1w, float* __restrict__ dtE) {
  const int co = threadIdx.x;
  if (co < 48) {
    dtE[co * 2 + 0] = e1w[co * 66 + 64];
    dtE[co * 2 + 1] = e1w[co * 66 + 65];
  }
}

// ---------------------------------------------------------------- input builders
__global__ __launch_bounds__(256) void packf1(const float* __restrict__ f1, hf* __restrict__ sA) {
  const int gid = blockIdx.x * 256 + threadIdx.x;  // 2*4096
  const int b = gid >> 12, pix = gid & 4095;
  unsigned words[16];
#pragma unroll
  for (int c = 0; c < 32; c += 2) {
    const float v0 = f1[((size_t)(b * 32 + c)) * 4096 + pix];
    const float v1 = f1[((size_t)(b * 32 + c + 1)) * 4096 + pix];
    words[c >> 1] = (unsigned)f2h_bits(v0) | ((unsigned)f2h_bits(v1) << 16);
  }
  uint4* dst = (uint4*)(sA + (size_t)gid * 32);
#pragma unroll
  for (int i = 0; i < 4; ++i)
    dst[i] = make_uint4(words[4 * i], words[4 * i + 1], words[4 * i + 2], words[4 * i + 3]);
}

__global__ __launch_bounds__(256) void packf2f32(const float* __restrict__ f2,
                                                 float* __restrict__ dst) {
  const int gid = blockIdx.x * 256 + threadIdx.x;  // 2*4096
  const int b = gid >> 12, pix = gid & 4095;
  float* op = dst + (size_t)gid * 32;
#pragma unroll
  for (int c = 0; c < 32; c += 4) {
    float4 v;
    v.x = f2[((size_t)(b * 32 + c + 0)) * 4096 + pix];
    v.y = f2[((size_t)(b * 32 + c + 1)) * 4096 + pix];
    v.z = f2[((size_t)(b * 32 + c + 2)) * 4096 + pix];
    v.w = f2[((size_t)(b * 32 + c + 3)) * 4096 + pix];
    *(float4*)(op + c) = v;
  }
}

__global__ __launch_bounds__(256) void sample2(const float* __restrict__ f2clf,
                                               const float* __restrict__ coords,
                                               hf* __restrict__ f2s) {
  const int gid = blockIdx.x * 256 + threadIdx.x;  // 162*4096
  const int n = gid >> 12, pix = gid & 4095;
  const int b = n / 81, ij = n - b * 81;
  const float di = (float)(ij / 9) - 4.f, dj = (float)(ij % 9) - 4.f;
  const float x = coords[((size_t)(b * 2 + 0)) * 4096 + pix] + di;
  const float y = coords[((size_t)(b * 2 + 1)) * 4096 + pix] + dj;
  const float x0f = floorf(x), y0f = floorf(y);
  const int x0 = (int)x0f, y0 = (int)y0f;
  const float wx1 = x - x0f, wx0 = 1.f - wx1;
  const float wy1 = y - y0f, wy0 = 1.f - wy1;
  const bool vx0 = (unsigned)x0 < 64u, vx1 = (unsigned)(x0 + 1) < 64u;
  const bool vy0 = (unsigned)y0 < 64u, vy1 = (unsigned)(y0 + 1) < 64u;
  const int x0c = min(max(x0, 0), 63), x1c = min(max(x0 + 1, 0), 63);
  const int y0c = min(max(y0, 0), 63), y1c = min(max(y0 + 1, 0), 63);
  const float w00 = (vy0 && vx0) ? wy0 * wx0 : 0.f;
  const float w01 = (vy0 && vx1) ? wy0 * wx1 : 0.f;
  const float w10 = (vy1 && vx0) ? wy1 * wx0 : 0.f;
  const float w11 = (vy1 && vx1) ? wy1 * wx1 : 0.f;
  const float* fb = f2clf + (size_t)b * 4096 * 32;
  const float* p00 = fb + (size_t)(y0c * 64 + x0c) * 32;
  const float* p01 = fb + (size_t)(y0c * 64 + x1c) * 32;
  const float* p10 = fb + (size_t)(y1c * 64 + x0c) * 32;
  const float* p11 = fb + (size_t)(y1c * 64 + x1c) * 32;
  unsigned words[16];
#pragma unroll
  for (int ch = 0; ch < 16; ++ch) {
    const float2 a  = *(const float2*)(p00 + ch * 2);
    const float2 bb = *(const float2*)(p01 + ch * 2);
    const float2 c  = *(const float2*)(p10 + ch * 2);
    const float2 d  = *(const float2*)(p11 + ch * 2);
    const float v0 = w00 * a.x + w01 * bb.x + w10 * c.x + w11 * d.x;
    const float v1 = w00 * a.y + w01 * bb.y + w10 * c.y + w11 * d.y;
    words[ch] = (unsigned)f2h_bits(v0) | ((unsigned)f2h_bits(v1) << 16);
  }
  uint4* dst = (uint4*)(f2s + (size_t)gid * 32);
#pragma unroll
  for (int i = 0; i < 4; ++i)
    dst[i] = make_uint4(words[4 * i], words[4 * i + 1], words[4 * i + 2], words[4 * i + 3]);
}

// ---------------------------------------------------------------- BNIN helper
DEVINL s8v bnin_apply(s8v v, const float* bnst, int gci) {
  const f32x4 scA = *(const f32x4*)(bnst + 256 + gci);
  const f32x4 scB = *(const f32x4*)(bnst + 256 + gci + 4);
  const f32x4 shA = *(const f32x4*)(bnst + 384 + gci);
  const f32x4 shB = *(const f32x4*)(bnst + 384 + gci + 4);
  h8v h = __builtin_bit_cast(h8v, v);
#pragma unroll
  for (int jj = 0; jj < 8; ++jj) {
    const float sc = (jj < 4) ? scA[jj] : scB[jj - 4];
    const float sh = (jj < 4) ? shA[jj] : shB[jj - 4];
    h[jj] = (hf)fmaxf((float)h[jj] * sc + sh, 0.f);
  }
  return __builtin_bit_cast(s8v, h);
}

// ---------------------------------------------------------------- MFMA conv template (round-11 path + BNIN)
template <int GEOM, int EPI, bool DUAL, bool BNIN, int G, int KP, int COP, int COB, int MFR,
          int IMGO, int IMGI, int PIXROWS, int WPIX, bool DELTA>
__global__ __launch_bounds__(256) void mconv(
    const hf* __restrict__ src1, const hf* __restrict__ src0,
    const hf* __restrict__ wp, const float* __restrict__ bias,
    const float* __restrict__ dtab, float* __restrict__ statL,
    const float* __restrict__ bnst,
    hf* __restrict__ outB, float* __restrict__ outF) {
  constexpr bool DIRECT = (GEOM == 3);
  constexpr int TAPS  = (GEOM == 2) ? 4 : (GEOM == 3) ? 1 : 9;
  constexpr int TR    = (GEOM == 1) ? (2 * PIXROWS + 1) : (GEOM == 3) ? 1 : (PIXROWS + 2);
  constexpr int TC    = (GEOM == 1) ? 65 : (GEOM == 3) ? 1 : (IMGI + 2);
  constexpr int NSLOT = TR * TC;
  constexpr int PSTR  = NSLOT + 1;
  constexpr int NCH   = KP / 32;
  constexpr int NPIXI = IMGI * IMGI;
  constexpr int NPIXO = (GEOM == 2) ? 4096 : IMGO * IMGO;
  constexpr int NCHUNK = NSLOT * 4;
  constexpr int CPT   = (NCHUNK + 255) / 256;
  constexpr int LDSE  = DIRECT ? 64 : 4 * PSTR * 8;

  __shared__ __align__(16) hf lds[LDSE];

  const int tid = threadIdx.x;
  const int wid = tid >> 6, lane = tid & 63, lg = lane >> 4, ln = lane & 15;
  const int n = blockIdx.z, b = n / 81, ij = n - b * 81;
  const int r0 = blockIdx.x * PIXROWS;
  const int qq = (GEOM == 2) ? (int)(blockIdx.y >> 1) : 0;
  const int pp = (GEOM == 2) ? (int)(blockIdx.y & 1) : 0;
  const int co0 = (GEOM == 2) ? 0 : (int)blockIdx.y * (MFR * 16);

  f32x4 acc[MFR][WPIX];
#pragma unroll
  for (int mf = 0; mf < MFR; ++mf)
#pragma unroll
    for (int pf = 0; pf < WPIX; ++pf) acc[mf][pf] = (f32x4){0.f, 0.f, 0.f, 0.f};

  if constexpr (DIRECT) {
#pragma unroll
    for (int ch = 0; ch < NCH; ++ch) {
      const int k0 = ch * 32;
      h8v afr[MFR];
#pragma unroll
      for (int mf = 0; mf < MFR; ++mf)
        afr[mf] = *(const h8v*)(wp + ((size_t)(co0 + mf * 16 + ln)) * KP + k0 + lg * 8);
#pragma unroll
      for (int pf = 0; pf < WPIX; ++pf) {
        const int pix = r0 * IMGO + wid * (WPIX * 16) + pf * 16 + ln;
        h8v bfr = (h8v){0, 0, 0, 0, 0, 0, 0, 0};
        if (DUAL) {
          bfr = (ch == 0)
              ? *(const h8v*)(src0 + (((size_t)b * NPIXI + pix) * 32 + lg * 8))
              : *(const h8v*)(src1 + (((size_t)n * NPIXI + pix) * 32 + lg * 8));
        } else {
          const int gci = k0 + lg * 8;
          if (gci < G)
            bfr = *(const h8v*)(src1 + (((size_t)n * NPIXI + pix) * G + gci));
        }
#pragma unroll
        for (int mf = 0; mf < MFR; ++mf)
          acc[mf][pf] = __builtin_amdgcn_mfma_f32_16x16x32_f16(afr[mf], bfr, acc[mf][pf], 0, 0, 0);
      }
    }
  } else {
    s8v rbuf[CPT];
    auto stage_load = [&](int k0) {
#pragma unroll
      for (int j = 0; j < CPT; ++j) {
        const int cidx = tid + j * 256;
        s8v v = (s8v){0, 0, 0, 0, 0, 0, 0, 0};
        if (cidx < NCHUNK) {
          const int s = cidx >> 2, p = cidx & 3;
          const int rs = s / TC, cs = s - rs * TC;
          int ir, ic;
          if (GEOM == 1) { ir = 2 * r0 - 1 + rs; ic = (cs < 32) ? 2 * cs : 2 * (cs - 32) - 1; }
          else           { ir = r0 - 1 + rs;     ic = cs - 1; }
          const int gci = k0 + p * 8;
          if (((unsigned)ir < (unsigned)IMGI) && ((unsigned)ic < (unsigned)IMGI)) {
            const int ipix = ir * IMGI + ic;
            if (DUAL) {
              if (gci < 32)
                v = *(const s8v*)(src0 + (((size_t)b * NPIXI + ipix) * 32 + gci));
              else
                v = *(const s8v*)(src1 + (((size_t)n * NPIXI + ipix) * 32 + (gci - 32)));
            } else if (gci < G) {
              v = *(const s8v*)(src1 + (((size_t)n * NPIXI + ipix) * G + gci));
              if constexpr (BNIN) v = bnin_apply(v, bnst, gci);
            }
          }
        }
        rbuf[j] = v;
      }
    };
    auto stage_write = [&]() {
#pragma unroll
      for (int j = 0; j < CPT; ++j) {
        const int cidx = tid + j * 256;
        if (cidx < NCHUNK) {
          const int s = cidx >> 2, p = cidx & 3;
          *(s8v*)(&lds[(size_t)(p * PSTR + s) * 8]) = rbuf[j];
        }
      }
    };

    stage_load(0);
#pragma unroll
    for (int ch = 0; ch < NCH; ++ch) {
      if (ch > 0) __syncthreads();
      stage_write();
      __syncthreads();
      if (ch + 1 < NCH) stage_load((ch + 1) * 32);
      const int k0 = ch * 32;
#pragma unroll
      for (int t = 0; t < TAPS; ++t) {
        int dh, dw, wt, kh = 0, kw = 0;
        if (GEOM == 2) {
          dh = qq + (t >> 1) - 1; dw = pp + (t & 1) - 1;
          wt = (qq + 2 * (t >> 1)) * 4 + (pp + 2 * (t & 1));
        } else { kh = t / 3; kw = t % 3; dh = kh - 1; dw = kw - 1; wt = t; }
        h8v afr[MFR];
#pragma unroll
        for (int mf = 0; mf < MFR; ++mf)
          afr[mf] = *(const h8v*)(wp + ((size_t)(wt * COP + co0 + mf * 16 + ln)) * KP + k0 + lg * 8);
#pragma unroll
        for (int pf = 0; pf < WPIX; ++pf) {
          const int pl = wid * (WPIX * 16) + pf * 16 + ln;
          const int rL = pl / IMGO, c = pl - rL * IMGO;
          int slot;
          if (GEOM == 1) slot = (2 * rL + kh) * 65 + ((kw == 1) ? c : (32 + c + (kw >> 1)));
          else           slot = (rL + dh + 1) * TC + (c + dw + 1);
          const h8v bfr = *(const h8v*)(&lds[(size_t)(lg * PSTR + slot) * 8]);
#pragma unroll
          for (int mf = 0; mf < MFR; ++mf)
            acc[mf][pf] = __builtin_amdgcn_mfma_f32_16x16x32_f16(afr[mf], bfr, acc[mf][pf], 0, 0, 0);
        }
      }
    }
  }

  const float di = (float)(ij / 9) - 4.f, dj = (float)(ij % 9) - 4.f;

  {
#pragma unroll
    for (int mf = 0; mf < MFR; ++mf) {
#pragma unroll
      for (int pf = 0; pf < WPIX; ++pf) {
        const int pl = wid * (WPIX * 16) + pf * 16 + ln;
        const int rL = pl / IMGO, c = pl - rL * IMGO;
        int opix;
        if constexpr (GEOM == 2) opix = (2 * (r0 + rL) + qq) * 64 + 2 * c + pp;
        else opix = (r0 + rL) * IMGO + c;
        if constexpr (DELTA && EPI == 0) {
          const int oh = r0 + rL;
          const int rc = (oh == 0) ? 0 : ((oh == IMGO - 1) ? 2 : 1);
          const int cc = (c == 0) ? 0 : ((c == IMGO - 1) ? 2 : 1);
#pragma unroll
          for (int rg = 0; rg < 4; ++rg) {
            const int co = co0 + mf * 16 + lg * 4 + rg;
            acc[mf][pf][rg] += di * dtab[(co * 9 + rc * 3 + cc) * 2 + 0] +
                               dj * dtab[(co * 9 + rc * 3 + cc) * 2 + 1];
          }
        }
        if constexpr (DELTA && EPI == 1) {
#pragma unroll
          for (int rg = 0; rg < 4; ++rg) {
            const int co = co0 + mf * 16 + lg * 4 + rg;
            acc[mf][pf][rg] += di * dtab[co * 2] + dj * dtab[co * 2 + 1];
          }
        }
        if constexpr (EPI == 1 || EPI == 2) {
          const float4 bv = *(const float4*)(bias + co0 + mf * 16 + lg * 4);
          acc[mf][pf][0] += bv.x; acc[mf][pf][1] += bv.y;
          acc[mf][pf][2] += bv.z; acc[mf][pf][3] += bv.w;
          if constexpr (EPI == 1) {
#pragma unroll
            for (int rg = 0; rg < 4; ++rg) acc[mf][pf][rg] = fmaxf(acc[mf][pf][rg], 0.f);
          }
        }
        ushort4 st;
        st.x = f2h_bits(acc[mf][pf][0]); st.y = f2h_bits(acc[mf][pf][1]);
        st.z = f2h_bits(acc[mf][pf][2]); st.w = f2h_bits(acc[mf][pf][3]);
        *reinterpret_cast<ushort4*>(outB + ((size_t)n * NPIXO + opix) * COB + co0 + mf * 16 + lg * 4) = st;
      }
    }
    if constexpr (EPI == 0) {
      __syncthreads();
      float* sl = (float*)lds;
#pragma unroll
      for (int mf = 0; mf < MFR; ++mf) {
#pragma unroll
        for (int rg = 0; rg < 4; ++rg) {
          float s = 0.f, q2 = 0.f;
#pragma unroll
          for (int pf = 0; pf < WPIX; ++pf) {
            const float v = acc[mf][pf][rg];
            s += v; q2 += v * v;
          }
#pragma unroll
          for (int o = 1; o < 16; o <<= 1) { s += __shfl_xor(s, o); q2 += __shfl_xor(q2, o); }
          if (ln == 0) {
            const int cl = mf * 16 + lg * 4 + rg;
            sl[(wid * MFR * 16 + cl) * 2 + 0] = s;
            sl[(wid * MFR * 16 + cl) * 2 + 1] = q2;
          }
        }
      }
      __syncthreads();
      for (int i = tid; i < MFR * 16 * 2; i += 256) {
        const int cl = i >> 1, stt = i & 1;
        float tot = 0.f;
#pragma unroll
        for (int w = 0; w < 4; ++w) tot += sl[(w * MFR * 16 + cl) * 2 + stt];
        atomicAdd(&statL[2 * (co0 + cl) + stt], tot);
      }
    }
  }
  (void)outF;
}

// ---------------------------------------------------------------- mconv2 (proven) + BNIN
template <int G, int COP, int MFR, int PIXROWS, int WPIX, bool BNIN>
__global__ __launch_bounds__(256) void mconv2(
    const hf* __restrict__ src1, const hf* __restrict__ wp,
    const float* __restrict__ bnst,
    float* __restrict__ statL, hf* __restrict__ outB) {
  constexpr int IMG = 32;
  constexpr int TAPS = 9;
  constexpr int TC = IMG + 2;
  constexpr int TR = PIXROWS + 2;
  constexpr int NSLOT = TR * TC;
  constexpr int PSTR = NSLOT + 1;
  constexpr int NCH = G / 32;
  constexpr int NPIX = IMG * IMG;
  constexpr int NCHUNK = NSLOT * 4;
  constexpr int COT = MFR * 16;      // 64
  constexpr int WPLANE = TAPS * COT;
  constexpr int WPSTR  = WPLANE + 1;
  constexpr int WCHUNK = WPLANE * 4;

  __shared__ __align__(16) hf alds[4 * PSTR * 8];
  __shared__ __align__(16) hf wlds[4 * WPSTR * 8];

  const int tid = threadIdx.x;
  const int wid = tid >> 6, lane = tid & 63, lg = lane >> 4, ln = lane & 15;
  const int n = blockIdx.z;
  const int r0 = blockIdx.x * PIXROWS;
  const int co0 = blockIdx.y * COT;

  f32x4 acc[MFR][WPIX];
#pragma unroll
  for (int mf = 0; mf < MFR; ++mf)
#pragma unroll
    for (int pf = 0; pf < WPIX; ++pf) acc[mf][pf] = (f32x4){0.f, 0.f, 0.f, 0.f};

  for (int ks = 0; ks < NCH; ++ks) {
    __syncthreads();
    for (int cidx = tid; cidx < NCHUNK; cidx += 256) {
      const int s = cidx >> 2, p = cidx & 3;
      const int rs = s / TC, cs = s - rs * TC;
      const int ir = r0 - 1 + rs, ic = cs - 1;
      s8v v = (s8v){0, 0, 0, 0, 0, 0, 0, 0};
      if (((unsigned)ir < (unsigned)IMG) && ((unsigned)ic < (unsigned)IMG)) {
        const int ipix = ir * IMG + ic;
        v = *(const s8v*)(src1 + (((size_t)n * NPIX + ipix) * G + ks * 32 + p * 8));
        if constexpr (BNIN) v = bnin_apply(v, bnst, ks * 32 + p * 8);
      }
      *(s8v*)(&alds[(size_t)(p * PSTR + s) * 8]) = v;
    }
    for (int widx = tid; widx < WCHUNK; widx += 256) {
      const int p = widx & 3;
      const int r = widx >> 2;
      const int co = r & (COT - 1);
      const int t = r >> 6;
      const s8v wv = *(const s8v*)(wp + (((size_t)(t * NCH + ks) * COP + co0 + co) * 32 + p * 8));
      *(s8v*)(&wlds[(size_t)(p * WPSTR + r) * 8]) = wv;
    }
    __syncthreads();
#pragma unroll
    for (int t = 0; t < TAPS; ++t) {
      const int kh = t / 3, kw = t % 3;
      const int dh = kh - 1, dw = kw - 1;
      h8v afr[MFR];
#pragma unroll
      for (int mf = 0; mf < MFR; ++mf)
        afr[mf] = *(const h8v*)(&wlds[(size_t)(lg * WPSTR + t * COT + mf * 16 + ln) * 8]);
#pragma unroll
      for (int pf = 0; pf < WPIX; ++pf) {
        const int pl = wid * (WPIX * 16) + pf * 16 + ln;
        const int rL = pl / IMG, c = pl - rL * IMG;
        const int slot = (rL + dh + 1) * TC + (c + dw + 1);
        const h8v bfr = *(const h8v*)(&alds[(size_t)(lg * PSTR + slot) * 8]);
#pragma unroll
        for (int mf = 0; mf < MFR; ++mf)
          acc[mf][pf] = __builtin_amdgcn_mfma_f32_16x16x32_f16(afr[mf], bfr, acc[mf][pf], 0, 0, 0);
      }
    }
  }

#pragma unroll
  for (int mf = 0; mf < MFR; ++mf) {
#pragma unroll
    for (int pf = 0; pf < WPIX; ++pf) {
      const int pl = wid * (WPIX * 16) + pf * 16 + ln;
      const int rL = pl / IMG, c = pl - rL * IMG;
      const int opix = (r0 + rL) * IMG + c;
      ushort4 st;
      st.x = f2h_bits(acc[mf][pf][0]); st.y = f2h_bits(acc[mf][pf][1]);
      st.z = f2h_bits(acc[mf][pf][2]); st.w = f2h_bits(acc[mf][pf][3]);
      *reinterpret_cast<ushort4*>(outB + ((size_t)n * NPIX + opix) * COP + co0 + mf * 16 + lg * 4) = st;
    }
  }
  __syncthreads();
  float* sl = (float*)alds;
#pragma unroll
  for (int mf = 0; mf < MFR; ++mf) {
#pragma unroll
    for (int rg = 0; rg < 4; ++rg) {
      float s = 0.f, q2 = 0.f;
#pragma unroll
      for (int pf = 0; pf < WPIX; ++pf) {
        const float v = acc[mf][pf][rg];
        s += v; q2 += v * v;
      }
#pragma unroll
      for (int o = 1; o < 16; o <<= 1) { s += __shfl_xor(s, o); q2 += __shfl_xor(q2, o); }
      if (ln == 0) {
        const int cl = mf * 16 + lg * 4 + rg;
        sl[(wid * MFR * 16 + cl) * 2 + 0] = s;
        sl[(wid * MFR * 16 + cl) * 2 + 1] = q2;
      }
    }
  }
  __syncthreads();
  for (int i = tid; i < MFR * 16 * 2; i += 256) {
    const int cl = i >> 1, stt = i & 1;
    float tot = 0.f;
#pragma unroll
    for (int w = 0; w < 4; ++w) tot += sl[(w * MFR * 16 + cl) * 2 + stt];
    atomicAdd(&statL[2 * (co0 + cl) + stt], tot);
  }
}

// ---------------------------------------------------------------- mconv2d: deconv weight-LDS + BNIN
__global__ __launch_bounds__(256) void mconv2d(
    const hf* __restrict__ src1, const hf* __restrict__ wp,
    const float* __restrict__ bnst,
    float* __restrict__ statL, hf* __restrict__ outB) {
  constexpr int IMG = 32;
  constexpr int TAPS = 4;
  constexpr int PIXROWS = 8;
  constexpr int WPIX = 4;
  constexpr int MFR = 2;
  constexpr int TC = IMG + 2;
  constexpr int TR = PIXROWS + 2;
  constexpr int NSLOT = TR * TC;
  constexpr int PSTR = NSLOT + 1;
  constexpr int NCH = 2;
  constexpr int NPIX = IMG * IMG;
  constexpr int NCHUNK = NSLOT * 4;
  constexpr int COT = MFR * 16;      // 32
  constexpr int WPLANE = TAPS * COT;
  constexpr int WPSTR  = WPLANE + 1;
  constexpr int WCHUNK = WPLANE * 4;
  constexpr int G = 64;

  __shared__ __align__(16) hf alds[4 * PSTR * 8];
  __shared__ __align__(16) hf wlds[4 * WPSTR * 8];

  const int tid = threadIdx.x;
  const int wid = tid >> 6, lane = tid & 63, lg = lane >> 4, ln = lane & 15;
  const int n = blockIdx.z;
  const int r0 = blockIdx.x * PIXROWS;
  const int par = blockIdx.y;
  const int qq = par >> 1, pp = par & 1;
  const hf* wbase = wp + (size_t)par * (TAPS * NCH * COT * 32);

  f32x4 acc[MFR][WPIX];
#pragma unroll
  for (int mf = 0; mf < MFR; ++mf)
#pragma unroll
    for (int pf = 0; pf < WPIX; ++pf) acc[mf][pf] = (f32x4){0.f, 0.f, 0.f, 0.f};

  for (int ks = 0; ks < NCH; ++ks) {
    __syncthreads();
    const int k0 = ks * 32;
    for (int cidx = tid; cidx < NCHUNK; cidx += 256) {
      const int s = cidx >> 2, p = cidx & 3;
      const int rs = s / TC, cs = s - rs * TC;
      const int ir = r0 - 1 + rs, ic = cs - 1;
      s8v v = (s8v){0, 0, 0, 0, 0, 0, 0, 0};
      if (((unsigned)ir < (unsigned)IMG) && ((unsigned)ic < (unsigned)IMG)) {
        const int ipix = ir * IMG + ic;
        v = *(const s8v*)(src1 + (((size_t)n * NPIX + ipix) * G + k0 + p * 8));
        v = bnin_apply(v, bnst, k0 + p * 8);
      }
      *(s8v*)(&alds[(size_t)(p * PSTR + s) * 8]) = v;
    }
    for (int widx = tid; widx < WCHUNK; widx += 256) {
      const int p = widx & 3;
      const int r = widx >> 2;
      const int co = r & (COT - 1);
      const int t = r >> 5;
      const s8v wv = *(const s8v*)(wbase + (((size_t)(t * NCH + ks) * COT + co) * 32 + p * 8));
      *(s8v*)(&wlds[(size_t)(p * WPSTR + r) * 8]) = wv;
    }
    __syncthreads();
#pragma unroll
    for (int t = 0; t < TAPS; ++t) {
      const int dh = qq + (t >> 1) - 1;
      const int dw = pp + (t & 1) - 1;
      h8v afr[MFR];
#pragma unroll
      for (int mf = 0; mf < MFR; ++mf)
        afr[mf] = *(const h8v*)(&wlds[(size_t)(lg * WPSTR + t * COT + mf * 16 + ln) * 8]);
#pragma unroll
      for (int pf = 0; pf < WPIX; ++pf) {
        const int pl = wid * (WPIX * 16) + pf * 16 + ln;
        const int rL = pl / IMG, c = pl - rL * IMG;
        const int slot = (rL + dh + 1) * TC + (c + dw + 1);
        const h8v bfr = *(const h8v*)(&alds[(size_t)(lg * PSTR + slot) * 8]);
#pragma unroll
        for (int mf = 0; mf < MFR; ++mf)
          acc[mf][pf] = __builtin_amdgcn_mfma_f32_16x16x32_f16(afr[mf], bfr, acc[mf][pf], 0, 0, 0);
      }
    }
  }

#pragma unroll
  for (int mf = 0; mf < MFR; ++mf) {
#pragma unroll
    for (int pf = 0; pf < WPIX; ++pf) {
      const int pl = wid * (WPIX * 16) + pf * 16 + ln;
      const int rL = pl / IMG, c = pl - rL * IMG;
      const int opix = (2 * (r0 + rL) + qq) * 64 + 2 * c + pp;
      ushort4 st;
      st.x = f2h_bits(acc[mf][pf][0]); st.y = f2h_bits(acc[mf][pf][1]);
      st.z = f2h_bits(acc[mf][pf][2]); st.w = f2h_bits(acc[mf][pf][3]);
      *reinterpret_cast<ushort4*>(outB + ((size_t)n * 4096 + opix) * 32 + mf * 16 + lg * 4) = st;
    }
  }
  __syncthreads();
  float* sl = (float*)alds;
#pragma unroll
  for (int mf = 0; mf < MFR; ++mf) {
#pragma unroll
    for (int rg = 0; rg < 4; ++rg) {
      float s = 0.f, q2 = 0.f;
#pragma unroll
      for (int pf = 0; pf < WPIX; ++pf) {
        const float v = acc[mf][pf][rg];
        s += v; q2 += v * v;
      }
#pragma unroll
      for (int o = 1; o < 16; o <<= 1) { s += __shfl_xor(s, o); q2 += __shfl_xor(q2, o); }
      if (ln == 0) {
        const int cl = mf * 16 + lg * 4 + rg;
        sl[(wid * MFR * 16 + cl) * 2 + 0] = s;
        sl[(wid * MFR * 16 + cl) * 2 + 1] = q2;
      }
    }
  }
  __syncthreads();
  for (int i = tid; i < MFR * 16 * 2; i += 256) {
    const int cl = i >> 1, stt = i & 1;
    float tot = 0.f;
#pragma unroll
    for (int w = 0; w < 4; ++w) tot += sl[(w * MFR * 16 + cl) * 2 + stt];
    atomicAdd(&statL[2 * cl + stt], tot);
  }
}

// ---------------------------------------------------------------- BN finalize
__global__ void bnfin_kernel(float* __restrict__ statL, const float* __restrict__ g,
                             const float* __restrict__ bt, int C, float invCnt) {
  const int c = threadIdx.x;
  if (c < C) {
    const float m = statL[2 * c] * invCnt;
    const float var = statL[2 * c + 1] * invCnt - m * m;
    const float sc = g[c] * rsqrtf(var + 1e-5f);
    statL[256 + c] = sc;
    statL[384 + c] = bt[c] - m * sc;
  }
}

// ---------------------------------------------------------------- conv5 (CO=1) on VALU, BN-on-read
__global__ __launch_bounds__(256) void conv5_kernel(
    const hf* __restrict__ xd, const float* __restrict__ w5, const float* __restrict__ b5,
    const float* __restrict__ bnst, float* __restrict__ outp) {
  const int gid = blockIdx.x * 256 + threadIdx.x;  // 162*4096
  const int n = gid >> 12, pix = gid & 4095;
  const int b = n / 81, ij = n - b * 81;
  const int oh = pix >> 6, ow = pix & 63;
  float acc = b5[0];
#pragma unroll
  for (int kh = 0; kh < 3; ++kh) {
    const int ih = oh + kh - 1;
#pragma unroll
    for (int kw = 0; kw < 3; ++kw) {
      const int iw = ow + kw - 1;
      if (((unsigned)ih < 64u) && ((unsigned)iw < 64u)) {
        const hf* xp = xd + ((size_t)n * 4096 + ih * 64 + iw) * 32;
#pragma unroll
        for (int cq = 0; cq < 4; ++cq) {
          const h8v v = *(const h8v*)(xp + cq * 8);
#pragma unroll
          for (int j = 0; j < 8; ++j) {
            const int c = cq * 8 + j;
            const float t = (hf)fmaxf((float)v[j] * bnst[256 + c] + bnst[384 + c], 0.f);
            acc += t * w5[c * 9 + kh * 3 + kw];
          }
        }
      }
    }
  }
  outp[((size_t)(b * 113 + ij)) * 4096 + pix] = acc;
}

// ---------------------------------------------------------------- DAP softmax
__global__ __launch_bounds__(64) void softmax_kernel(
    const float* __restrict__ outp, const float* __restrict__ dapw, float* __restrict__ score) {
  __shared__ float cb[64 * 81];
  __shared__ float sb[64 * 81];
  const int t = threadIdx.x;
  const int gid = blockIdx.x * 64 + t;
  const int b = gid >> 12, hw = gid & 4095;
  for (int d = 0; d < 81; ++d)
    cb[t * 81 + d] = outp[((size_t)(b * 113 + d)) * 4096 + hw];
  float smax = -1e30f;
  for (int o = 0; o < 81; ++o) {
    float s = 0.f;
    const float* dr = dapw + o * 81;
    for (int d = 0; d < 81; ++d) s += dr[d] * cb[t * 81 + d];
    sb[t * 81 + o] = s;
    smax = fmaxf(smax, s);
  }
  float sum = 0.f;
  for (int o = 0; o < 81; ++o) {
    const float e = __expf(sb[t * 81 + o] - smax);
    sb[t * 81 + o] = e;
    sum += e;
  }
  const float inv = 1.f / sum;
  for (int o = 0; o < 81; ++o)
    score[((size_t)(b * 81 + o)) * 4096 + hw] = sb[t * 81 + o] * inv;
}

// ---------------------------------------------------------------- emb reduce
__global__ __launch_bounds__(256) void emb_kernel(
    const float* __restrict__ score, const hf* __restrict__ e3, float* __restrict__ outp) {
  const int idx = blockIdx.x * 256 + threadIdx.x;  // 2*32*4096
  const int b = idx >> 17, r = idx & 131071, m = r >> 12, hw = r & 4095;
  float acc = 0.f;
  for (int d = 0; d < 81; ++d) {
    const float sc = score[((size_t)(b * 81 + d)) * 4096 + hw];
    acc += sc * (float)e3[(((size_t)(b * 81 + d)) * 4096 + hw) * 32 + m];
  }
  outp[((size_t)(b * 113 + 81 + m)) * 4096 + hw] = acc;
}

// ======================================================================
extern "C" void kernel_launch(void* const* d_in, const int* in_sizes, int n_in,
                              void* d_out, int out_size, void* d_ws, size_t ws_size,
                              hipStream_t stream) {
  const float* f1     = (const float*)d_in[0];
  const float* f2     = (const float*)d_in[1];
  const float* coords = (const float*)d_in[2];
  const float* w1     = (const float*)d_in[3];
  const float* g1     = (const float*)d_in[4];
  const float* bb1    = (const float*)d_in[5];
  const float* w2     = (const float*)d_in[6];
  const float* g2     = (const float*)d_in[7];
  const float* bb2    = (const float*)d_in[8];
  const float* w3     = (const float*)d_in[9];
  const float* g3     = (const float*)d_in[10];
  const float* bb3    = (const float*)d_in[11];
  const float* w4     = (const float*)d_in[12];
  const float* g4     = (const float*)d_in[13];
  const float* bb4    = (const float*)d_in[14];
  const float* wdcv   = (const float*)d_in[15];
  const float* gd     = (const float*)d_in[16];
  const float* bbd    = (const float*)d_in[17];
  const float* w5     = (const float*)d_in[18];
  const float* b5     = (const float*)d_in[19];
  const float* e1w    = (const float*)d_in[20];
  const float* e1bi   = (const float*)d_in[21];
  const float* e2w    = (const float*)d_in[22];
  const float* e2bi   = (const float*)d_in[23];
  const float* e3w    = (const float*)d_in[24];
  const float* e3bi   = (const float*)d_in[25];
  const float* dapw   = (const float*)d_in[26];
  float* out = (float*)d_out;
  char* ws = (char*)d_ws;

  hf* sA  = (hf*)(ws + OFF_SA);
  hf* f2s = (hf*)(ws + OFF_F2S);
  hf* be1 = (hf*)(ws + OFF_E1);
  hf* be2 = (hf*)(ws + OFF_E2);
  hf* be3 = (hf*)(ws + OFF_E3);
  hf* x1  = (hf*)(ws + OFF_X1);
  hf* x2  = (hf*)(ws + OFF_X2);
  hf* x3  = (hf*)(ws + OFF_X3);
  hf* x4  = (hf*)(ws + OFF_X4);
  hf* xd  = (hf*)(ws + OFF_XD);
  float* score = (float*)(ws + OFF_SCORE);
  float* stats = (float*)(ws + OFF_STATS);
  hf* wc1 = (hf*)(ws + OFF_WC1);
  hf* wc2 = (hf*)(ws + OFF_WC2);
  hf* wc3 = (hf*)(ws + OFF_WC3);
  hf* wc4 = (hf*)(ws + OFF_WC4);
  hf* wdc = (hf*)(ws + OFF_WDC);
  hf* we1 = (hf*)(ws + OFF_WE1);
  hf* we2 = (hf*)(ws + OFF_WE2);
  hf* we3 = (hf*)(ws + OFF_WE3);
  float* dt1 = (float*)(ws + OFF_DT1);
  float* dtE = (float*)(ws + OFF_DTE);
  float* f2clf = (float*)(ws + OFF_F2CLF);

  hipMemsetAsync(stats, 0, 2560 * sizeof(float), stream);

  // weight prepacks (exact r17 set)
  prepack<<<216, 256, 0, stream>>>(w1,   wc1, 96, 96, 64, 66, 64, 9);
  prepack<<<432, 256, 0, stream>>>(w2,   wc2, 128, 128, 96, 96, 96, 9);
  prepack2<<<576, 256, 0, stream>>>(w3,  wc3, 128, 128, 4);
  prepack2<<<288, 256, 0, stream>>>(w4,  wc4, 64, 128, 4);
  prepack2d<<<128, 256, 0, stream>>>(wdcv, wdc);
  prepack<<<12,  256, 0, stream>>>(e1w,  we1, 48, 48, 64, 66, 64, 1);
  prepack<<<16,  256, 0, stream>>>(e2w,  we2, 64, 64, 48, 48, 64, 1);
  prepack<<<8,   256, 0, stream>>>(e3w,  we3, 32, 32, 64, 64, 64, 1);
  dtab1_kernel<<<7, 256, 0, stream>>>(w1, dt1);
  dtabE_kernel<<<1, 96, 0, stream>>>(e1w, dtE);

  // inputs (f2 interpolated in fp32)
  packf1<<<32, 256, 0, stream>>>(f1, sA);
  packf2f32<<<32, 256, 0, stream>>>(f2, f2clf);
  sample2<<<2592, 256, 0, stream>>>(f2clf, coords, f2s);

  // embedding branch (DIRECT 1x1 convs — byte-identical to r17)
  mconv<3, 1, true, false, 32, 64, 48, 48, 3, 64, 64, 4, 4, true>
      <<<dim3(16, 1, 162), 256, 0, stream>>>(f2s, sA, we1, e1bi, dtE, nullptr, nullptr, be1, nullptr);
  mconv<3, 1, false, false, 48, 64, 64, 64, 4, 64, 64, 4, 4, false>
      <<<dim3(16, 1, 162), 256, 0, stream>>>(be1, nullptr, we2, e2bi, nullptr, nullptr, nullptr, be2, nullptr);
  mconv<3, 2, false, false, 64, 64, 32, 32, 2, 64, 64, 4, 4, false>
      <<<dim3(16, 1, 162), 256, 0, stream>>>(be2, nullptr, we3, e3bi, nullptr, nullptr, nullptr, be3, nullptr);

  // conv1: UNTOUCHED r17 path (the only kernel that tolerates no modification)
  mconv<0, 0, true, false, 32, 64, 96, 96, 3, 64, 64, 4, 4, true>
      <<<dim3(16, 2, 162), 256, 0, stream>>>(f2s, sA, wc1, nullptr, dt1, stats + 0, nullptr, x1, nullptr);
  bnfin_kernel<<<1, 128, 0, stream>>>(stats + 0, g1, bb1, 96, 1.f / 663552.f);

  // conv2: r17 path + BN1 on read (norm_ip<12> eliminated)
  mconv<1, 0, false, true, 96, 96, 128, 128, 4, 32, 64, 4, 2, false>
      <<<dim3(8, 2, 162), 256, 0, stream>>>(x1, nullptr, wc2, nullptr, nullptr, stats + 512, stats + 0, x2, nullptr);
  bnfin_kernel<<<1, 128, 0, stream>>>(stats + 512, g2, bb2, 128, 1.f / 165888.f);

  // conv3: weight-LDS path + BN2 on read
  mconv2<128, 128, 4, 4, 2, true>
      <<<dim3(8, 2, 162), 256, 0, stream>>>(x2, wc3, stats + 512, stats + 1024, x3);
  bnfin_kernel<<<1, 128, 0, stream>>>(stats + 1024, g3, bb3, 128, 1.f / 165888.f);

  // conv4: weight-LDS path + BN3 on read
  mconv2<128, 64, 4, 4, 2, true>
      <<<dim3(8, 1, 162), 256, 0, stream>>>(x3, wc4, stats + 1024, stats + 1536, x4);
  bnfin_kernel<<<1, 128, 0, stream>>>(stats + 1536, g4, bb4, 64, 1.f / 165888.f);

  // deconv: weight-LDS path + BN4 on read
  mconv2d<<<dim3(4, 4, 162), 256, 0, stream>>>(x4, wdc, stats + 1536, stats + 2048, xd);
  bnfin_kernel<<<1, 128, 0, stream>>>(stats + 2048, gd, bbd, 32, 1.f / 663552.f);

  // conv5 on VALU + BNd on read -> cost planes of out
  conv5_kernel<<<2592, 256, 0, stream>>>(xd, w5, b5, stats + 2048, out);

  // DAP softmax + embedding reduction
  softmax_kernel<<<128, 64, 0, stream>>>(out, dapw, score);
  emb_kernel<<<1024, 256, 0, stream>>>(score, be3, out);

  (void)in_sizes; (void)n_in; (void)out_size; (void)ws_size;
}

// Round 21
// 924.892 us; speedup vs baseline: 1.1509x; 1.0283x over previous
//
#include <hip/hip_runtime.h>
#include <hip/hip_bf16.h>

typedef _Float16 hf;
typedef short    s8v  __attribute__((ext_vector_type(8)));
typedef _Float16 h8v  __attribute__((ext_vector_type(8)));
typedef float    f32x4 __attribute__((ext_vector_type(4)));

#define DEVINL __device__ __forceinline__

DEVINL unsigned short f2h_bits(float f) { return __builtin_bit_cast(unsigned short, (hf)f); }
DEVINL float h2f_bits(unsigned short u) { return (float)__builtin_bit_cast(hf, u); }

// ---------------------------------------------------------------- arena
static constexpr size_t OFF_SA    = 0;
static constexpr size_t OFF_F2S   = 524288;
static constexpr size_t OFF_E1    = 42991616;
static constexpr size_t OFF_E2    = 106692608;
static constexpr size_t OFF_E3    = 42991616;
static constexpr size_t OFF_X1    = 85458944;
static constexpr size_t OFF_X2    = 524288;
static constexpr size_t OFF_X3    = 85458944;
static constexpr size_t OFF_X4    = 524288;
static constexpr size_t OFF_XD    = 127926272;
static constexpr size_t OFF_SCORE = 524288;
static constexpr size_t OFF_STATS = 212860928;
static constexpr size_t OFF_WC1   = 212871168;
static constexpr size_t OFF_WC2   = 212981760;
static constexpr size_t OFF_WC3   = 213202944;
static constexpr size_t OFF_WC4   = 213497856;
static constexpr size_t OFF_WDC   = 213645312;
static constexpr size_t OFF_WE1   = 213720064;
static constexpr size_t OFF_WE2   = 213726208;
static constexpr size_t OFF_WE3   = 213734400;
static constexpr size_t OFF_DT1   = 213738496;
static constexpr size_t OFF_DTE   = 213745408;
static constexpr size_t OFF_F2CLF = 213746048;

// ---------------------------------------------------------------- prepack (old [t][co][KP])
__global__ void prepack(const float* __restrict__ src, hf* __restrict__ dst,
                        int COr, int COP, int CINr, int CINsrc, int KP, int TAPS) {
  const int idx = blockIdx.x * 256 + threadIdx.x;
  const int total = TAPS * COP * KP;
  if (idx >= total) return;
  const int k = idx % KP;
  const int r = idx / KP;
  const int co = r % COP;
  const int t = r / COP;
  float v = 0.f;
  if (co < COr && k < CINr) v = src[((size_t)co * CINsrc + k) * TAPS + t];
  dst[idx] = (hf)v;
}

// dense layout: dst[t][ks][co][32]
__global__ void prepack2(const float* __restrict__ src, hf* __restrict__ dst,
                         int COP, int CIN, int NCHn) {
  const int idx = blockIdx.x * 256 + threadIdx.x;
  const int total = 9 * NCHn * COP * 32;
  if (idx >= total) return;
  const int kk = idx & 31;
  const int r = idx >> 5;
  const int co = r % COP;
  const int r2 = r / COP;
  const int ks = r2 % NCHn;
  const int t = r2 / NCHn;
  dst[idx] = (hf)src[((size_t)co * CIN + ks * 32 + kk) * 9 + t];
}

// deconv parity-major dense: dst[par][tt][ks][co][32]
__global__ void prepack2d(const float* __restrict__ src, hf* __restrict__ dst) {
  const int idx = blockIdx.x * 256 + threadIdx.x;  // 32768
  if (idx >= 32768) return;
  const int kk = idx & 31;
  const int co = (idx >> 5) & 31;
  const int ks = (idx >> 10) & 1;
  const int tt = (idx >> 11) & 3;
  const int par = idx >> 13;
  const int qq = par >> 1, pp = par & 1;
  const int a = tt >> 1, b = tt & 1;
  dst[idx] = (hf)src[(((size_t)co * 64 + ks * 32 + kk) * 4 + (qq + 2 * a)) * 4 + (pp + 2 * b)];
}

__global__ void dtab1_kernel(const float* __restrict__ w1, float* __restrict__ dtab) {
  const int idx = blockIdx.x * 256 + threadIdx.x;  // 96*9*2
  if (idx >= 96 * 9 * 2) return;
  const int c = idx & 1;
  const int r = idx >> 1;
  const int pat = r % 9;
  const int co = r / 9;
  const int rc = pat / 3, cc = pat % 3;
  const int kh0 = (rc == 0) ? 1 : 0, kh1 = (rc == 2) ? 1 : 2;
  const int kw0 = (cc == 0) ? 1 : 0, kw1 = (cc == 2) ? 1 : 2;
  float s = 0.f;
  for (int kh = kh0; kh <= kh1; ++kh)
    for (int kw = kw0; kw <= kw1; ++kw)
      s += w1[((size_t)(co * 66 + 64 + c) * 3 + kh) * 3 + kw];
  dtab[(co * 9 + pat) * 2 + c] = s;
}

__global__ void dtabE_kernel(const float* __restrict__ e1w, float* __restrict__ dtE) {
  const int co = threadIdx.x;
  if (co < 48) {
    dtE[co * 2 + 0] = e1w[co * 66 + 64];
    dtE[co * 2 + 1] = e1w[co * 66 + 65];
  }
}

// ---------------------------------------------------------------- input builders
__global__ __launch_bounds__(256) void packf1(const float* __restrict__ f1, hf* __restrict__ sA) {
  const int gid = blockIdx.x * 256 + threadIdx.x;  // 2*4096
  const int b = gid >> 12, pix = gid & 4095;
  unsigned words[16];
#pragma unroll
  for (int c = 0; c < 32; c += 2) {
    const float v0 = f1[((size_t)(b * 32 + c)) * 4096 + pix];
    const float v1 = f1[((size_t)(b * 32 + c + 1)) * 4096 + pix];
    words[c >> 1] = (unsigned)f2h_bits(v0) | ((unsigned)f2h_bits(v1) << 16);
  }
  uint4* dst = (uint4*)(sA + (size_t)gid * 32);
#pragma unroll
  for (int i = 0; i < 4; ++i)
    dst[i] = make_uint4(words[4 * i], words[4 * i + 1], words[4 * i + 2], words[4 * i + 3]);
}

__global__ __launch_bounds__(256) void packf2f32(const float* __restrict__ f2,
                                                 float* __restrict__ dst) {
  const int gid = blockIdx.x * 256 + threadIdx.x;  // 2*4096
  const int b = gid >> 12, pix = gid & 4095;
  float* op = dst + (size_t)gid * 32;
#pragma unroll
  for (int c = 0; c < 32; c += 4) {
    float4 v;
    v.x = f2[((size_t)(b * 32 + c + 0)) * 4096 + pix];
    v.y = f2[((size_t)(b * 32 + c + 1)) * 4096 + pix];
    v.z = f2[((size_t)(b * 32 + c + 2)) * 4096 + pix];
    v.w = f2[((size_t)(b * 32 + c + 3)) * 4096 + pix];
    *(float4*)(op + c) = v;
  }
}

__global__ __launch_bounds__(256) void sample2(const float* __restrict__ f2clf,
                                               const float* __restrict__ coords,
                                               hf* __restrict__ f2s) {
  const int gid = blockIdx.x * 256 + threadIdx.x;  // 162*4096
  const int n = gid >> 12, pix = gid & 4095;
  const int b = n / 81, ij = n - b * 81;
  const float di = (float)(ij / 9) - 4.f, dj = (float)(ij % 9) - 4.f;
  const float x = coords[((size_t)(b * 2 + 0)) * 4096 + pix] + di;
  const float y = coords[((size_t)(b * 2 + 1)) * 4096 + pix] + dj;
  const float x0f = floorf(x), y0f = floorf(y);
  const int x0 = (int)x0f, y0 = (int)y0f;
  const float wx1 = x - x0f, wx0 = 1.f - wx1;
  const float wy1 = y - y0f, wy0 = 1.f - wy1;
  const bool vx0 = (unsigned)x0 < 64u, vx1 = (unsigned)(x0 + 1) < 64u;
  const bool vy0 = (unsigned)y0 < 64u, vy1 = (unsigned)(y0 + 1) < 64u;
  const int x0c = min(max(x0, 0), 63), x1c = min(max(x0 + 1, 0), 63);
  const int y0c = min(max(y0, 0), 63), y1c = min(max(y0 + 1, 0), 63);
  const float w00 = (vy0 && vx0) ? wy0 * wx0 : 0.f;
  const float w01 = (vy0 && vx1) ? wy0 * wx1 : 0.f;
  const float w10 = (vy1 && vx0) ? wy1 * wx0 : 0.f;
  const float w11 = (vy1 && vx1) ? wy1 * wx1 : 0.f;
  const float* fb = f2clf + (size_t)b * 4096 * 32;
  const float* p00 = fb + (size_t)(y0c * 64 + x0c) * 32;
  const float* p01 = fb + (size_t)(y0c * 64 + x1c) * 32;
  const float* p10 = fb + (size_t)(y1c * 64 + x0c) * 32;
  const float* p11 = fb + (size_t)(y1c * 64 + x1c) * 32;
  unsigned words[16];
#pragma unroll
  for (int ch = 0; ch < 16; ++ch) {
    const float2 a  = *(const float2*)(p00 + ch * 2);
    const float2 bb = *(const float2*)(p01 + ch * 2);
    const float2 c  = *(const float2*)(p10 + ch * 2);
    const float2 d  = *(const float2*)(p11 + ch * 2);
    const float v0 = w00 * a.x + w01 * bb.x + w10 * c.x + w11 * d.x;
    const float v1 = w00 * a.y + w01 * bb.y + w10 * c.y + w11 * d.y;
    words[ch] = (unsigned)f2h_bits(v0) | ((unsigned)f2h_bits(v1) << 16);
  }
  uint4* dst = (uint4*)(f2s + (size_t)gid * 32);
#pragma unroll
  for (int i = 0; i < 4; ++i)
    dst[i] = make_uint4(words[4 * i], words[4 * i + 1], words[4 * i + 2], words[4 * i + 3]);
}

// ---------------------------------------------------------------- BNIN helper
DEVINL s8v bnin_apply(s8v v, const float* bnst, int gci) {
  const f32x4 scA = *(const f32x4*)(bnst + 256 + gci);
  const f32x4 scB = *(const f32x4*)(bnst + 256 + gci + 4);
  const f32x4 shA = *(const f32x4*)(bnst + 384 + gci);
  const f32x4 shB = *(const f32x4*)(bnst + 384 + gci + 4);
  h8v h = __builtin_bit_cast(h8v, v);
#pragma unroll
  for (int jj = 0; jj < 8; ++jj) {
    const float sc = (jj < 4) ? scA[jj] : scB[jj - 4];
    const float sh = (jj < 4) ? shA[jj] : shB[jj - 4];
    h[jj] = (hf)fmaxf((float)h[jj] * sc + sh, 0.f);
  }
  return __builtin_bit_cast(s8v, h);
}

// ---------------------------------------------------------------- MFMA conv template (r20)
template <int GEOM, int EPI, bool DUAL, bool BNIN, int G, int KP, int COP, int COB, int MFR,
          int IMGO, int IMGI, int PIXROWS, int WPIX, bool DELTA>
__global__ __launch_bounds__(256) void mconv(
    const hf* __restrict__ src1, const hf* __restrict__ src0,
    const hf* __restrict__ wp, const float* __restrict__ bias,
    const float* __restrict__ dtab, float* __restrict__ statL,
    const float* __restrict__ bnst,
    hf* __restrict__ outB, float* __restrict__ outF) {
  constexpr bool DIRECT = (GEOM == 3);
  constexpr int TAPS  = (GEOM == 2) ? 4 : (GEOM == 3) ? 1 : 9;
  constexpr int TR    = (GEOM == 1) ? (2 * PIXROWS + 1) : (GEOM == 3) ? 1 : (PIXROWS + 2);
  constexpr int TC    = (GEOM == 1) ? 65 : (GEOM == 3) ? 1 : (IMGI + 2);
  constexpr int NSLOT = TR * TC;
  constexpr int PSTR  = NSLOT + 1;
  constexpr int NCH   = KP / 32;
  constexpr int NPIXI = IMGI * IMGI;
  constexpr int NPIXO = (GEOM == 2) ? 4096 : IMGO * IMGO;
  constexpr int NCHUNK = NSLOT * 4;
  constexpr int CPT   = (NCHUNK + 255) / 256;
  constexpr int LDSE  = DIRECT ? 64 : 4 * PSTR * 8;

  __shared__ __align__(16) hf lds[LDSE];

  const int tid = threadIdx.x;
  const int wid = tid >> 6, lane = tid & 63, lg = lane >> 4, ln = lane & 15;
  const int n = blockIdx.z, b = n / 81, ij = n - b * 81;
  const int r0 = blockIdx.x * PIXROWS;
  const int qq = (GEOM == 2) ? (int)(blockIdx.y >> 1) : 0;
  const int pp = (GEOM == 2) ? (int)(blockIdx.y & 1) : 0;
  const int co0 = (GEOM == 2) ? 0 : (int)blockIdx.y * (MFR * 16);

  f32x4 acc[MFR][WPIX];
#pragma unroll
  for (int mf = 0; mf < MFR; ++mf)
#pragma unroll
    for (int pf = 0; pf < WPIX; ++pf) acc[mf][pf] = (f32x4){0.f, 0.f, 0.f, 0.f};

  if constexpr (DIRECT) {
#pragma unroll
    for (int ch = 0; ch < NCH; ++ch) {
      const int k0 = ch * 32;
      h8v afr[MFR];
#pragma unroll
      for (int mf = 0; mf < MFR; ++mf)
        afr[mf] = *(const h8v*)(wp + ((size_t)(co0 + mf * 16 + ln)) * KP + k0 + lg * 8);
#pragma unroll
      for (int pf = 0; pf < WPIX; ++pf) {
        const int pix = r0 * IMGO + wid * (WPIX * 16) + pf * 16 + ln;
        h8v bfr = (h8v){0, 0, 0, 0, 0, 0, 0, 0};
        if (DUAL) {
          bfr = (ch == 0)
              ? *(const h8v*)(src0 + (((size_t)b * NPIXI + pix) * 32 + lg * 8))
              : *(const h8v*)(src1 + (((size_t)n * NPIXI + pix) * 32 + lg * 8));
        } else {
          const int gci = k0 + lg * 8;
          if (gci < G)
            bfr = *(const h8v*)(src1 + (((size_t)n * NPIXI + pix) * G + gci));
        }
#pragma unroll
        for (int mf = 0; mf < MFR; ++mf)
          acc[mf][pf] = __builtin_amdgcn_mfma_f32_16x16x32_f16(afr[mf], bfr, acc[mf][pf], 0, 0, 0);
      }
    }
  } else {
    s8v rbuf[CPT];
    auto stage_load = [&](int k0) {
#pragma unroll
      for (int j = 0; j < CPT; ++j) {
        const int cidx = tid + j * 256;
        s8v v = (s8v){0, 0, 0, 0, 0, 0, 0, 0};
        if (cidx < NCHUNK) {
          const int s = cidx >> 2, p = cidx & 3;
          const int rs = s / TC, cs = s - rs * TC;
          int ir, ic;
          if (GEOM == 1) { ir = 2 * r0 - 1 + rs; ic = (cs < 32) ? 2 * cs : 2 * (cs - 32) - 1; }
          else           { ir = r0 - 1 + rs;     ic = cs - 1; }
          const int gci = k0 + p * 8;
          if (((unsigned)ir < (unsigned)IMGI) && ((unsigned)ic < (unsigned)IMGI)) {
            const int ipix = ir * IMGI + ic;
            if (DUAL) {
              if (gci < 32)
                v = *(const s8v*)(src0 + (((size_t)b * NPIXI + ipix) * 32 + gci));
              else
                v = *(const s8v*)(src1 + (((size_t)n * NPIXI + ipix) * 32 + (gci - 32)));
            } else if (gci < G) {
              v = *(const s8v*)(src1 + (((size_t)n * NPIXI + ipix) * G + gci));
              if constexpr (BNIN) v = bnin_apply(v, bnst, gci);
            }
          }
        }
        rbuf[j] = v;
      }
    };
    auto stage_write = [&]() {
#pragma unroll
      for (int j = 0; j < CPT; ++j) {
        const int cidx = tid + j * 256;
        if (cidx < NCHUNK) {
          const int s = cidx >> 2, p = cidx & 3;
          *(s8v*)(&lds[(size_t)(p * PSTR + s) * 8]) = rbuf[j];
        }
      }
    };

    stage_load(0);
#pragma unroll
    for (int ch = 0; ch < NCH; ++ch) {
      if (ch > 0) __syncthreads();
      stage_write();
      __syncthreads();
      if (ch + 1 < NCH) stage_load((ch + 1) * 32);
      const int k0 = ch * 32;
#pragma unroll
      for (int t = 0; t < TAPS; ++t) {
        int dh, dw, wt, kh = 0, kw = 0;
        if (GEOM == 2) {
          dh = qq + (t >> 1) - 1; dw = pp + (t & 1) - 1;
          wt = (qq + 2 * (t >> 1)) * 4 + (pp + 2 * (t & 1));
        } else { kh = t / 3; kw = t % 3; dh = kh - 1; dw = kw - 1; wt = t; }
        h8v afr[MFR];
#pragma unroll
        for (int mf = 0; mf < MFR; ++mf)
          afr[mf] = *(const h8v*)(wp + ((size_t)(wt * COP + co0 + mf * 16 + ln)) * KP + k0 + lg * 8);
#pragma unroll
        for (int pf = 0; pf < WPIX; ++pf) {
          const int pl = wid * (WPIX * 16) + pf * 16 + ln;
          const int rL = pl / IMGO, c = pl - rL * IMGO;
          int slot;
          if (GEOM == 1) slot = (2 * rL + kh) * 65 + ((kw == 1) ? c : (32 + c + (kw >> 1)));
          else           slot = (rL + dh + 1) * TC + (c + dw + 1);
          const h8v bfr = *(const h8v*)(&lds[(size_t)(lg * PSTR + slot) * 8]);
#pragma unroll
          for (int mf = 0; mf < MFR; ++mf)
            acc[mf][pf] = __builtin_amdgcn_mfma_f32_16x16x32_f16(afr[mf], bfr, acc[mf][pf], 0, 0, 0);
        }
      }
    }
  }

  const float di = (float)(ij / 9) - 4.f, dj = (float)(ij % 9) - 4.f;

  {
#pragma unroll
    for (int mf = 0; mf < MFR; ++mf) {
#pragma unroll
      for (int pf = 0; pf < WPIX; ++pf) {
        const int pl = wid * (WPIX * 16) + pf * 16 + ln;
        const int rL = pl / IMGO, c = pl - rL * IMGO;
        int opix;
        if constexpr (GEOM == 2) opix = (2 * (r0 + rL) + qq) * 64 + 2 * c + pp;
        else opix = (r0 + rL) * IMGO + c;
        if constexpr (DELTA && EPI == 0) {
          const int oh = r0 + rL;
          const int rc = (oh == 0) ? 0 : ((oh == IMGO - 1) ? 2 : 1);
          const int cc = (c == 0) ? 0 : ((c == IMGO - 1) ? 2 : 1);
#pragma unroll
          for (int rg = 0; rg < 4; ++rg) {
            const int co = co0 + mf * 16 + lg * 4 + rg;
            acc[mf][pf][rg] += di * dtab[(co * 9 + rc * 3 + cc) * 2 + 0] +
                               dj * dtab[(co * 9 + rc * 3 + cc) * 2 + 1];
          }
        }
        if constexpr (DELTA && EPI == 1) {
#pragma unroll
          for (int rg = 0; rg < 4; ++rg) {
            const int co = co0 + mf * 16 + lg * 4 + rg;
            acc[mf][pf][rg] += di * dtab[co * 2] + dj * dtab[co * 2 + 1];
          }
        }
        if constexpr (EPI == 1 || EPI == 2) {
          const float4 bv = *(const float4*)(bias + co0 + mf * 16 + lg * 4);
          acc[mf][pf][0] += bv.x; acc[mf][pf][1] += bv.y;
          acc[mf][pf][2] += bv.z; acc[mf][pf][3] += bv.w;
          if constexpr (EPI == 1) {
#pragma unroll
            for (int rg = 0; rg < 4; ++rg) acc[mf][pf][rg] = fmaxf(acc[mf][pf][rg], 0.f);
          }
        }
        ushort4 st;
        st.x = f2h_bits(acc[mf][pf][0]); st.y = f2h_bits(acc[mf][pf][1]);
        st.z = f2h_bits(acc[mf][pf][2]); st.w = f2h_bits(acc[mf][pf][3]);
        *reinterpret_cast<ushort4*>(outB + ((size_t)n * NPIXO + opix) * COB + co0 + mf * 16 + lg * 4) = st;
      }
    }
    if constexpr (EPI == 0) {
      __syncthreads();
      float* sl = (float*)lds;
#pragma unroll
      for (int mf = 0; mf < MFR; ++mf) {
#pragma unroll
        for (int rg = 0; rg < 4; ++rg) {
          float s = 0.f, q2 = 0.f;
#pragma unroll
          for (int pf = 0; pf < WPIX; ++pf) {
            const float v = acc[mf][pf][rg];
            s += v; q2 += v * v;
          }
#pragma unroll
          for (int o = 1; o < 16; o <<= 1) { s += __shfl_xor(s, o); q2 += __shfl_xor(q2, o); }
          if (ln == 0) {
            const int cl = mf * 16 + lg * 4 + rg;
            sl[(wid * MFR * 16 + cl) * 2 + 0] = s;
            sl[(wid * MFR * 16 + cl) * 2 + 1] = q2;
          }
        }
      }
      __syncthreads();
      for (int i = tid; i < MFR * 16 * 2; i += 256) {
        const int cl = i >> 1, stt = i & 1;
        float tot = 0.f;
#pragma unroll
        for (int w = 0; w < 4; ++w) tot += sl[(w * MFR * 16 + cl) * 2 + stt];
        atomicAdd(&statL[2 * (co0 + cl) + stt], tot);
      }
    }
  }
  (void)outF;
}

// ---------------------------------------------------------------- mconv2s2: conv2 stride-2, weight-LDS tap-split
// GEOM1 staging from proven path; weights dense [t][ks][co][32] staged 3 taps/group.
// PIXROWS=4, WPIX=2, MFR=4 (COT=64); BN1 on read; MFMA order = ks outer, t=0..8 ascending.
__global__ __launch_bounds__(256) void mconv2s2(
    const hf* __restrict__ src1, const hf* __restrict__ wp,
    const float* __restrict__ bnst, float* __restrict__ statL, hf* __restrict__ outB) {
  constexpr int IMGI = 64, IMGO = 32;
  constexpr int PIXROWS = 4, WPIX = 2, MFR = 4;
  constexpr int TR = 2 * PIXROWS + 1;   // 9
  constexpr int TC = 65;
  constexpr int NSLOT = TR * TC;        // 585
  constexpr int PSTR = NSLOT + 1;       // 586
  constexpr int NCH = 3;                // K = 96
  constexpr int G = 96;
  constexpr int NPIXI = IMGI * IMGI;
  constexpr int NCHUNK = NSLOT * 4;     // 2340
  constexpr int COT = MFR * 16;         // 64
  constexpr int COP = 128;
  constexpr int WPLANE = 3 * COT;       // 192 (3 taps per group)
  constexpr int WPSTR  = WPLANE + 1;    // 193
  constexpr int WCHUNK = WPLANE * 4;    // 768

  __shared__ __align__(16) hf alds[4 * PSTR * 8];   // 37.5 KB
  __shared__ __align__(16) hf wlds[4 * WPSTR * 8];  // 12.35 KB

  const int tid = threadIdx.x;
  const int wid = tid >> 6, lane = tid & 63, lg = lane >> 4, ln = lane & 15;
  const int n = blockIdx.z;
  const int r0 = blockIdx.x * PIXROWS;
  const int co0 = (int)blockIdx.y * COT;

  f32x4 acc[MFR][WPIX];
#pragma unroll
  for (int mf = 0; mf < MFR; ++mf)
#pragma unroll
    for (int pf = 0; pf < WPIX; ++pf) acc[mf][pf] = (f32x4){0.f, 0.f, 0.f, 0.f};

  for (int ks = 0; ks < NCH; ++ks) {
    const int k0 = ks * 32;
    __syncthreads();  // protect alds/wlds from prior-iteration reads
    // ---- activation staging (GEOM1 addressing, verbatim from proven mconv) + BN1 on read
    for (int cidx = tid; cidx < NCHUNK; cidx += 256) {
      const int s = cidx >> 2, p = cidx & 3;
      const int rs = s / TC, cs = s - rs * TC;
      const int ir = 2 * r0 - 1 + rs;
      const int ic = (cs < 32) ? 2 * cs : 2 * (cs - 32) - 1;
      s8v v = (s8v){0, 0, 0, 0, 0, 0, 0, 0};
      const int gci = k0 + p * 8;
      if (((unsigned)ir < (unsigned)IMGI) && ((unsigned)ic < (unsigned)IMGI)) {
        const int ipix = ir * IMGI + ic;
        v = *(const s8v*)(src1 + (((size_t)n * NPIXI + ipix) * G + gci));
        v = bnin_apply(v, bnst, gci);
      }
      *(s8v*)(&alds[(size_t)(p * PSTR + s) * 8]) = v;
    }
    // ---- tap groups: 3 taps staged at a time
#pragma unroll
    for (int tg = 0; tg < 3; ++tg) {
      if (tg > 0) __syncthreads();  // protect wlds overwrite
      for (int widx = tid; widx < WCHUNK; widx += 256) {
        const int p = widx & 3;
        const int r = widx >> 2;            // r = tt*COT + co_local
        const int co = r & (COT - 1);
        const int tt = r >> 6;              // 0..2
        const int tglob = tg * 3 + tt;
        const s8v wv = *(const s8v*)(wp + (((size_t)(tglob * NCH + ks) * COP + co0 + co) * 32 + p * 8));
        *(s8v*)(&wlds[(size_t)(p * WPSTR + r) * 8]) = wv;
      }
      __syncthreads();  // weights (and on tg==0, activations) ready
#pragma unroll
      for (int tt = 0; tt < 3; ++tt) {
        const int kh = tg, kw = tt;         // tglob = tg*3+tt -> kh=tglob/3, kw=tglob%3
        h8v afr[MFR];
#pragma unroll
        for (int mf = 0; mf < MFR; ++mf)
          afr[mf] = *(const h8v*)(&wlds[(size_t)(lg * WPSTR + tt * COT + mf * 16 + ln) * 8]);
#pragma unroll
        for (int pf = 0; pf < WPIX; ++pf) {
          const int pl = wid * (WPIX * 16) + pf * 16 + ln;
          const int rL = pl / IMGO, c = pl - rL * IMGO;
          const int slot = (2 * rL + kh) * 65 + ((kw == 1) ? c : (32 + c + (kw >> 1)));
          const h8v bfr = *(const h8v*)(&alds[(size_t)(lg * PSTR + slot) * 8]);
#pragma unroll
          for (int mf = 0; mf < MFR; ++mf)
            acc[mf][pf] = __builtin_amdgcn_mfma_f32_16x16x32_f16(afr[mf], bfr, acc[mf][pf], 0, 0, 0);
        }
      }
    }
  }

  // ---- epilogue: raw store + BN stats (identical to mconv EPI=0, GEOM1 opix)
#pragma unroll
  for (int mf = 0; mf < MFR; ++mf) {
#pragma unroll
    for (int pf = 0; pf < WPIX; ++pf) {
      const int pl = wid * (WPIX * 16) + pf * 16 + ln;
      const int rL = pl / IMGO, c = pl - rL * IMGO;
      const int opix = (r0 + rL) * IMGO + c;
      ushort4 st;
      st.x = f2h_bits(acc[mf][pf][0]); st.y = f2h_bits(acc[mf][pf][1]);
      st.z = f2h_bits(acc[mf][pf][2]); st.w = f2h_bits(acc[mf][pf][3]);
      *reinterpret_cast<ushort4*>(outB + ((size_t)n * 1024 + opix) * COP + co0 + mf * 16 + lg * 4) = st;
    }
  }
  __syncthreads();
  float* sl = (float*)alds;
#pragma unroll
  for (int mf = 0; mf < MFR; ++mf) {
#pragma unroll
    for (int rg = 0; rg < 4; ++rg) {
      float s = 0.f, q2 = 0.f;
#pragma unroll
      for (int pf = 0; pf < WPIX; ++pf) {
        const float v = acc[mf][pf][rg];
        s += v; q2 += v * v;
      }
#pragma unroll
      for (int o = 1; o < 16; o <<= 1) { s += __shfl_xor(s, o); q2 += __shfl_xor(q2, o); }
      if (ln == 0) {
        const int cl = mf * 16 + lg * 4 + rg;
        sl[(wid * MFR * 16 + cl) * 2 + 0] = s;
        sl[(wid * MFR * 16 + cl) * 2 + 1] = q2;
      }
    }
  }
  __syncthreads();
  for (int i = tid; i < MFR * 16 * 2; i += 256) {
    const int cl = i >> 1, stt = i & 1;
    float tot = 0.f;
#pragma unroll
    for (int w = 0; w < 4; ++w) tot += sl[(w * MFR * 16 + cl) * 2 + stt];
    atomicAdd(&statL[2 * (co0 + cl) + stt], tot);
  }
}

// ---------------------------------------------------------------- mconv2 (proven) + BNIN
template <int G, int COP, int MFR, int PIXROWS, int WPIX, bool BNIN>
__global__ __launch_bounds__(256) void mconv2(
    const hf* __restrict__ src1, const hf* __restrict__ wp,
    const float* __restrict__ bnst,
    float* __restrict__ statL, hf* __restrict__ outB) {
  constexpr int IMG = 32;
  constexpr int TAPS = 9;
  constexpr int TC = IMG + 2;
  constexpr int TR = PIXROWS + 2;
  constexpr int NSLOT = TR * TC;
  constexpr int PSTR = NSLOT + 1;
  constexpr int NCH = G / 32;
  constexpr int NPIX = IMG * IMG;
  constexpr int NCHUNK = NSLOT * 4;
  constexpr int COT = MFR * 16;      // 64
  constexpr int WPLANE = TAPS * COT;
  constexpr int WPSTR  = WPLANE + 1;
  constexpr int WCHUNK = WPLANE * 4;

  __shared__ __align__(16) hf alds[4 * PSTR * 8];
  __shared__ __align__(16) hf wlds[4 * WPSTR * 8];

  const int tid = threadIdx.x;
  const int wid = tid >> 6, lane = tid & 63, lg = lane >> 4, ln = lane & 15;
  const int n = blockIdx.z;
  const int r0 = blockIdx.x * PIXROWS;
  const int co0 = blockIdx.y * COT;

  f32x4 acc[MFR][WPIX];
#pragma unroll
  for (int mf = 0; mf < MFR; ++mf)
#pragma unroll
    for (int pf = 0; pf < WPIX; ++pf) acc[mf][pf] = (f32x4){0.f, 0.f, 0.f, 0.f};

  for (int ks = 0; ks < NCH; ++ks) {
    __syncthreads();
    for (int cidx = tid; cidx < NCHUNK; cidx += 256) {
      const int s = cidx >> 2, p = cidx & 3;
      const int rs = s / TC, cs = s - rs * TC;
      const int ir = r0 - 1 + rs, ic = cs - 1;
      s8v v = (s8v){0, 0, 0, 0, 0, 0, 0, 0};
      if (((unsigned)ir < (unsigned)IMG) && ((unsigned)ic < (unsigned)IMG)) {
        const int ipix = ir * IMG + ic;
        v = *(const s8v*)(src1 + (((size_t)n * NPIX + ipix) * G + ks * 32 + p * 8));
        if constexpr (BNIN) v = bnin_apply(v, bnst, ks * 32 + p * 8);
      }
      *(s8v*)(&alds[(size_t)(p * PSTR + s) * 8]) = v;
    }
    for (int widx = tid; widx < WCHUNK; widx += 256) {
      const int p = widx & 3;
      const int r = widx >> 2;
      const int co = r & (COT - 1);
      const int t = r >> 6;
      const s8v wv = *(const s8v*)(wp + (((size_t)(t * NCH + ks) * COP + co0 + co) * 32 + p * 8));
      *(s8v*)(&wlds[(size_t)(p * WPSTR + r) * 8]) = wv;
    }
    __syncthreads();
#pragma unroll
    for (int t = 0; t < TAPS; ++t) {
      const int kh = t / 3, kw = t % 3;
      const int dh = kh - 1, dw = kw - 1;
      h8v afr[MFR];
#pragma unroll
      for (int mf = 0; mf < MFR; ++mf)
        afr[mf] = *(const h8v*)(&wlds[(size_t)(lg * WPSTR + t * COT + mf * 16 + ln) * 8]);
#pragma unroll
      for (int pf = 0; pf < WPIX; ++pf) {
        const int pl = wid * (WPIX * 16) + pf * 16 + ln;
        const int rL = pl / IMG, c = pl - rL * IMG;
        const int slot = (rL + dh + 1) * TC + (c + dw + 1);
        const h8v bfr = *(const h8v*)(&alds[(size_t)(lg * PSTR + slot) * 8]);
#pragma unroll
        for (int mf = 0; mf < MFR; ++mf)
          acc[mf][pf] = __builtin_amdgcn_mfma_f32_16x16x32_f16(afr[mf], bfr, acc[mf][pf], 0, 0, 0);
      }
    }
  }

#pragma unroll
  for (int mf = 0; mf < MFR; ++mf) {
#pragma unroll
    for (int pf = 0; pf < WPIX; ++pf) {
      const int pl = wid * (WPIX * 16) + pf * 16 + ln;
      const int rL = pl / IMG, c = pl - rL * IMG;
      const int opix = (r0 + rL) * IMG + c;
      ushort4 st;
      st.x = f2h_bits(acc[mf][pf][0]); st.y = f2h_bits(acc[mf][pf][1]);
      st.z = f2h_bits(acc[mf][pf][2]); st.w = f2h_bits(acc[mf][pf][3]);
      *reinterpret_cast<ushort4*>(outB + ((size_t)n * NPIX + opix) * COP + co0 + mf * 16 + lg * 4) = st;
    }
  }
  __syncthreads();
  float* sl = (float*)alds;
#pragma unroll
  for (int mf = 0; mf < MFR; ++mf) {
#pragma unroll
    for (int rg = 0; rg < 4; ++rg) {
      float s = 0.f, q2 = 0.f;
#pragma unroll
      for (int pf = 0; pf < WPIX; ++pf) {
        const float v = acc[mf][pf][rg];
        s += v; q2 += v * v;
      }
#pragma unroll
      for (int o = 1; o < 16; o <<= 1) { s += __shfl_xor(s, o); q2 += __shfl_xor(q2, o); }
      if (ln == 0) {
        const int cl = mf * 16 + lg * 4 + rg;
        sl[(wid * MFR * 16 + cl) * 2 + 0] = s;
        sl[(wid * MFR * 16 + cl) * 2 + 1] = q2;
      }
    }
  }
  __syncthreads();
  for (int i = tid; i < MFR * 16 * 2; i += 256) {
    const int cl = i >> 1, stt = i & 1;
    float tot = 0.f;
#pragma unroll
    for (int w = 0; w < 4; ++w) tot += sl[(w * MFR * 16 + cl) * 2 + stt];
    atomicAdd(&statL[2 * (co0 + cl) + stt], tot);
  }
}

// ---------------------------------------------------------------- mconv2d: deconv weight-LDS + BNIN
__global__ __launch_bounds__(256) void mconv2d(
    const hf* __restrict__ src1, const hf* __restrict__ wp,
    const float* __restrict__ bnst,
    float* __restrict__ statL, hf* __restrict__ outB) {
  constexpr int IMG = 32;
  constexpr int TAPS = 4;
  constexpr int PIXROWS = 8;
  constexpr int WPIX = 4;
  constexpr int MFR = 2;
  constexpr int TC = IMG + 2;
  constexpr int TR = PIXROWS + 2;
  constexpr int NSLOT = TR * TC;
  constexpr int PSTR = NSLOT + 1;
  constexpr int NCH = 2;
  constexpr int NPIX = IMG * IMG;
  constexpr int NCHUNK = NSLOT * 4;
  constexpr int COT = MFR * 16;      // 32
  constexpr int WPLANE = TAPS * COT;
  constexpr int WPSTR  = WPLANE + 1;
  constexpr int WCHUNK = WPLANE * 4;
  constexpr int G = 64;

  __shared__ __align__(16) hf alds[4 * PSTR * 8];
  __shared__ __align__(16) hf wlds[4 * WPSTR * 8];

  const int tid = threadIdx.x;
  const int wid = tid >> 6, lane = tid & 63, lg = lane >> 4, ln = lane & 15;
  const int n = blockIdx.z;
  const int r0 = blockIdx.x * PIXROWS;
  const int par = blockIdx.y;
  const int qq = par >> 1, pp = par & 1;
  const hf* wbase = wp + (size_t)par * (TAPS * NCH * COT * 32);

  f32x4 acc[MFR][WPIX];
#pragma unroll
  for (int mf = 0; mf < MFR; ++mf)
#pragma unroll
    for (int pf = 0; pf < WPIX; ++pf) acc[mf][pf] = (f32x4){0.f, 0.f, 0.f, 0.f};

  for (int ks = 0; ks < NCH; ++ks) {
    __syncthreads();
    const int k0 = ks * 32;
    for (int cidx = tid; cidx < NCHUNK; cidx += 256) {
      const int s = cidx >> 2, p = cidx & 3;
      const int rs = s / TC, cs = s - rs * TC;
      const int ir = r0 - 1 + rs, ic = cs - 1;
      s8v v = (s8v){0, 0, 0, 0, 0, 0, 0, 0};
      if (((unsigned)ir < (unsigned)IMG) && ((unsigned)ic < (unsigned)IMG)) {
        const int ipix = ir * IMG + ic;
        v = *(const s8v*)(src1 + (((size_t)n * NPIX + ipix) * G + k0 + p * 8));
        v = bnin_apply(v, bnst, k0 + p * 8);
      }
      *(s8v*)(&alds[(size_t)(p * PSTR + s) * 8]) = v;
    }
    for (int widx = tid; widx < WCHUNK; widx += 256) {
      const int p = widx & 3;
      const int r = widx >> 2;
      const int co = r & (COT - 1);
      const int t = r >> 5;
      const s8v wv = *(const s8v*)(wbase + (((size_t)(t * NCH + ks) * COT + co) * 32 + p * 8));
      *(s8v*)(&wlds[(size_t)(p * WPSTR + r) * 8]) = wv;
    }
    __syncthreads();
#pragma unroll
    for (int t = 0; t < TAPS; ++t) {
      const int dh = qq + (t >> 1) - 1;
      const int dw = pp + (t & 1) - 1;
      h8v afr[MFR];
#pragma unroll
      for (int mf = 0; mf < MFR; ++mf)
        afr[mf] = *(const h8v*)(&wlds[(size_t)(lg * WPSTR + t * COT + mf * 16 + ln) * 8]);
#pragma unroll
      for (int pf = 0; pf < WPIX; ++pf) {
        const int pl = wid * (WPIX * 16) + pf * 16 + ln;
        const int rL = pl / IMG, c = pl - rL * IMG;
        const int slot = (rL + dh + 1) * TC + (c + dw + 1);
        const h8v bfr = *(const h8v*)(&alds[(size_t)(lg * PSTR + slot) * 8]);
#pragma unroll
        for (int mf = 0; mf < MFR; ++mf)
          acc[mf][pf] = __builtin_amdgcn_mfma_f32_16x16x32_f16(afr[mf], bfr, acc[mf][pf], 0, 0, 0);
      }
    }
  }

#pragma unroll
  for (int mf = 0; mf < MFR; ++mf) {
#pragma unroll
    for (int pf = 0; pf < WPIX; ++pf) {
      const int pl = wid * (WPIX * 16) + pf * 16 + ln;
      const int rL = pl / IMG, c = pl - rL * IMG;
      const int opix = (2 * (r0 + rL) + qq) * 64 + 2 * c + pp;
      ushort4 st;
      st.x = f2h_bits(acc[mf][pf][0]); st.y = f2h_bits(acc[mf][pf][1]);
      st.z = f2h_bits(acc[mf][pf][2]); st.w = f2h_bits(acc[mf][pf][3]);
      *reinterpret_cast<ushort4*>(outB + ((size_t)n * 4096 + opix) * 32 + mf * 16 + lg * 4) = st;
    }
  }
  __syncthreads();
  float* sl = (float*)alds;
#pragma unroll
  for (int mf = 0; mf < MFR; ++mf) {
#pragma unroll
    for (int rg = 0; rg < 4; ++rg) {
      float s = 0.f, q2 = 0.f;
#pragma unroll
      for (int pf = 0; pf < WPIX; ++pf) {
        const float v = acc[mf][pf][rg];
        s += v; q2 += v * v;
      }
#pragma unroll
      for (int o = 1; o < 16; o <<= 1) { s += __shfl_xor(s, o); q2 += __shfl_xor(q2, o); }
      if (ln == 0) {
        const int cl = mf * 16 + lg * 4 + rg;
        sl[(wid * MFR * 16 + cl) * 2 + 0] = s;
        sl[(wid * MFR * 16 + cl) * 2 + 1] = q2;
      }
    }
  }
  __syncthreads();
  for (int i = tid; i < MFR * 16 * 2; i += 256) {
    const int cl = i >> 1, stt = i & 1;
    float tot = 0.f;
#pragma unroll
    for (int w = 0; w < 4; ++w) tot += sl[(w * MFR * 16 + cl) * 2 + stt];
    atomicAdd(&statL[2 * cl + stt], tot);
  }
}

// ---------------------------------------------------------------- BN finalize
__global__ void bnfin_kernel(float* __restrict__ statL, const float* __restrict__ g,
                             const float* __restrict__ bt, int C, float invCnt) {
  const int c = threadIdx.x;
  if (c < C) {
    const float m = statL[2 * c] * invCnt;
    const float var = statL[2 * c + 1] * invCnt - m * m;
    const float sc = g[c] * rsqrtf(var + 1e-5f);
    statL[256 + c] = sc;
    statL[384 + c] = bt[c] - m * sc;
  }
}

// ---------------------------------------------------------------- conv5 (CO=1) on VALU, BN-on-read
__global__ __launch_bounds__(256) void conv5_kernel(
    const hf* __restrict__ xd, const float* __restrict__ w5, const float* __restrict__ b5,
    const float* __restrict__ bnst, float* __restrict__ outp) {
  const int gid = blockIdx.x * 256 + threadIdx.x;  // 162*4096
  const int n = gid >> 12, pix = gid & 4095;
  const int b = n / 81, ij = n - b * 81;
  const int oh = pix >> 6, ow = pix & 63;
  float acc = b5[0];
#pragma unroll
  for (int kh = 0; kh < 3; ++kh) {
    const int ih = oh + kh - 1;
#pragma unroll
    for (int kw = 0; kw < 3; ++kw) {
      const int iw = ow + kw - 1;
      if (((unsigned)ih < 64u) && ((unsigned)iw < 64u)) {
        const hf* xp = xd + ((size_t)n * 4096 + ih * 64 + iw) * 32;
#pragma unroll
        for (int cq = 0; cq < 4; ++cq) {
          const h8v v = *(const h8v*)(xp + cq * 8);
#pragma unroll
          for (int j = 0; j < 8; ++j) {
            const int c = cq * 8 + j;
            const float t = (hf)fmaxf((float)v[j] * bnst[256 + c] + bnst[384 + c], 0.f);
            acc += t * w5[c * 9 + kh * 3 + kw];
          }
        }
      }
    }
  }
  outp[((size_t)(b * 113 + ij)) * 4096 + pix] = acc;
}

// ---------------------------------------------------------------- DAP softmax
__global__ __launch_bounds__(64) void softmax_kernel(
    const float* __restrict__ outp, const float* __restrict__ dapw, float* __restrict__ score) {
  __shared__ float cb[64 * 81];
  __shared__ float sb[64 * 81];
  const int t = threadIdx.x;
  const int gid = blockIdx.x * 64 + t;
  const int b = gid >> 12, hw = gid & 4095;
  for (int d = 0; d < 81; ++d)
    cb[t * 81 + d] = outp[((size_t)(b * 113 + d)) * 4096 + hw];
  float smax = -1e30f;
  for (int o = 0; o < 81; ++o) {
    float s = 0.f;
    const float* dr = dapw + o * 81;
    for (int d = 0; d < 81; ++d) s += dr[d] * cb[t * 81 + d];
    sb[t * 81 + o] = s;
    smax = fmaxf(smax, s);
  }
  float sum = 0.f;
  for (int o = 0; o < 81; ++o) {
    const float e = __expf(sb[t * 81 + o] - smax);
    sb[t * 81 + o] = e;
    sum += e;
  }
  const float inv = 1.f / sum;
  for (int o = 0; o < 81; ++o)
    score[((size_t)(b * 81 + o)) * 4096 + hw] = sb[t * 81 + o] * inv;
}

// ---------------------------------------------------------------- emb reduce
__global__ __launch_bounds__(256) void emb_kernel(
    const float* __restrict__ score, const hf* __restrict__ e3, float* __restrict__ outp) {
  const int idx = blockIdx.x * 256 + threadIdx.x;  // 2*32*4096
  const int b = idx >> 17, r = idx & 131071, m = r >> 12, hw = r & 4095;
  float acc = 0.f;
  for (int d = 0; d < 81; ++d) {
    const float sc = score[((size_t)(b * 81 + d)) * 4096 + hw];
    acc += sc * (float)e3[(((size_t)(b * 81 + d)) * 4096 + hw) * 32 + m];
  }
  outp[((size_t)(b * 113 + 81 + m)) * 4096 + hw] = acc;
}

// ======================================================================
extern "C" void kernel_launch(void* const* d_in, const int* in_sizes, int n_in,
                              void* d_out, int out_size, void* d_ws, size_t ws_size,
                              hipStream_t stream) {
  const float* f1     = (const float*)d_in[0];
  const float* f2     = (const float*)d_in[1];
  const float* coords = (const float*)d_in[2];
  const float* w1     = (const float*)d_in[3];
  const float* g1     = (const float*)d_in[4];
  const float* bb1    = (const float*)d_in[5];
  const float* w2     = (const float*)d_in[6];
  const float* g2     = (const float*)d_in[7];
  const float* bb2    = (const float*)d_in[8];
  const float* w3     = (const float*)d_in[9];
  const float* g3     = (const float*)d_in[10];
  const float* bb3    = (const float*)d_in[11];
  const float* w4     = (const float*)d_in[12];
  const float* g4     = (const float*)d_in[13];
  const float* bb4    = (const float*)d_in[14];
  const float* wdcv   = (const float*)d_in[15];
  const float* gd     = (const float*)d_in[16];
  const float* bbd    = (const float*)d_in[17];
  const float* w5     = (const float*)d_in[18];
  const float* b5     = (const float*)d_in[19];
  const float* e1w    = (const float*)d_in[20];
  const float* e1bi   = (const float*)d_in[21];
  const float* e2w    = (const float*)d_in[22];
  const float* e2bi   = (const float*)d_in[23];
  const float* e3w    = (const float*)d_in[24];
  const float* e3bi   = (const float*)d_in[25];
  const float* dapw   = (const float*)d_in[26];
  float* out = (float*)d_out;
  char* ws = (char*)d_ws;

  hf* sA  = (hf*)(ws + OFF_SA);
  hf* f2s = (hf*)(ws + OFF_F2S);
  hf* be1 = (hf*)(ws + OFF_E1);
  hf* be2 = (hf*)(ws + OFF_E2);
  hf* be3 = (hf*)(ws + OFF_E3);
  hf* x1  = (hf*)(ws + OFF_X1);
  hf* x2  = (hf*)(ws + OFF_X2);
  hf* x3  = (hf*)(ws + OFF_X3);
  hf* x4  = (hf*)(ws + OFF_X4);
  hf* xd  = (hf*)(ws + OFF_XD);
  float* score = (float*)(ws + OFF_SCORE);
  float* stats = (float*)(ws + OFF_STATS);
  hf* wc1 = (hf*)(ws + OFF_WC1);
  hf* wc2 = (hf*)(ws + OFF_WC2);
  hf* wc3 = (hf*)(ws + OFF_WC3);
  hf* wc4 = (hf*)(ws + OFF_WC4);
  hf* wdc = (hf*)(ws + OFF_WDC);
  hf* we1 = (hf*)(ws + OFF_WE1);
  hf* we2 = (hf*)(ws + OFF_WE2);
  hf* we3 = (hf*)(ws + OFF_WE3);
  float* dt1 = (float*)(ws + OFF_DT1);
  float* dtE = (float*)(ws + OFF_DTE);
  float* f2clf = (float*)(ws + OFF_F2CLF);

  hipMemsetAsync(stats, 0, 2560 * sizeof(float), stream);

  // weight prepacks (r20 + ONE change: wc2 now dense [t][ks][co][32] for mconv2s2)
  prepack<<<216, 256, 0, stream>>>(w1,   wc1, 96, 96, 64, 66, 64, 9);
  prepack2<<<432, 256, 0, stream>>>(w2,  wc2, 128, 96, 3);
  prepack2<<<576, 256, 0, stream>>>(w3,  wc3, 128, 128, 4);
  prepack2<<<288, 256, 0, stream>>>(w4,  wc4, 64, 128, 4);
  prepack2d<<<128, 256, 0, stream>>>(wdcv, wdc);
  prepack<<<12,  256, 0, stream>>>(e1w,  we1, 48, 48, 64, 66, 64, 1);
  prepack<<<16,  256, 0, stream>>>(e2w,  we2, 64, 64, 48, 48, 64, 1);
  prepack<<<8,   256, 0, stream>>>(e3w,  we3, 32, 32, 64, 64, 64, 1);
  dtab1_kernel<<<7, 256, 0, stream>>>(w1, dt1);
  dtabE_kernel<<<1, 96, 0, stream>>>(e1w, dtE);

  // inputs (f2 interpolated in fp32)
  packf1<<<32, 256, 0, stream>>>(f1, sA);
  packf2f32<<<32, 256, 0, stream>>>(f2, f2clf);
  sample2<<<2592, 256, 0, stream>>>(f2clf, coords, f2s);

  // embedding branch (DIRECT 1x1 convs — byte-identical to r20)
  mconv<3, 1, true, false, 32, 64, 48, 48, 3, 64, 64, 4, 4, true>
      <<<dim3(16, 1, 162), 256, 0, stream>>>(f2s, sA, we1, e1bi, dtE, nullptr, nullptr, be1, nullptr);
  mconv<3, 1, false, false, 48, 64, 64, 64, 4, 64, 64, 4, 4, false>
      <<<dim3(16, 1, 162), 256, 0, stream>>>(be1, nullptr, we2, e2bi, nullptr, nullptr, nullptr, be2, nullptr);
  mconv<3, 2, false, false, 64, 64, 32, 32, 2, 64, 64, 4, 4, false>
      <<<dim3(16, 1, 162), 256, 0, stream>>>(be2, nullptr, we3, e3bi, nullptr, nullptr, nullptr, be3, nullptr);

  // conv1: UNTOUCHED r17/r20 path
  mconv<0, 0, true, false, 32, 64, 96, 96, 3, 64, 64, 4, 4, true>
      <<<dim3(16, 2, 162), 256, 0, stream>>>(f2s, sA, wc1, nullptr, dt1, stats + 0, nullptr, x1, nullptr);
  bnfin_kernel<<<1, 128, 0, stream>>>(stats + 0, g1, bb1, 96, 1.f / 663552.f);

  // conv2: THE single change — weight-LDS tap-split + BN1 on read
  mconv2s2<<<dim3(8, 2, 162), 256, 0, stream>>>(x1, wc2, stats + 0, stats + 512, x2);
  bnfin_kernel<<<1, 128, 0, stream>>>(stats + 512, g2, bb2, 128, 1.f / 165888.f);

  // conv3: weight-LDS path + BN2 on read
  mconv2<128, 128, 4, 4, 2, true>
      <<<dim3(8, 2, 162), 256, 0, stream>>>(x2, wc3, stats + 512, stats + 1024, x3);
  bnfin_kernel<<<1, 128, 0, stream>>>(stats + 1024, g3, bb3, 128, 1.f / 165888.f);

  // conv4: weight-LDS path + BN3 on read
  mconv2<128, 64, 4, 4, 2, true>
      <<<dim3(8, 1, 162), 256, 0, stream>>>(x3, wc4, stats + 1024, stats + 1536, x4);
  bnfin_kernel<<<1, 128, 0, stream>>>(stats + 1536, g4, bb4, 64, 1.f / 165888.f);

  // deconv: weight-LDS path + BN4 on read
  mconv2d<<<dim3(4, 4, 162), 256, 0, stream>>>(x4, wdc, stats + 1536, stats + 2048, xd);
  bnfin_kernel<<<1, 128, 0, stream>>>(stats + 2048, gd, bbd, 32, 1.f / 663552.f);

  // conv5 on VALU + BNd on read -> cost planes of out
  conv5_kernel<<<2592, 256, 0, stream>>>(xd, w5, b5, stats + 2048, out);

  // DAP softmax + embedding reduction
  softmax_kernel<<<128, 64, 0, stream>>>(out, dapw, score);
  emb_kernel<<<1024, 256, 0, stream>>>(score, be3, out);

  (void)in_sizes; (void)n_in; (void)out_size; (void)ws_size;
}

// Round 24
// 798.562 us; speedup vs baseline: 1.3330x; 1.1582x over previous
//
#include <hip/hip_runtime.h>
#include <hip/hip_bf16.h>

typedef _Float16 hf;
typedef short    s8v  __attribute__((ext_vector_type(8)));
typedef _Float16 h8v  __attribute__((ext_vector_type(8)));
typedef float    f32x4 __attribute__((ext_vector_type(4)));

#define DEVINL __device__ __forceinline__

DEVINL unsigned short f2h_bits(float f) { return __builtin_bit_cast(unsigned short, (hf)f); }
DEVINL float h2f_bits(unsigned short u) { return (float)__builtin_bit_cast(hf, u); }

// ---------------------------------------------------------------- arena
static constexpr size_t OFF_SA    = 0;
static constexpr size_t OFF_F2S   = 524288;
static constexpr size_t OFF_E3    = 42991616;
static constexpr size_t OFF_X1    = 85458944;
static constexpr size_t OFF_X2    = 524288;
static constexpr size_t OFF_X3    = 85458944;
static constexpr size_t OFF_X4    = 524288;
static constexpr size_t OFF_XD    = 127926272;
static constexpr size_t OFF_SCORE = 524288;
static constexpr size_t OFF_STATS = 212860928;
static constexpr size_t OFF_WC1   = 212871168;
static constexpr size_t OFF_WC2   = 212981760;
static constexpr size_t OFF_WC3   = 213202944;
static constexpr size_t OFF_WC4   = 213497856;
static constexpr size_t OFF_WDC   = 213645312;
static constexpr size_t OFF_WE1   = 213720064;
static constexpr size_t OFF_WE2   = 213726208;
static constexpr size_t OFF_WE3   = 213734400;
static constexpr size_t OFF_DT1   = 213738496;
static constexpr size_t OFF_DTE   = 213745408;
static constexpr size_t OFF_F2CLF = 213746048;
static constexpr size_t OFF_PART  = 214794752;  // BN stat partials (fp32), reused per conv
static constexpr size_t OFF_STATD = 216785920;  // BN stat exact sums (f64), 5 slots x 256

// ---------------------------------------------------------------- prepack (old [t][co][KP])
__global__ void prepack(const float* __restrict__ src, hf* __restrict__ dst,
                        int COr, int COP, int CINr, int CINsrc, int KP, int TAPS) {
  const int idx = blockIdx.x * 256 + threadIdx.x;
  const int total = TAPS * COP * KP;
  if (idx >= total) return;
  const int k = idx % KP;
  const int r = idx / KP;
  const int co = r % COP;
  const int t = r / COP;
  float v = 0.f;
  if (co < COr && k < CINr) v = src[((size_t)co * CINsrc + k) * TAPS + t];
  dst[idx] = (hf)v;
}

// dense layout: dst[t][ks][co][32]
__global__ void prepack2(const float* __restrict__ src, hf* __restrict__ dst,
                         int COP, int CIN, int NCHn) {
  const int idx = blockIdx.x * 256 + threadIdx.x;
  const int total = 9 * NCHn * COP * 32;
  if (idx >= total) return;
  const int kk = idx & 31;
  const int r = idx >> 5;
  const int co = r % COP;
  const int r2 = r / COP;
  const int ks = r2 % NCHn;
  const int t = r2 / NCHn;
  dst[idx] = (hf)src[((size_t)co * CIN + ks * 32 + kk) * 9 + t];
}

// deconv parity-major dense: dst[par][tt][ks][co][32]
__global__ void prepack2d(const float* __restrict__ src, hf* __restrict__ dst) {
  const int idx = blockIdx.x * 256 + threadIdx.x;  // 32768
  if (idx >= 32768) return;
  const int kk = idx & 31;
  const int co = (idx >> 5) & 31;
  const int ks = (idx >> 10) & 1;
  const int tt = (idx >> 11) & 3;
  const int par = idx >> 13;
  const int qq = par >> 1, pp = par & 1;
  const int a = tt >> 1, b = tt & 1;
  dst[idx] = (hf)src[(((size_t)co * 64 + ks * 32 + kk) * 4 + (qq + 2 * a)) * 4 + (pp + 2 * b)];
}

__global__ void dtab1_kernel(const float* __restrict__ w1, float* __restrict__ dtab) {
  const int idx = blockIdx.x * 256 + threadIdx.x;  // 96*9*2
  if (idx >= 96 * 9 * 2) return;
  const int c = idx & 1;
  const int r = idx >> 1;
  const int pat = r % 9;
  const int co = r / 9;
  const int rc = pat / 3, cc = pat % 3;
  const int kh0 = (rc == 0) ? 1 : 0, kh1 = (rc == 2) ? 1 : 2;
  const int kw0 = (cc == 0) ? 1 : 0, kw1 = (cc == 2) ? 1 : 2;
  float s = 0.f;
  for (int kh = kh0; kh <= kh1; ++kh)
    for (int kw = kw0; kw <= kw1; ++kw)
      s += w1[((size_t)(co * 66 + 64 + c) * 3 + kh) * 3 + kw];
  dtab[(co * 9 + pat) * 2 + c] = s;
}

__global__ void dtabE_kernel(const float* __restrict__ e1w, float* __restrict__ dtE) {
  const int co = threadIdx.x;
  if (co < 48) {
    dtE[co * 2 + 0] = e1w[co * 66 + 64];
    dtE[co * 2 + 1] = e1w[co * 66 + 65];
  }
}

// ---------------------------------------------------------------- input builders
__global__ __launch_bounds__(256) void packf1(const float* __restrict__ f1, hf* __restrict__ sA) {
  const int gid = blockIdx.x * 256 + threadIdx.x;  // 2*4096
  const int b = gid >> 12, pix = gid & 4095;
  unsigned words[16];
#pragma unroll
  for (int c = 0; c < 32; c += 2) {
    const float v0 = f1[((size_t)(b * 32 + c)) * 4096 + pix];
    const float v1 = f1[((size_t)(b * 32 + c + 1)) * 4096 + pix];
    words[c >> 1] = (unsigned)f2h_bits(v0) | ((unsigned)f2h_bits(v1) << 16);
  }
  uint4* dst = (uint4*)(sA + (size_t)gid * 32);
#pragma unroll
  for (int i = 0; i < 4; ++i)
    dst[i] = make_uint4(words[4 * i], words[4 * i + 1], words[4 * i + 2], words[4 * i + 3]);
}

__global__ __launch_bounds__(256) void packf2f32(const float* __restrict__ f2,
                                                 float* __restrict__ dst) {
  const int gid = blockIdx.x * 256 + threadIdx.x;  // 2*4096
  const int b = gid >> 12, pix = gid & 4095;
  float* op = dst + (size_t)gid * 32;
#pragma unroll
  for (int c = 0; c < 32; c += 4) {
    float4 v;
    v.x = f2[((size_t)(b * 32 + c + 0)) * 4096 + pix];
    v.y = f2[((size_t)(b * 32 + c + 1)) * 4096 + pix];
    v.z = f2[((size_t)(b * 32 + c + 2)) * 4096 + pix];
    v.w = f2[((size_t)(b * 32 + c + 3)) * 4096 + pix];
    *(float4*)(op + c) = v;
  }
}

__global__ __launch_bounds__(256) void sample2(const float* __restrict__ f2clf,
                                               const float* __restrict__ coords,
                                               hf* __restrict__ f2s) {
  const int gid = blockIdx.x * 256 + threadIdx.x;  // 162*4096
  const int n = gid >> 12, pix = gid & 4095;
  const int b = n / 81, ij = n - b * 81;
  const float di = (float)(ij / 9) - 4.f, dj = (float)(ij % 9) - 4.f;
  const float x = coords[((size_t)(b * 2 + 0)) * 4096 + pix] + di;
  const float y = coords[((size_t)(b * 2 + 1)) * 4096 + pix] + dj;
  const float x0f = floorf(x), y0f = floorf(y);
  const int x0 = (int)x0f, y0 = (int)y0f;
  const float wx1 = x - x0f, wx0 = 1.f - wx1;
  const float wy1 = y - y0f, wy0 = 1.f - wy1;
  const bool vx0 = (unsigned)x0 < 64u, vx1 = (unsigned)(x0 + 1) < 64u;
  const bool vy0 = (unsigned)y0 < 64u, vy1 = (unsigned)(y0 + 1) < 64u;
  const int x0c = min(max(x0, 0), 63), x1c = min(max(x0 + 1, 0), 63);
  const int y0c = min(max(y0, 0), 63), y1c = min(max(y0 + 1, 0), 63);
  const float w00 = (vy0 && vx0) ? wy0 * wx0 : 0.f;
  const float w01 = (vy0 && vx1) ? wy0 * wx1 : 0.f;
  const float w10 = (vy1 && vx0) ? wy1 * wx0 : 0.f;
  const float w11 = (vy1 && vx1) ? wy1 * wx1 : 0.f;
  const float* fb = f2clf + (size_t)b * 4096 * 32;
  const float* p00 = fb + (size_t)(y0c * 64 + x0c) * 32;
  const float* p01 = fb + (size_t)(y0c * 64 + x1c) * 32;
  const float* p10 = fb + (size_t)(y1c * 64 + x0c) * 32;
  const float* p11 = fb + (size_t)(y1c * 64 + x1c) * 32;
  unsigned words[16];
#pragma unroll
  for (int ch = 0; ch < 16; ++ch) {
    const float2 a  = *(const float2*)(p00 + ch * 2);
    const float2 bb = *(const float2*)(p01 + ch * 2);
    const float2 c  = *(const float2*)(p10 + ch * 2);
    const float2 d  = *(const float2*)(p11 + ch * 2);
    const float v0 = w00 * a.x + w01 * bb.x + w10 * c.x + w11 * d.x;
    const float v1 = w00 * a.y + w01 * bb.y + w10 * c.y + w11 * d.y;
    words[ch] = (unsigned)f2h_bits(v0) | ((unsigned)f2h_bits(v1) << 16);
  }
  uint4* dst = (uint4*)(f2s + (size_t)gid * 32);
#pragma unroll
  for (int i = 0; i < 4; ++i)
    dst[i] = make_uint4(words[4 * i], words[4 * i + 1], words[4 * i + 2], words[4 * i + 3]);
}

// ---------------------------------------------------------------- BNIN helper
DEVINL s8v bnin_apply(s8v v, const float* bnst, int gci) {
  const f32x4 scA = *(const f32x4*)(bnst + 256 + gci);
  const f32x4 scB = *(const f32x4*)(bnst + 256 + gci + 4);
  const f32x4 shA = *(const f32x4*)(bnst + 384 + gci);
  const f32x4 shB = *(const f32x4*)(bnst + 384 + gci + 4);
  h8v h = __builtin_bit_cast(h8v, v);
#pragma unroll
  for (int jj = 0; jj < 8; ++jj) {
    const float sc = (jj < 4) ? scA[jj] : scB[jj - 4];
    const float sh = (jj < 4) ? shA[jj] : shB[jj - 4];
    h[jj] = (hf)fmaxf((float)h[jj] * sc + sh, 0.f);
  }
  return __builtin_bit_cast(s8v, h);
}

// ---------------------------------------------------------------- MFMA conv template (stats -> partial store)
template <int GEOM, int EPI, bool DUAL, bool BNIN, int G, int KP, int COP, int COB, int MFR,
          int IMGO, int IMGI, int PIXROWS, int WPIX, bool DELTA>
__global__ __launch_bounds__(256) void mconv(
    const hf* __restrict__ src1, const hf* __restrict__ src0,
    const hf* __restrict__ wp, const float* __restrict__ bias,
    const float* __restrict__ dtab, float* __restrict__ statL,
    const float* __restrict__ bnst,
    hf* __restrict__ outB, float* __restrict__ outF) {
  constexpr bool DIRECT = (GEOM == 3);
  constexpr int TAPS  = (GEOM == 2) ? 4 : (GEOM == 3) ? 1 : 9;
  constexpr int TR    = (GEOM == 1) ? (2 * PIXROWS + 1) : (GEOM == 3) ? 1 : (PIXROWS + 2);
  constexpr int TC    = (GEOM == 1) ? 65 : (GEOM == 3) ? 1 : (IMGI + 2);
  constexpr int NSLOT = TR * TC;
  constexpr int PSTR  = NSLOT + 1;
  constexpr int NCH   = KP / 32;
  constexpr int NPIXI = IMGI * IMGI;
  constexpr int NPIXO = (GEOM == 2) ? 4096 : IMGO * IMGO;
  constexpr int NCHUNK = NSLOT * 4;
  constexpr int CPT   = (NCHUNK + 255) / 256;
  constexpr int LDSE  = DIRECT ? 64 : 4 * PSTR * 8;

  __shared__ __align__(16) hf lds[LDSE];

  const int tid = threadIdx.x;
  const int wid = tid >> 6, lane = tid & 63, lg = lane >> 4, ln = lane & 15;
  const int n = blockIdx.z, b = n / 81, ij = n - b * 81;
  const int r0 = blockIdx.x * PIXROWS;
  const int qq = (GEOM == 2) ? (int)(blockIdx.y >> 1) : 0;
  const int pp = (GEOM == 2) ? (int)(blockIdx.y & 1) : 0;
  const int co0 = (GEOM == 2) ? 0 : (int)blockIdx.y * (MFR * 16);

  f32x4 acc[MFR][WPIX];
#pragma unroll
  for (int mf = 0; mf < MFR; ++mf)
#pragma unroll
    for (int pf = 0; pf < WPIX; ++pf) acc[mf][pf] = (f32x4){0.f, 0.f, 0.f, 0.f};

  if constexpr (DIRECT) {
#pragma unroll
    for (int ch = 0; ch < NCH; ++ch) {
      const int k0 = ch * 32;
      h8v afr[MFR];
#pragma unroll
      for (int mf = 0; mf < MFR; ++mf)
        afr[mf] = *(const h8v*)(wp + ((size_t)(co0 + mf * 16 + ln)) * KP + k0 + lg * 8);
#pragma unroll
      for (int pf = 0; pf < WPIX; ++pf) {
        const int pix = r0 * IMGO + wid * (WPIX * 16) + pf * 16 + ln;
        h8v bfr = (h8v){0, 0, 0, 0, 0, 0, 0, 0};
        if (DUAL) {
          bfr = (ch == 0)
              ? *(const h8v*)(src0 + (((size_t)b * NPIXI + pix) * 32 + lg * 8))
              : *(const h8v*)(src1 + (((size_t)n * NPIXI + pix) * 32 + lg * 8));
        } else {
          const int gci = k0 + lg * 8;
          if (gci < G)
            bfr = *(const h8v*)(src1 + (((size_t)n * NPIXI + pix) * G + gci));
        }
#pragma unroll
        for (int mf = 0; mf < MFR; ++mf)
          acc[mf][pf] = __builtin_amdgcn_mfma_f32_16x16x32_f16(afr[mf], bfr, acc[mf][pf], 0, 0, 0);
      }
    }
  } else {
    s8v rbuf[CPT];
    auto stage_load = [&](int k0) {
#pragma unroll
      for (int j = 0; j < CPT; ++j) {
        const int cidx = tid + j * 256;
        s8v v = (s8v){0, 0, 0, 0, 0, 0, 0, 0};
        if (cidx < NCHUNK) {
          const int s = cidx >> 2, p = cidx & 3;
          const int rs = s / TC, cs = s - rs * TC;
          int ir, ic;
          if (GEOM == 1) { ir = 2 * r0 - 1 + rs; ic = (cs < 32) ? 2 * cs : 2 * (cs - 32) - 1; }
          else           { ir = r0 - 1 + rs;     ic = cs - 1; }
          const int gci = k0 + p * 8;
          if (((unsigned)ir < (unsigned)IMGI) && ((unsigned)ic < (unsigned)IMGI)) {
            const int ipix = ir * IMGI + ic;
            if (DUAL) {
              if (gci < 32)
                v = *(const s8v*)(src0 + (((size_t)b * NPIXI + ipix) * 32 + gci));
              else
                v = *(const s8v*)(src1 + (((size_t)n * NPIXI + ipix) * 32 + (gci - 32)));
            } else if (gci < G) {
              v = *(const s8v*)(src1 + (((size_t)n * NPIXI + ipix) * G + gci));
              if constexpr (BNIN) v = bnin_apply(v, bnst, gci);
            }
          }
        }
        rbuf[j] = v;
      }
    };
    auto stage_write = [&]() {
#pragma unroll
      for (int j = 0; j < CPT; ++j) {
        const int cidx = tid + j * 256;
        if (cidx < NCHUNK) {
          const int s = cidx >> 2, p = cidx & 3;
          *(s8v*)(&lds[(size_t)(p * PSTR + s) * 8]) = rbuf[j];
        }
      }
    };

    stage_load(0);
#pragma unroll
    for (int ch = 0; ch < NCH; ++ch) {
      if (ch > 0) __syncthreads();
      stage_write();
      __syncthreads();
      if (ch + 1 < NCH) stage_load((ch + 1) * 32);
      const int k0 = ch * 32;
#pragma unroll
      for (int t = 0; t < TAPS; ++t) {
        int dh, dw, wt, kh = 0, kw = 0;
        if (GEOM == 2) {
          dh = qq + (t >> 1) - 1; dw = pp + (t & 1) - 1;
          wt = (qq + 2 * (t >> 1)) * 4 + (pp + 2 * (t & 1));
        } else { kh = t / 3; kw = t % 3; dh = kh - 1; dw = kw - 1; wt = t; }
        h8v afr[MFR];
#pragma unroll
        for (int mf = 0; mf < MFR; ++mf)
          afr[mf] = *(const h8v*)(wp + ((size_t)(wt * COP + co0 + mf * 16 + ln)) * KP + k0 + lg * 8);
#pragma unroll
        for (int pf = 0; pf < WPIX; ++pf) {
          const int pl = wid * (WPIX * 16) + pf * 16 + ln;
          const int rL = pl / IMGO, c = pl - rL * IMGO;
          int slot;
          if (GEOM == 1) slot = (2 * rL + kh) * 65 + ((kw == 1) ? c : (32 + c + (kw >> 1)));
          else           slot = (rL + dh + 1) * TC + (c + dw + 1);
          const h8v bfr = *(const h8v*)(&lds[(size_t)(lg * PSTR + slot) * 8]);
#pragma unroll
          for (int mf = 0; mf < MFR; ++mf)
            acc[mf][pf] = __builtin_amdgcn_mfma_f32_16x16x32_f16(afr[mf], bfr, acc[mf][pf], 0, 0, 0);
        }
      }
    }
  }

  const float di = (float)(ij / 9) - 4.f, dj = (float)(ij % 9) - 4.f;

  {
#pragma unroll
    for (int mf = 0; mf < MFR; ++mf) {
#pragma unroll
      for (int pf = 0; pf < WPIX; ++pf) {
        const int pl = wid * (WPIX * 16) + pf * 16 + ln;
        const int rL = pl / IMGO, c = pl - rL * IMGO;
        int opix;
        if constexpr (GEOM == 2) opix = (2 * (r0 + rL) + qq) * 64 + 2 * c + pp;
        else opix = (r0 + rL) * IMGO + c;
        if constexpr (DELTA && EPI == 0) {
          const int oh = r0 + rL;
          const int rc = (oh == 0) ? 0 : ((oh == IMGO - 1) ? 2 : 1);
          const int cc = (c == 0) ? 0 : ((c == IMGO - 1) ? 2 : 1);
#pragma unroll
          for (int rg = 0; rg < 4; ++rg) {
            const int co = co0 + mf * 16 + lg * 4 + rg;
            acc[mf][pf][rg] += di * dtab[(co * 9 + rc * 3 + cc) * 2 + 0] +
                               dj * dtab[(co * 9 + rc * 3 + cc) * 2 + 1];
          }
        }
        if constexpr (DELTA && EPI == 1) {
#pragma unroll
          for (int rg = 0; rg < 4; ++rg) {
            const int co = co0 + mf * 16 + lg * 4 + rg;
            acc[mf][pf][rg] += di * dtab[co * 2] + dj * dtab[co * 2 + 1];
          }
        }
        if constexpr (EPI == 1 || EPI == 2) {
          const float4 bv = *(const float4*)(bias + co0 + mf * 16 + lg * 4);
          acc[mf][pf][0] += bv.x; acc[mf][pf][1] += bv.y;
          acc[mf][pf][2] += bv.z; acc[mf][pf][3] += bv.w;
          if constexpr (EPI == 1) {
#pragma unroll
            for (int rg = 0; rg < 4; ++rg) acc[mf][pf][rg] = fmaxf(acc[mf][pf][rg], 0.f);
          }
        }
        ushort4 st;
        st.x = f2h_bits(acc[mf][pf][0]); st.y = f2h_bits(acc[mf][pf][1]);
        st.z = f2h_bits(acc[mf][pf][2]); st.w = f2h_bits(acc[mf][pf][3]);
        *reinterpret_cast<ushort4*>(outB + ((size_t)n * NPIXO + opix) * COB + co0 + mf * 16 + lg * 4) = st;
      }
    }
    if constexpr (EPI == 0) {
      __syncthreads();
      float* sl = (float*)lds;
#pragma unroll
      for (int mf = 0; mf < MFR; ++mf) {
#pragma unroll
        for (int rg = 0; rg < 4; ++rg) {
          float s = 0.f, q2 = 0.f;
#pragma unroll
          for (int pf = 0; pf < WPIX; ++pf) {
            const float v = acc[mf][pf][rg];
            s += v; q2 += v * v;
          }
#pragma unroll
          for (int o = 1; o < 16; o <<= 1) { s += __shfl_xor(s, o); q2 += __shfl_xor(q2, o); }
          if (ln == 0) {
            const int cl = mf * 16 + lg * 4 + rg;
            sl[(wid * MFR * 16 + cl) * 2 + 0] = s;
            sl[(wid * MFR * 16 + cl) * 2 + 1] = q2;
          }
        }
      }
      __syncthreads();
      const int NPB = gridDim.x * gridDim.z;
      const int pb = (int)blockIdx.x * gridDim.z + blockIdx.z;
      for (int i = tid; i < MFR * 16 * 2; i += 256) {
        const int cl = i >> 1, stt = i & 1;
        float tot = 0.f;
#pragma unroll
        for (int w = 0; w < 4; ++w) tot += sl[(w * MFR * 16 + cl) * 2 + stt];
        statL[(size_t)((co0 + cl) * 2 + stt) * NPB + pb] = tot;
      }
    }
  }
  (void)outF;
}

// ---------------------------------------------------------------- efuse: e1+e2+e3 fused via LDS relays
__global__ __launch_bounds__(256) void efuse(
    const hf* __restrict__ f2s_, const hf* __restrict__ sA_,
    const hf* __restrict__ w1p, const float* __restrict__ b1v, const float* __restrict__ dtE,
    const hf* __restrict__ w2p, const float* __restrict__ b2v,
    const hf* __restrict__ w3p, const float* __restrict__ b3v,
    hf* __restrict__ outB) {
  constexpr int PSTRE = 72;
  __shared__ __align__(16) hf ldsA[256 * PSTRE];
  __shared__ __align__(16) hf ldsB[256 * PSTRE];

  const int tid = threadIdx.x;
  const int wid = tid >> 6, lane = tid & 63, lg = lane >> 4, ln = lane & 15;
  const int n = blockIdx.z, b = n / 81, ij = n - b * 81;
  const int r0 = blockIdx.x * 4;
  const float di = (float)(ij / 9) - 4.f, dj = (float)(ij % 9) - 4.f;

  // e1: (f1,f2s) 64 -> 48
  f32x4 acc1[3][4];
#pragma unroll
  for (int mf = 0; mf < 3; ++mf)
#pragma unroll
    for (int pf = 0; pf < 4; ++pf) acc1[mf][pf] = (f32x4){0.f, 0.f, 0.f, 0.f};
#pragma unroll
  for (int ch = 0; ch < 2; ++ch) {
    const int k0 = ch * 32;
    h8v afr[3];
#pragma unroll
    for (int mf = 0; mf < 3; ++mf)
      afr[mf] = *(const h8v*)(w1p + ((size_t)(mf * 16 + ln)) * 64 + k0 + lg * 8);
#pragma unroll
    for (int pf = 0; pf < 4; ++pf) {
      const int pix = r0 * 64 + wid * 64 + pf * 16 + ln;
      const h8v bfr = (ch == 0)
          ? *(const h8v*)(sA_ + (((size_t)b * 4096 + pix) * 32 + lg * 8))
          : *(const h8v*)(f2s_ + (((size_t)n * 4096 + pix) * 32 + lg * 8));
#pragma unroll
      for (int mf = 0; mf < 3; ++mf)
        acc1[mf][pf] = __builtin_amdgcn_mfma_f32_16x16x32_f16(afr[mf], bfr, acc1[mf][pf], 0, 0, 0);
    }
  }
#pragma unroll
  for (int mf = 0; mf < 3; ++mf) {
#pragma unroll
    for (int pf = 0; pf < 4; ++pf) {
      const int pixL = wid * 64 + pf * 16 + ln;
#pragma unroll
      for (int rg = 0; rg < 4; ++rg) {
        const int co = mf * 16 + lg * 4 + rg;
        acc1[mf][pf][rg] += di * dtE[co * 2] + dj * dtE[co * 2 + 1];
      }
      const float4 bv = *(const float4*)(b1v + mf * 16 + lg * 4);
      acc1[mf][pf][0] += bv.x; acc1[mf][pf][1] += bv.y;
      acc1[mf][pf][2] += bv.z; acc1[mf][pf][3] += bv.w;
#pragma unroll
      for (int rg = 0; rg < 4; ++rg) acc1[mf][pf][rg] = fmaxf(acc1[mf][pf][rg], 0.f);
      ushort4 st;
      st.x = f2h_bits(acc1[mf][pf][0]); st.y = f2h_bits(acc1[mf][pf][1]);
      st.z = f2h_bits(acc1[mf][pf][2]); st.w = f2h_bits(acc1[mf][pf][3]);
      *reinterpret_cast<ushort4*>(&ldsA[(size_t)pixL * PSTRE + mf * 16 + lg * 4]) = st;
    }
  }
  for (int z = tid; z < 256 * 16; z += 256)
    ldsA[(size_t)(z >> 4) * PSTRE + 48 + (z & 15)] = (hf)0.f;
  __syncthreads();

  // e2: 48(+pad) -> 64
  f32x4 acc2[4][4];
#pragma unroll
  for (int mf = 0; mf < 4; ++mf)
#pragma unroll
    for (int pf = 0; pf < 4; ++pf) acc2[mf][pf] = (f32x4){0.f, 0.f, 0.f, 0.f};
#pragma unroll
  for (int ch = 0; ch < 2; ++ch) {
    const int k0 = ch * 32;
    h8v afr[4];
#pragma unroll
    for (int mf = 0; mf < 4; ++mf)
      afr[mf] = *(const h8v*)(w2p + ((size_t)(mf * 16 + ln)) * 64 + k0 + lg * 8);
#pragma unroll
    for (int pf = 0; pf < 4; ++pf) {
      const int pixL = wid * 64 + pf * 16 + ln;
      const h8v bfr = *(const h8v*)(&ldsA[(size_t)pixL * PSTRE + k0 + lg * 8]);
#pragma unroll
      for (int mf = 0; mf < 4; ++mf)
        acc2[mf][pf] = __builtin_amdgcn_mfma_f32_16x16x32_f16(afr[mf], bfr, acc2[mf][pf], 0, 0, 0);
    }
  }
#pragma unroll
  for (int mf = 0; mf < 4; ++mf) {
#pragma unroll
    for (int pf = 0; pf < 4; ++pf) {
      const int pixL = wid * 64 + pf * 16 + ln;
      const float4 bv = *(const float4*)(b2v + mf * 16 + lg * 4);
      acc2[mf][pf][0] += bv.x; acc2[mf][pf][1] += bv.y;
      acc2[mf][pf][2] += bv.z; acc2[mf][pf][3] += bv.w;
#pragma unroll
      for (int rg = 0; rg < 4; ++rg) acc2[mf][pf][rg] = fmaxf(acc2[mf][pf][rg], 0.f);
      ushort4 st;
      st.x = f2h_bits(acc2[mf][pf][0]); st.y = f2h_bits(acc2[mf][pf][1]);
      st.z = f2h_bits(acc2[mf][pf][2]); st.w = f2h_bits(acc2[mf][pf][3]);
      *reinterpret_cast<ushort4*>(&ldsB[(size_t)pixL * PSTRE + mf * 16 + lg * 4]) = st;
    }
  }
  __syncthreads();

  // e3: 64 -> 32 -> global
  f32x4 acc3[2][4];
#pragma unroll
  for (int mf = 0; mf < 2; ++mf)
#pragma unroll
    for (int pf = 0; pf < 4; ++pf) acc3[mf][pf] = (f32x4){0.f, 0.f, 0.f, 0.f};
#pragma unroll
  for (int ch = 0; ch < 2; ++ch) {
    const int k0 = ch * 32;
    h8v afr[2];
#pragma unroll
    for (int mf = 0; mf < 2; ++mf)
      afr[mf] = *(const h8v*)(w3p + ((size_t)(mf * 16 + ln)) * 64 + k0 + lg * 8);
#pragma unroll
    for (int pf = 0; pf < 4; ++pf) {
      const int pixL = wid * 64 + pf * 16 + ln;
      const h8v bfr = *(const h8v*)(&ldsB[(size_t)pixL * PSTRE + k0 + lg * 8]);
#pragma unroll
      for (int mf = 0; mf < 2; ++mf)
        acc3[mf][pf] = __builtin_amdgcn_mfma_f32_16x16x32_f16(afr[mf], bfr, acc3[mf][pf], 0, 0, 0);
    }
  }
#pragma unroll
  for (int mf = 0; mf < 2; ++mf) {
#pragma unroll
    for (int pf = 0; pf < 4; ++pf) {
      const int pix = r0 * 64 + wid * 64 + pf * 16 + ln;
      const float4 bv = *(const float4*)(b3v + mf * 16 + lg * 4);
      acc3[mf][pf][0] += bv.x; acc3[mf][pf][1] += bv.y;
      acc3[mf][pf][2] += bv.z; acc3[mf][pf][3] += bv.w;
      ushort4 st;
      st.x = f2h_bits(acc3[mf][pf][0]); st.y = f2h_bits(acc3[mf][pf][1]);
      st.z = f2h_bits(acc3[mf][pf][2]); st.w = f2h_bits(acc3[mf][pf][3]);
      *reinterpret_cast<ushort4*>(outB + (((size_t)n * 4096 + pix) * 32 + mf * 16 + lg * 4)) = st;
    }
  }
}

// ---------------------------------------------------------------- mconv2s2 (stats -> partial store)
__global__ __launch_bounds__(256) void mconv2s2(
    const hf* __restrict__ src1, const hf* __restrict__ wp,
    const float* __restrict__ bnst, float* __restrict__ statL, hf* __restrict__ outB) {
  constexpr int IMGI = 64, IMGO = 32;
  constexpr int PIXROWS = 4, WPIX = 2, MFR = 4;
  constexpr int TR = 2 * PIXROWS + 1;
  constexpr int TC = 65;
  constexpr int NSLOT = TR * TC;
  constexpr int PSTR = NSLOT + 1;
  constexpr int NCH = 3;
  constexpr int G = 96;
  constexpr int NPIXI = IMGI * IMGI;
  constexpr int NCHUNK = NSLOT * 4;
  constexpr int COT = MFR * 16;
  constexpr int COP = 128;
  constexpr int WPLANE = 3 * COT;
  constexpr int WPSTR  = WPLANE + 1;
  constexpr int WCHUNK = WPLANE * 4;

  __shared__ __align__(16) hf alds[4 * PSTR * 8];
  __shared__ __align__(16) hf wlds[4 * WPSTR * 8];

  const int tid = threadIdx.x;
  const int wid = tid >> 6, lane = tid & 63, lg = lane >> 4, ln = lane & 15;
  const int n = blockIdx.z;
  const int r0 = blockIdx.x * PIXROWS;
  const int co0 = (int)blockIdx.y * COT;

  f32x4 acc[MFR][WPIX];
#pragma unroll
  for (int mf = 0; mf < MFR; ++mf)
#pragma unroll
    for (int pf = 0; pf < WPIX; ++pf) acc[mf][pf] = (f32x4){0.f, 0.f, 0.f, 0.f};

  for (int ks = 0; ks < NCH; ++ks) {
    const int k0 = ks * 32;
    __syncthreads();
    for (int cidx = tid; cidx < NCHUNK; cidx += 256) {
      const int s = cidx >> 2, p = cidx & 3;
      const int rs = s / TC, cs = s - rs * TC;
      const int ir = 2 * r0 - 1 + rs;
      const int ic = (cs < 32) ? 2 * cs : 2 * (cs - 32) - 1;
      s8v v = (s8v){0, 0, 0, 0, 0, 0, 0, 0};
      const int gci = k0 + p * 8;
      if (((unsigned)ir < (unsigned)IMGI) && ((unsigned)ic < (unsigned)IMGI)) {
        const int ipix = ir * IMGI + ic;
        v = *(const s8v*)(src1 + (((size_t)n * NPIXI + ipix) * G + gci));
        v = bnin_apply(v, bnst, gci);
      }
      *(s8v*)(&alds[(size_t)(p * PSTR + s) * 8]) = v;
    }
#pragma unroll
    for (int tg = 0; tg < 3; ++tg) {
      if (tg > 0) __syncthreads();
      for (int widx = tid; widx < WCHUNK; widx += 256) {
        const int p = widx & 3;
        const int r = widx >> 2;
        const int co = r & (COT - 1);
        const int tt = r >> 6;
        const int tglob = tg * 3 + tt;
        const s8v wv = *(const s8v*)(wp + (((size_t)(tglob * NCH + ks) * COP + co0 + co) * 32 + p * 8));
        *(s8v*)(&wlds[(size_t)(p * WPSTR + r) * 8]) = wv;
      }
      __syncthreads();
#pragma unroll
      for (int tt = 0; tt < 3; ++tt) {
        const int kh = tg, kw = tt;
        h8v afr[MFR];
#pragma unroll
        for (int mf = 0; mf < MFR; ++mf)
          afr[mf] = *(const h8v*)(&wlds[(size_t)(lg * WPSTR + tt * COT + mf * 16 + ln) * 8]);
#pragma unroll
        for (int pf = 0; pf < WPIX; ++pf) {
          const int pl = wid * (WPIX * 16) + pf * 16 + ln;
          const int rL = pl / IMGO, c = pl - rL * IMGO;
          const int slot = (2 * rL + kh) * 65 + ((kw == 1) ? c : (32 + c + (kw >> 1)));
          const h8v bfr = *(const h8v*)(&alds[(size_t)(lg * PSTR + slot) * 8]);
#pragma unroll
          for (int mf = 0; mf < MFR; ++mf)
            acc[mf][pf] = __builtin_amdgcn_mfma_f32_16x16x32_f16(afr[mf], bfr, acc[mf][pf], 0, 0, 0);
        }
      }
    }
  }

#pragma unroll
  for (int mf = 0; mf < MFR; ++mf) {
#pragma unroll
    for (int pf = 0; pf < WPIX; ++pf) {
      const int pl = wid * (WPIX * 16) + pf * 16 + ln;
      const int rL = pl / IMGO, c = pl - rL * IMGO;
      const int opix = (r0 + rL) * IMGO + c;
      ushort4 st;
      st.x = f2h_bits(acc[mf][pf][0]); st.y = f2h_bits(acc[mf][pf][1]);
      st.z = f2h_bits(acc[mf][pf][2]); st.w = f2h_bits(acc[mf][pf][3]);
      *reinterpret_cast<ushort4*>(outB + ((size_t)n * 1024 + opix) * COP + co0 + mf * 16 + lg * 4) = st;
    }
  }
  __syncthreads();
  float* sl = (float*)alds;
#pragma unroll
  for (int mf = 0; mf < MFR; ++mf) {
#pragma unroll
    for (int rg = 0; rg < 4; ++rg) {
      float s = 0.f, q2 = 0.f;
#pragma unroll
      for (int pf = 0; pf < WPIX; ++pf) {
        const float v = acc[mf][pf][rg];
        s += v; q2 += v * v;
      }
#pragma unroll
      for (int o = 1; o < 16; o <<= 1) { s += __shfl_xor(s, o); q2 += __shfl_xor(q2, o); }
      if (ln == 0) {
        const int cl = mf * 16 + lg * 4 + rg;
        sl[(wid * MFR * 16 + cl) * 2 + 0] = s;
        sl[(wid * MFR * 16 + cl) * 2 + 1] = q2;
      }
    }
  }
  __syncthreads();
  const int NPB = gridDim.x * gridDim.z;
  const int pb = (int)blockIdx.x * gridDim.z + blockIdx.z;
  for (int i = tid; i < MFR * 16 * 2; i += 256) {
    const int cl = i >> 1, stt = i & 1;
    float tot = 0.f;
#pragma unroll
    for (int w = 0; w < 4; ++w) tot += sl[(w * MFR * 16 + cl) * 2 + stt];
    statL[(size_t)((co0 + cl) * 2 + stt) * NPB + pb] = tot;
  }
}

// ---------------------------------------------------------------- mconv2 (stats -> partial store)
template <int G, int COP, int MFR, int PIXROWS, int WPIX, bool BNIN>
__global__ __launch_bounds__(256) void mconv2(
    const hf* __restrict__ src1, const hf* __restrict__ wp,
    const float* __restrict__ bnst,
    float* __restrict__ statL, hf* __restrict__ outB) {
  constexpr int IMG = 32;
  constexpr int TAPS = 9;
  constexpr int TC = IMG + 2;
  constexpr int TR = PIXROWS + 2;
  constexpr int NSLOT = TR * TC;
  constexpr int PSTR = NSLOT + 1;
  constexpr int NCH = G / 32;
  constexpr int NPIX = IMG * IMG;
  constexpr int NCHUNK = NSLOT * 4;
  constexpr int COT = MFR * 16;
  constexpr int WPLANE = TAPS * COT;
  constexpr int WPSTR  = WPLANE + 1;
  constexpr int WCHUNK = WPLANE * 4;

  __shared__ __align__(16) hf alds[4 * PSTR * 8];
  __shared__ __align__(16) hf wlds[4 * WPSTR * 8];

  const int tid = threadIdx.x;
  const int wid = tid >> 6, lane = tid & 63, lg = lane >> 4, ln = lane & 15;
  const int n = blockIdx.z;
  const int r0 = blockIdx.x * PIXROWS;
  const int co0 = blockIdx.y * COT;

  f32x4 acc[MFR][WPIX];
#pragma unroll
  for (int mf = 0; mf < MFR; ++mf)
#pragma unroll
    for (int pf = 0; pf < WPIX; ++pf) acc[mf][pf] = (f32x4){0.f, 0.f, 0.f, 0.f};

  for (int ks = 0; ks < NCH; ++ks) {
    __syncthreads();
    for (int cidx = tid; cidx < NCHUNK; cidx += 256) {
      const int s = cidx >> 2, p = cidx & 3;
      const int rs = s / TC, cs = s - rs * TC;
      const int ir = r0 - 1 + rs, ic = cs - 1;
      s8v v = (s8v){0, 0, 0, 0, 0, 0, 0, 0};
      if (((unsigned)ir < (unsigned)IMG) && ((unsigned)ic < (unsigned)IMG)) {
        const int ipix = ir * IMG + ic;
        v = *(const s8v*)(src1 + (((size_t)n * NPIX + ipix) * G + ks * 32 + p * 8));
        if constexpr (BNIN) v = bnin_apply(v, bnst, ks * 32 + p * 8);
      }
      *(s8v*)(&alds[(size_t)(p * PSTR + s) * 8]) = v;
    }
    for (int widx = tid; widx < WCHUNK; widx += 256) {
      const int p = widx & 3;
      const int r = widx >> 2;
      const int co = r & (COT - 1);
      const int t = r >> 6;
      const s8v wv = *(const s8v*)(wp + (((size_t)(t * NCH + ks) * COP + co0 + co) * 32 + p * 8));
      *(s8v*)(&wlds[(size_t)(p * WPSTR + r) * 8]) = wv;
    }
    __syncthreads();
#pragma unroll
    for (int t = 0; t < TAPS; ++t) {
      const int kh = t / 3, kw = t % 3;
      const int dh = kh - 1, dw = kw - 1;
      h8v afr[MFR];
#pragma unroll
      for (int mf = 0; mf < MFR; ++mf)
        afr[mf] = *(const h8v*)(&wlds[(size_t)(lg * WPSTR + t * COT + mf * 16 + ln) * 8]);
#pragma unroll
      for (int pf = 0; pf < WPIX; ++pf) {
        const int pl = wid * (WPIX * 16) + pf * 16 + ln;
        const int rL = pl / IMG, c = pl - rL * IMG;
        const int slot = (rL + dh + 1) * TC + (c + dw + 1);
        const h8v bfr = *(const h8v*)(&alds[(size_t)(lg * PSTR + slot) * 8]);
#pragma unroll
        for (int mf = 0; mf < MFR; ++mf)
          acc[mf][pf] = __builtin_amdgcn_mfma_f32_16x16x32_f16(afr[mf], bfr, acc[mf][pf], 0, 0, 0);
      }
    }
  }

#pragma unroll
  for (int mf = 0; mf < MFR; ++mf) {
#pragma unroll
    for (int pf = 0; pf < WPIX; ++pf) {
      const int pl = wid * (WPIX * 16) + pf * 16 + ln;
      const int rL = pl / IMG, c = pl - rL * IMG;
      const int opix = (r0 + rL) * IMG + c;
      ushort4 st;
      st.x = f2h_bits(acc[mf][pf][0]); st.y = f2h_bits(acc[mf][pf][1]);
      st.z = f2h_bits(acc[mf][pf][2]); st.w = f2h_bits(acc[mf][pf][3]);
      *reinterpret_cast<ushort4*>(outB + ((size_t)n * NPIX + opix) * COP + co0 + mf * 16 + lg * 4) = st;
    }
  }
  __syncthreads();
  float* sl = (float*)alds;
#pragma unroll
  for (int mf = 0; mf < MFR; ++mf) {
#pragma unroll
    for (int rg = 0; rg < 4; ++rg) {
      float s = 0.f, q2 = 0.f;
#pragma unroll
      for (int pf = 0; pf < WPIX; ++pf) {
        const float v = acc[mf][pf][rg];
        s += v; q2 += v * v;
      }
#pragma unroll
      for (int o = 1; o < 16; o <<= 1) { s += __shfl_xor(s, o); q2 += __shfl_xor(q2, o); }
      if (ln == 0) {
        const int cl = mf * 16 + lg * 4 + rg;
        sl[(wid * MFR * 16 + cl) * 2 + 0] = s;
        sl[(wid * MFR * 16 + cl) * 2 + 1] = q2;
      }
    }
  }
  __syncthreads();
  const int NPB = gridDim.x * gridDim.z;
  const int pb = (int)blockIdx.x * gridDim.z + blockIdx.z;
  for (int i = tid; i < MFR * 16 * 2; i += 256) {
    const int cl = i >> 1, stt = i & 1;
    float tot = 0.f;
#pragma unroll
    for (int w = 0; w < 4; ++w) tot += sl[(w * MFR * 16 + cl) * 2 + stt];
    statL[(size_t)((co0 + cl) * 2 + stt) * NPB + pb] = tot;
  }
}

// ---------------------------------------------------------------- mconv2d (stats -> partial store)
__global__ __launch_bounds__(256) void mconv2d(
    const hf* __restrict__ src1, const hf* __restrict__ wp,
    const float* __restrict__ bnst,
    float* __restrict__ statL, hf* __restrict__ outB) {
  constexpr int IMG = 32;
  constexpr int TAPS = 4;
  constexpr int PIXROWS = 8;
  constexpr int WPIX = 4;
  constexpr int MFR = 2;
  constexpr int TC = IMG + 2;
  constexpr int TR = PIXROWS + 2;
  constexpr int NSLOT = TR * TC;
  constexpr int PSTR = NSLOT + 1;
  constexpr int NCH = 2;
  constexpr int NPIX = IMG * IMG;
  constexpr int NCHUNK = NSLOT * 4;
  constexpr int COT = MFR * 16;
  constexpr int WPLANE = TAPS * COT;
  constexpr int WPSTR  = WPLANE + 1;
  constexpr int WCHUNK = WPLANE * 4;
  constexpr int G = 64;

  __shared__ __align__(16) hf alds[4 * PSTR * 8];
  __shared__ __align__(16) hf wlds[4 * WPSTR * 8];

  const int tid = threadIdx.x;
  const int wid = tid >> 6, lane = tid & 63, lg = lane >> 4, ln = lane & 15;
  const int n = blockIdx.z;
  const int r0 = blockIdx.x * PIXROWS;
  const int par = blockIdx.y;
  const int qq = par >> 1, pp = par & 1;
  const hf* wbase = wp + (size_t)par * (TAPS * NCH * COT * 32);

  f32x4 acc[MFR][WPIX];
#pragma unroll
  for (int mf = 0; mf < MFR; ++mf)
#pragma unroll
    for (int pf = 0; pf < WPIX; ++pf) acc[mf][pf] = (f32x4){0.f, 0.f, 0.f, 0.f};

  for (int ks = 0; ks < NCH; ++ks) {
    __syncthreads();
    const int k0 = ks * 32;
    for (int cidx = tid; cidx < NCHUNK; cidx += 256) {
      const int s = cidx >> 2, p = cidx & 3;
      const int rs = s / TC, cs = s - rs * TC;
      const int ir = r0 - 1 + rs, ic = cs - 1;
      s8v v = (s8v){0, 0, 0, 0, 0, 0, 0, 0};
      if (((unsigned)ir < (unsigned)IMG) && ((unsigned)ic < (unsigned)IMG)) {
        const int ipix = ir * IMG + ic;
        v = *(const s8v*)(src1 + (((size_t)n * NPIX + ipix) * G + k0 + p * 8));
        v = bnin_apply(v, bnst, k0 + p * 8);
      }
      *(s8v*)(&alds[(size_t)(p * PSTR + s) * 8]) = v;
    }
    for (int widx = tid; widx < WCHUNK; widx += 256) {
      const int p = widx & 3;
      const int r = widx >> 2;
      const int co = r & (COT - 1);
      const int t = r >> 5;
      const s8v wv = *(const s8v*)(wbase + (((size_t)(t * NCH + ks) * COT + co) * 32 + p * 8));
      *(s8v*)(&wlds[(size_t)(p * WPSTR + r) * 8]) = wv;
    }
    __syncthreads();
#pragma unroll
    for (int t = 0; t < TAPS; ++t) {
      const int dh = qq + (t >> 1) - 1;
      const int dw = pp + (t & 1) - 1;
      h8v afr[MFR];
#pragma unroll
      for (int mf = 0; mf < MFR; ++mf)
        afr[mf] = *(const h8v*)(&wlds[(size_t)(lg * WPSTR + t * COT + mf * 16 + ln) * 8]);
#pragma unroll
      for (int pf = 0; pf < WPIX; ++pf) {
        const int pl = wid * (WPIX * 16) + pf * 16 + ln;
        const int rL = pl / IMG, c = pl - rL * IMG;
        const int slot = (rL + dh + 1) * TC + (c + dw + 1);
        const h8v bfr = *(const h8v*)(&alds[(size_t)(lg * PSTR + slot) * 8]);
#pragma unroll
        for (int mf = 0; mf < MFR; ++mf)
          acc[mf][pf] = __builtin_amdgcn_mfma_f32_16x16x32_f16(afr[mf], bfr, acc[mf][pf], 0, 0, 0);
      }
    }
  }

#pragma unroll
  for (int mf = 0; mf < MFR; ++mf) {
#pragma unroll
    for (int pf = 0; pf < WPIX; ++pf) {
      const int pl = wid * (WPIX * 16) + pf * 16 + ln;
      const int rL = pl / IMG, c = pl - rL * IMG;
      const int opix = (2 * (r0 + rL) + qq) * 64 + 2 * c + pp;
      ushort4 st;
      st.x = f2h_bits(acc[mf][pf][0]); st.y = f2h_bits(acc[mf][pf][1]);
      st.z = f2h_bits(acc[mf][pf][2]); st.w = f2h_bits(acc[mf][pf][3]);
      *reinterpret_cast<ushort4*>(outB + ((size_t)n * 4096 + opix) * 32 + mf * 16 + lg * 4) = st;
    }
  }
  __syncthreads();
  float* sl = (float*)alds;
#pragma unroll
  for (int mf = 0; mf < MFR; ++mf) {
#pragma unroll
    for (int rg = 0; rg < 4; ++rg) {
      float s = 0.f, q2 = 0.f;
#pragma unroll
      for (int pf = 0; pf < WPIX; ++pf) {
        const float v = acc[mf][pf][rg];
        s += v; q2 += v * v;
      }
#pragma unroll
      for (int o = 1; o < 16; o <<= 1) { s += __shfl_xor(s, o); q2 += __shfl_xor(q2, o); }
      if (ln == 0) {
        const int cl = mf * 16 + lg * 4 + rg;
        sl[(wid * MFR * 16 + cl) * 2 + 0] = s;
        sl[(wid * MFR * 16 + cl) * 2 + 1] = q2;
      }
    }
  }
  __syncthreads();
  const int NPB = gridDim.x * gridDim.y * gridDim.z;
  const int pb = ((int)blockIdx.y * gridDim.x + blockIdx.x) * gridDim.z + blockIdx.z;
  for (int i = tid; i < MFR * 16 * 2; i += 256) {
    const int cl = i >> 1, stt = i & 1;
    float tot = 0.f;
#pragma unroll
    for (int w = 0; w < 4; ++w) tot += sl[(w * MFR * 16 + cl) * 2 + stt];
    statL[(size_t)(cl * 2 + stt) * NPB + pb] = tot;
  }
}

// ---------------------------------------------------------------- deterministic stat reduction (f64 exact)
__global__ __launch_bounds__(256) void bnred(const float* __restrict__ part,
                                             double* __restrict__ statD, int NPB) {
  const int chstat = blockIdx.x;
  const int t = threadIdx.x;
  double s = 0.0;
  for (int p = t; p < NPB; p += 256) s += (double)part[(size_t)chstat * NPB + p];
#pragma unroll
  for (int o = 1; o < 64; o <<= 1) s += __shfl_xor(s, o);
  __shared__ double wsum[4];
  if ((t & 63) == 0) wsum[t >> 6] = s;
  __syncthreads();
  if (t == 0) statD[chstat] = (wsum[0] + wsum[1]) + (wsum[2] + wsum[3]);
}

// ---------------------------------------------------------------- BN finalize (f64)
__global__ void bnfin_kernel(const double* __restrict__ statD, float* __restrict__ statL,
                             const float* __restrict__ g, const float* __restrict__ bt,
                             int C, double invCnt) {
  const int c = threadIdx.x;
  if (c < C) {
    const double m = statD[2 * c] * invCnt;
    const double var = statD[2 * c + 1] * invCnt - m * m;
    const double sc = (double)g[c] / sqrt(var + 1e-5);
    statL[256 + c] = (float)sc;
    statL[384 + c] = (float)((double)bt[c] - m * sc);
  }
}

// ---------------------------------------------------------------- conv5 (CO=1) on VALU, BN-on-read
__global__ __launch_bounds__(256) void conv5_kernel(
    const hf* __restrict__ xd, const float* __restrict__ w5, const float* __restrict__ b5,
    const float* __restrict__ bnst, float* __restrict__ outp) {
  const int gid = blockIdx.x * 256 + threadIdx.x;  // 162*4096
  const int n = gid >> 12, pix = gid & 4095;
  const int b = n / 81, ij = n - b * 81;
  const int oh = pix >> 6, ow = pix & 63;
  float acc = b5[0];
#pragma unroll
  for (int kh = 0; kh < 3; ++kh) {
    const int ih = oh + kh - 1;
#pragma unroll
    for (int kw = 0; kw < 3; ++kw) {
      const int iw = ow + kw - 1;
      if (((unsigned)ih < 64u) && ((unsigned)iw < 64u)) {
        const hf* xp = xd + ((size_t)n * 4096 + ih * 64 + iw) * 32;
#pragma unroll
        for (int cq = 0; cq < 4; ++cq) {
          const h8v v = *(const h8v*)(xp + cq * 8);
#pragma unroll
          for (int j = 0; j < 8; ++j) {
            const int c = cq * 8 + j;
            const float t = (hf)fmaxf((float)v[j] * bnst[256 + c] + bnst[384 + c], 0.f);
            acc += t * w5[c * 9 + kh * 3 + kw];
          }
        }
      }
    }
  }
  outp[((size_t)(b * 113 + ij)) * 4096 + pix] = acc;
}

// ---------------------------------------------------------------- DAP softmax
__global__ __launch_bounds__(64) void softmax_kernel(
    const float* __restrict__ outp, const float* __restrict__ dapw, float* __restrict__ score) {
  __shared__ float cb[64 * 81];
  __shared__ float sb[64 * 81];
  const int t = threadIdx.x;
  const int gid = blockIdx.x * 64 + t;
  const int b = gid >> 12, hw = gid & 4095;
  for (int d = 0; d < 81; ++d)
    cb[t * 81 + d] = outp[((size_t)(b * 113 + d)) * 4096 + hw];
  float smax = -1e30f;
  for (int o = 0; o < 81; ++o) {
    float s = 0.f;
    const float* dr = dapw + o * 81;
    for (int d = 0; d < 81; ++d) s += dr[d] * cb[t * 81 + d];
    sb[t * 81 + o] = s;
    smax = fmaxf(smax, s);
  }
  float sum = 0.f;
  for (int o = 0; o < 81; ++o) {
    const float e = __expf(sb[t * 81 + o] - smax);
    sb[t * 81 + o] = e;
    sum += e;
  }
  const float inv = 1.f / sum;
  for (int o = 0; o < 81; ++o)
    score[((size_t)(b * 81 + o)) * 4096 + hw] = sb[t * 81 + o] * inv;
}

// ---------------------------------------------------------------- emb reduce
__global__ __launch_bounds__(256) void emb_kernel(
    const float* __restrict__ score, const hf* __restrict__ e3, float* __restrict__ outp) {
  const int idx = blockIdx.x * 256 + threadIdx.x;  // 2*32*4096
  const int b = idx >> 17, r = idx & 131071, m = r >> 12, hw = r & 4095;
  float acc = 0.f;
  for (int d = 0; d < 81; ++d) {
    const float sc = score[((size_t)(b * 81 + d)) * 4096 + hw];
    acc += sc * (float)e3[(((size_t)(b * 81 + d)) * 4096 + hw) * 32 + m];
  }
  outp[((size_t)(b * 113 + 81 + m)) * 4096 + hw] = acc;
}

// ======================================================================
extern "C" void kernel_launch(void* const* d_in, const int* in_sizes, int n_in,
                              void* d_out, int out_size, void* d_ws, size_t ws_size,
                              hipStream_t stream) {
  const float* f1     = (const float*)d_in[0];
  const float* f2     = (const float*)d_in[1];
  const float* coords = (const float*)d_in[2];
  const float* w1     = (const float*)d_in[3];
  const float* g1     = (const float*)d_in[4];
  const float* bb1    = (const float*)d_in[5];
  const float* w2     = (const float*)d_in[6];
  const float* g2     = (const float*)d_in[7];
  const float* bb2    = (const float*)d_in[8];
  const float* w3     = (const float*)d_in[9];
  const float* g3     = (const float*)d_in[10];
  const float* bb3    = (const float*)d_in[11];
  const float* w4     = (const float*)d_in[12];
  const float* g4     = (const float*)d_in[13];
  const float* bb4    = (const float*)d_in[14];
  const float* wdcv   = (const float*)d_in[15];
  const float* gd     = (const float*)d_in[16];
  const float* bbd    = (const float*)d_in[17];
  const float* w5     = (const float*)d_in[18];
  const float* b5     = (const float*)d_in[19];
  const float* e1w    = (const float*)d_in[20];
  const float* e1bi   = (const float*)d_in[21];
  const float* e2w    = (const float*)d_in[22];
  const float* e2bi   = (const float*)d_in[23];
  const float* e3w    = (const float*)d_in[24];
  const float* e3bi   = (const float*)d_in[25];
  const float* dapw   = (const float*)d_in[26];
  float* out = (float*)d_out;
  char* ws = (char*)d_ws;

  hf* sA  = (hf*)(ws + OFF_SA);
  hf* f2s = (hf*)(ws + OFF_F2S);
  hf* be3 = (hf*)(ws + OFF_E3);
  hf* x1  = (hf*)(ws + OFF_X1);
  hf* x2  = (hf*)(ws + OFF_X2);
  hf* x3  = (hf*)(ws + OFF_X3);
  hf* x4  = (hf*)(ws + OFF_X4);
  hf* xd  = (hf*)(ws + OFF_XD);
  float* score = (float*)(ws + OFF_SCORE);
  float* stats = (float*)(ws + OFF_STATS);
  hf* wc1 = (hf*)(ws + OFF_WC1);
  hf* wc2 = (hf*)(ws + OFF_WC2);
  hf* wc3 = (hf*)(ws + OFF_WC3);
  hf* wc4 = (hf*)(ws + OFF_WC4);
  hf* wdc = (hf*)(ws + OFF_WDC);
  hf* we1 = (hf*)(ws + OFF_WE1);
  hf* we2 = (hf*)(ws + OFF_WE2);
  hf* we3 = (hf*)(ws + OFF_WE3);
  float* dt1 = (float*)(ws + OFF_DT1);
  float* dtE = (float*)(ws + OFF_DTE);
  float* f2clf = (float*)(ws + OFF_F2CLF);
  float* part = (float*)(ws + OFF_PART);
  double* statD = (double*)(ws + OFF_STATD);

  hipMemsetAsync(stats, 0, 2560 * sizeof(float), stream);

  // weight prepacks (identical to r23)
  prepack<<<216, 256, 0, stream>>>(w1,   wc1, 96, 96, 64, 66, 64, 9);
  prepack2<<<432, 256, 0, stream>>>(w2,  wc2, 128, 96, 3);
  prepack2<<<576, 256, 0, stream>>>(w3,  wc3, 128, 128, 4);
  prepack2<<<288, 256, 0, stream>>>(w4,  wc4, 64, 128, 4);
  prepack2d<<<128, 256, 0, stream>>>(wdcv, wdc);
  prepack<<<12,  256, 0, stream>>>(e1w,  we1, 48, 48, 64, 66, 64, 1);
  prepack<<<16,  256, 0, stream>>>(e2w,  we2, 64, 64, 48, 48, 64, 1);
  prepack<<<8,   256, 0, stream>>>(e3w,  we3, 32, 32, 64, 64, 64, 1);
  dtab1_kernel<<<7, 256, 0, stream>>>(w1, dt1);
  dtabE_kernel<<<1, 96, 0, stream>>>(e1w, dtE);

  // inputs (f2 interpolated in fp32)
  packf1<<<32, 256, 0, stream>>>(f1, sA);
  packf2f32<<<32, 256, 0, stream>>>(f2, f2clf);
  sample2<<<2592, 256, 0, stream>>>(f2clf, coords, f2s);

  // embedding branch: fused e1+e2+e3
  efuse<<<dim3(16, 1, 162), 256, 0, stream>>>(f2s, sA, we1, e1bi, dtE, we2, e2bi, we3, e3bi, be3);

  // conv1: r17 main path; stats via f64-exact deterministic reduction
  mconv<0, 0, true, false, 32, 64, 96, 96, 3, 64, 64, 4, 4, true>
      <<<dim3(16, 2, 162), 256, 0, stream>>>(f2s, sA, wc1, nullptr, dt1, part, nullptr, x1, nullptr);
  bnred<<<192, 256, 0, stream>>>(part, statD + 0, 2592);
  bnfin_kernel<<<1, 128, 0, stream>>>(statD + 0, stats + 0, g1, bb1, 96, 1.0 / 663552.0);

  // conv2: weight-LDS tap-split + BN1 on read
  mconv2s2<<<dim3(8, 2, 162), 256, 0, stream>>>(x1, wc2, stats + 0, part, x2);
  bnred<<<256, 256, 0, stream>>>(part, statD + 256, 1296);
  bnfin_kernel<<<1, 128, 0, stream>>>(statD + 256, stats + 512, g2, bb2, 128, 1.0 / 165888.0);

  // conv3: weight-LDS path + BN2 on read
  mconv2<128, 128, 4, 4, 2, true>
      <<<dim3(8, 2, 162), 256, 0, stream>>>(x2, wc3, stats + 512, part, x3);
  bnred<<<256, 256, 0, stream>>>(part, statD + 512, 1296);
  bnfin_kernel<<<1, 128, 0, stream>>>(statD + 512, stats + 1024, g3, bb3, 128, 1.0 / 165888.0);

  // conv4: weight-LDS path + BN3 on read
  mconv2<128, 64, 4, 4, 2, true>
      <<<dim3(8, 1, 162), 256, 0, stream>>>(x3, wc4, stats + 1024, part, x4);
  bnred<<<128, 256, 0, stream>>>(part, statD + 768, 1296);
  bnfin_kernel<<<1, 128, 0, stream>>>(statD + 768, stats + 1536, g4, bb4, 64, 1.0 / 165888.0);

  // deconv: weight-LDS path + BN4 on read
  mconv2d<<<dim3(4, 4, 162), 256, 0, stream>>>(x4, wdc, stats + 1536, part, xd);
  bnred<<<64, 256, 0, stream>>>(part, statD + 1024, 2592);
  bnfin_kernel<<<1, 128, 0, stream>>>(statD + 1024, stats + 2048, gd, bbd, 32, 1.0 / 663552.0);

  // conv5 on VALU + BNd on read -> cost planes of out
  conv5_kernel<<<2592, 256, 0, stream>>>(xd, w5, b5, stats + 2048, out);

  // DAP softmax + embedding reduction
  softmax_kernel<<<128, 64, 0, stream>>>(out, dapw, score);
  emb_kernel<<<1024, 256, 0, stream>>>(score, be3, out);

  (void)in_sizes; (void)n_in; (void)out_size; (void)ws_size;
}

// Round 26
// 780.209 us; speedup vs baseline: 1.3643x; 1.0235x over previous
//
#include <hip/hip_runtime.h>
#include <hip/hip_bf16.h>

typedef _Float16 hf;
typedef short    s8v  __attribute__((ext_vector_type(8)));
typedef _Float16 h8v  __attribute__((ext_vector_type(8)));
typedef float    f32x4 __attribute__((ext_vector_type(4)));

#define DEVINL __device__ __forceinline__

DEVINL unsigned short f2h_bits(float f) { return __builtin_bit_cast(unsigned short, (hf)f); }
DEVINL float h2f_bits(unsigned short u) { return (float)__builtin_bit_cast(hf, u); }

// ---------------------------------------------------------------- arena
static constexpr size_t OFF_SA    = 0;
static constexpr size_t OFF_F2S   = 524288;
static constexpr size_t OFF_E3    = 42991616;
static constexpr size_t OFF_X1    = 85458944;
static constexpr size_t OFF_X2    = 524288;
static constexpr size_t OFF_X3    = 85458944;
static constexpr size_t OFF_X4    = 524288;
static constexpr size_t OFF_XD    = 127926272;
static constexpr size_t OFF_SCORE = 524288;
static constexpr size_t OFF_STATS = 212860928;
static constexpr size_t OFF_WC1   = 212871168;
static constexpr size_t OFF_WC2   = 212981760;
static constexpr size_t OFF_WC3   = 213202944;
static constexpr size_t OFF_WC4   = 213497856;
static constexpr size_t OFF_WDC   = 213645312;
static constexpr size_t OFF_WE1   = 213720064;
static constexpr size_t OFF_WE2   = 213726208;
static constexpr size_t OFF_WE3   = 213734400;
static constexpr size_t OFF_DT1   = 213738496;
static constexpr size_t OFF_DTE   = 213745408;
static constexpr size_t OFF_F2CLF = 213746048;
static constexpr size_t OFF_PART  = 214794752;  // BN stat partials (fp32), reused per conv

// ---------------------------------------------------------------- prep sub-bodies (verbatim, idx-rebased)
DEVINL void prep_prepack(int idx, const float* __restrict__ src, hf* __restrict__ dst,
                         int COr, int COP, int CINr, int CINsrc, int KP, int TAPS) {
  const int total = TAPS * COP * KP;
  if (idx >= total) return;
  const int k = idx % KP;
  const int r = idx / KP;
  const int co = r % COP;
  const int t = r / COP;
  float v = 0.f;
  if (co < COr && k < CINr) v = src[((size_t)co * CINsrc + k) * TAPS + t];
  dst[idx] = (hf)v;
}

DEVINL void prep_prepack2(int idx, const float* __restrict__ src, hf* __restrict__ dst,
                          int COP, int CIN, int NCHn) {
  const int total = 9 * NCHn * COP * 32;
  if (idx >= total) return;
  const int kk = idx & 31;
  const int r = idx >> 5;
  const int co = r % COP;
  const int r2 = r / COP;
  const int ks = r2 % NCHn;
  const int t = r2 / NCHn;
  dst[idx] = (hf)src[((size_t)co * CIN + ks * 32 + kk) * 9 + t];
}

DEVINL void prep_prepack2d(int idx, const float* __restrict__ src, hf* __restrict__ dst) {
  if (idx >= 32768) return;
  const int kk = idx & 31;
  const int co = (idx >> 5) & 31;
  const int ks = (idx >> 10) & 1;
  const int tt = (idx >> 11) & 3;
  const int par = idx >> 13;
  const int qq = par >> 1, pp = par & 1;
  const int a = tt >> 1, b = tt & 1;
  dst[idx] = (hf)src[(((size_t)co * 64 + ks * 32 + kk) * 4 + (qq + 2 * a)) * 4 + (pp + 2 * b)];
}

DEVINL void prep_dtab1(int idx, const float* __restrict__ w1, float* __restrict__ dtab) {
  if (idx >= 96 * 9 * 2) return;
  const int c = idx & 1;
  const int r = idx >> 1;
  const int pat = r % 9;
  const int co = r / 9;
  const int rc = pat / 3, cc = pat % 3;
  const int kh0 = (rc == 0) ? 1 : 0, kh1 = (rc == 2) ? 1 : 2;
  const int kw0 = (cc == 0) ? 1 : 0, kw1 = (cc == 2) ? 1 : 2;
  float s = 0.f;
  for (int kh = kh0; kh <= kh1; ++kh)
    for (int kw = kw0; kw <= kw1; ++kw)
      s += w1[((size_t)(co * 66 + 64 + c) * 3 + kh) * 3 + kw];
  dtab[(co * 9 + pat) * 2 + c] = s;
}

DEVINL void prep_dtabE(int co, const float* __restrict__ e1w, float* __restrict__ dtE) {
  if (co < 48) {
    dtE[co * 2 + 0] = e1w[co * 66 + 64];
    dtE[co * 2 + 1] = e1w[co * 66 + 65];
  }
}

DEVINL void prep_packf1(int gid, const float* __restrict__ f1, hf* __restrict__ sA) {
  const int b = gid >> 12, pix = gid & 4095;
  unsigned words[16];
#pragma unroll
  for (int c = 0; c < 32; c += 2) {
    const float v0 = f1[((size_t)(b * 32 + c)) * 4096 + pix];
    const float v1 = f1[((size_t)(b * 32 + c + 1)) * 4096 + pix];
    words[c >> 1] = (unsigned)f2h_bits(v0) | ((unsigned)f2h_bits(v1) << 16);
  }
  uint4* dst = (uint4*)(sA + (size_t)gid * 32);
#pragma unroll
  for (int i = 0; i < 4; ++i)
    dst[i] = make_uint4(words[4 * i], words[4 * i + 1], words[4 * i + 2], words[4 * i + 3]);
}

DEVINL void prep_packf2(int gid, const float* __restrict__ f2, float* __restrict__ dst) {
  const int b = gid >> 12, pix = gid & 4095;
  float* op = dst + (size_t)gid * 32;
#pragma unroll
  for (int c = 0; c < 32; c += 4) {
    float4 v;
    v.x = f2[((size_t)(b * 32 + c + 0)) * 4096 + pix];
    v.y = f2[((size_t)(b * 32 + c + 1)) * 4096 + pix];
    v.z = f2[((size_t)(b * 32 + c + 2)) * 4096 + pix];
    v.w = f2[((size_t)(b * 32 + c + 3)) * 4096 + pix];
    *(float4*)(op + c) = v;
  }
}

// ---------------------------------------------------------------- prep mega-kernel (12 launches -> 1)
__global__ __launch_bounds__(256) void prep(
    const float* __restrict__ w1, const float* __restrict__ w2,
    const float* __restrict__ w3, const float* __restrict__ w4,
    const float* __restrict__ wdcv,
    const float* __restrict__ e1w, const float* __restrict__ e2w,
    const float* __restrict__ e3w,
    const float* __restrict__ f1, const float* __restrict__ f2,
    hf* __restrict__ wc1, hf* __restrict__ wc2, hf* __restrict__ wc3,
    hf* __restrict__ wc4, hf* __restrict__ wdc,
    hf* __restrict__ we1, hf* __restrict__ we2, hf* __restrict__ we3,
    float* __restrict__ dt1, float* __restrict__ dtE,
    hf* __restrict__ sA, float* __restrict__ f2clf) {
  const int b = blockIdx.x, t = threadIdx.x;
  if      (b < 216)  prep_prepack((b - 0) * 256 + t,    w1,  wc1, 96, 96, 64, 66, 64, 9);
  else if (b < 648)  prep_prepack2((b - 216) * 256 + t, w2,  wc2, 128, 96, 3);
  else if (b < 1224) prep_prepack2((b - 648) * 256 + t, w3,  wc3, 128, 128, 4);
  else if (b < 1512) prep_prepack2((b - 1224) * 256 + t, w4, wc4, 64, 128, 4);
  else if (b < 1640) prep_prepack2d((b - 1512) * 256 + t, wdcv, wdc);
  else if (b < 1652) prep_prepack((b - 1640) * 256 + t, e1w, we1, 48, 48, 64, 66, 64, 1);
  else if (b < 1668) prep_prepack((b - 1652) * 256 + t, e2w, we2, 64, 64, 48, 48, 64, 1);
  else if (b < 1676) prep_prepack((b - 1668) * 256 + t, e3w, we3, 32, 32, 64, 64, 64, 1);
  else if (b < 1683) prep_dtab1((b - 1676) * 256 + t,   w1,  dt1);
  else if (b < 1684) prep_dtabE(t, e1w, dtE);
  else if (b < 1716) prep_packf1((b - 1684) * 256 + t,  f1,  sA);
  else               prep_packf2((b - 1716) * 256 + t,  f2,  f2clf);
}

// ---------------------------------------------------------------- sample2
__global__ __launch_bounds__(256) void sample2(const float* __restrict__ f2clf,
                                               const float* __restrict__ coords,
                                               hf* __restrict__ f2s) {
  const int gid = blockIdx.x * 256 + threadIdx.x;  // 162*4096
  const int n = gid >> 12, pix = gid & 4095;
  const int b = n / 81, ij = n - b * 81;
  const float di = (float)(ij / 9) - 4.f, dj = (float)(ij % 9) - 4.f;
  const float x = coords[((size_t)(b * 2 + 0)) * 4096 + pix] + di;
  const float y = coords[((size_t)(b * 2 + 1)) * 4096 + pix] + dj;
  const float x0f = floorf(x), y0f = floorf(y);
  const int x0 = (int)x0f, y0 = (int)y0f;
  const float wx1 = x - x0f, wx0 = 1.f - wx1;
  const float wy1 = y - y0f, wy0 = 1.f - wy1;
  const bool vx0 = (unsigned)x0 < 64u, vx1 = (unsigned)(x0 + 1) < 64u;
  const bool vy0 = (unsigned)y0 < 64u, vy1 = (unsigned)(y0 + 1) < 64u;
  const int x0c = min(max(x0, 0), 63), x1c = min(max(x0 + 1, 0), 63);
  const int y0c = min(max(y0, 0), 63), y1c = min(max(y0 + 1, 0), 63);
  const float w00 = (vy0 && vx0) ? wy0 * wx0 : 0.f;
  const float w01 = (vy0 && vx1) ? wy0 * wx1 : 0.f;
  const float w10 = (vy1 && vx0) ? wy1 * wx0 : 0.f;
  const float w11 = (vy1 && vx1) ? wy1 * wx1 : 0.f;
  const float* fb = f2clf + (size_t)b * 4096 * 32;
  const float* p00 = fb + (size_t)(y0c * 64 + x0c) * 32;
  const float* p01 = fb + (size_t)(y0c * 64 + x1c) * 32;
  const float* p10 = fb + (size_t)(y1c * 64 + x0c) * 32;
  const float* p11 = fb + (size_t)(y1c * 64 + x1c) * 32;
  unsigned words[16];
#pragma unroll
  for (int ch = 0; ch < 16; ++ch) {
    const float2 a  = *(const float2*)(p00 + ch * 2);
    const float2 bb = *(const float2*)(p01 + ch * 2);
    const float2 c  = *(const float2*)(p10 + ch * 2);
    const float2 d  = *(const float2*)(p11 + ch * 2);
    const float v0 = w00 * a.x + w01 * bb.x + w10 * c.x + w11 * d.x;
    const float v1 = w00 * a.y + w01 * bb.y + w10 * c.y + w11 * d.y;
    words[ch] = (unsigned)f2h_bits(v0) | ((unsigned)f2h_bits(v1) << 16);
  }
  uint4* dst = (uint4*)(f2s + (size_t)gid * 32);
#pragma unroll
  for (int i = 0; i < 4; ++i)
    dst[i] = make_uint4(words[4 * i], words[4 * i + 1], words[4 * i + 2], words[4 * i + 3]);
}

// ---------------------------------------------------------------- BNIN helper
DEVINL s8v bnin_apply(s8v v, const float* bnst, int gci) {
  const f32x4 scA = *(const f32x4*)(bnst + 256 + gci);
  const f32x4 scB = *(const f32x4*)(bnst + 256 + gci + 4);
  const f32x4 shA = *(const f32x4*)(bnst + 384 + gci);
  const f32x4 shB = *(const f32x4*)(bnst + 384 + gci + 4);
  h8v h = __builtin_bit_cast(h8v, v);
#pragma unroll
  for (int jj = 0; jj < 8; ++jj) {
    const float sc = (jj < 4) ? scA[jj] : scB[jj - 4];
    const float sh = (jj < 4) ? shA[jj] : shB[jj - 4];
    h[jj] = (hf)fmaxf((float)h[jj] * sc + sh, 0.f);
  }
  return __builtin_bit_cast(s8v, h);
}

// ---------------------------------------------------------------- MFMA conv template (stats -> partial store)
template <int GEOM, int EPI, bool DUAL, bool BNIN, int G, int KP, int COP, int COB, int MFR,
          int IMGO, int IMGI, int PIXROWS, int WPIX, bool DELTA>
__global__ __launch_bounds__(256) void mconv(
    const hf* __restrict__ src1, const hf* __restrict__ src0,
    const hf* __restrict__ wp, const float* __restrict__ bias,
    const float* __restrict__ dtab, float* __restrict__ statL,
    const float* __restrict__ bnst,
    hf* __restrict__ outB, float* __restrict__ outF) {
  constexpr bool DIRECT = (GEOM == 3);
  constexpr int TAPS  = (GEOM == 2) ? 4 : (GEOM == 3) ? 1 : 9;
  constexpr int TR    = (GEOM == 1) ? (2 * PIXROWS + 1) : (GEOM == 3) ? 1 : (PIXROWS + 2);
  constexpr int TC    = (GEOM == 1) ? 65 : (GEOM == 3) ? 1 : (IMGI + 2);
  constexpr int NSLOT = TR * TC;
  constexpr int PSTR  = NSLOT + 1;
  constexpr int NCH   = KP / 32;
  constexpr int NPIXI = IMGI * IMGI;
  constexpr int NPIXO = (GEOM == 2) ? 4096 : IMGO * IMGO;
  constexpr int NCHUNK = NSLOT * 4;
  constexpr int CPT   = (NCHUNK + 255) / 256;
  constexpr int LDSE  = DIRECT ? 64 : 4 * PSTR * 8;

  __shared__ __align__(16) hf lds[LDSE];

  const int tid = threadIdx.x;
  const int wid = tid >> 6, lane = tid & 63, lg = lane >> 4, ln = lane & 15;
  const int n = blockIdx.z, b = n / 81, ij = n - b * 81;
  const int r0 = blockIdx.x * PIXROWS;
  const int qq = (GEOM == 2) ? (int)(blockIdx.y >> 1) : 0;
  const int pp = (GEOM == 2) ? (int)(blockIdx.y & 1) : 0;
  const int co0 = (GEOM == 2) ? 0 : (int)blockIdx.y * (MFR * 16);

  f32x4 acc[MFR][WPIX];
#pragma unroll
  for (int mf = 0; mf < MFR; ++mf)
#pragma unroll
    for (int pf = 0; pf < WPIX; ++pf) acc[mf][pf] = (f32x4){0.f, 0.f, 0.f, 0.f};

  if constexpr (DIRECT) {
#pragma unroll
    for (int ch = 0; ch < NCH; ++ch) {
      const int k0 = ch * 32;
      h8v afr[MFR];
#pragma unroll
      for (int mf = 0; mf < MFR; ++mf)
        afr[mf] = *(const h8v*)(wp + ((size_t)(co0 + mf * 16 + ln)) * KP + k0 + lg * 8);
#pragma unroll
      for (int pf = 0; pf < WPIX; ++pf) {
        const int pix = r0 * IMGO + wid * (WPIX * 16) + pf * 16 + ln;
        h8v bfr = (h8v){0, 0, 0, 0, 0, 0, 0, 0};
        if (DUAL) {
          bfr = (ch == 0)
              ? *(const h8v*)(src0 + (((size_t)b * NPIXI + pix) * 32 + lg * 8))
              : *(const h8v*)(src1 + (((size_t)n * NPIXI + pix) * 32 + lg * 8));
        } else {
          const int gci = k0 + lg * 8;
          if (gci < G)
            bfr = *(const h8v*)(src1 + (((size_t)n * NPIXI + pix) * G + gci));
        }
#pragma unroll
        for (int mf = 0; mf < MFR; ++mf)
          acc[mf][pf] = __builtin_amdgcn_mfma_f32_16x16x32_f16(afr[mf], bfr, acc[mf][pf], 0, 0, 0);
      }
    }
  } else {
    s8v rbuf[CPT];
    auto stage_load = [&](int k0) {
#pragma unroll
      for (int j = 0; j < CPT; ++j) {
        const int cidx = tid + j * 256;
        s8v v = (s8v){0, 0, 0, 0, 0, 0, 0, 0};
        if (cidx < NCHUNK) {
          const int s = cidx >> 2, p = cidx & 3;
          const int rs = s / TC, cs = s - rs * TC;
          int ir, ic;
          if (GEOM == 1) { ir = 2 * r0 - 1 + rs; ic = (cs < 32) ? 2 * cs : 2 * (cs - 32) - 1; }
          else           { ir = r0 - 1 + rs;     ic = cs - 1; }
          const int gci = k0 + p * 8;
          if (((unsigned)ir < (unsigned)IMGI) && ((unsigned)ic < (unsigned)IMGI)) {
            const int ipix = ir * IMGI + ic;
            if (DUAL) {
              if (gci < 32)
                v = *(const s8v*)(src0 + (((size_t)b * NPIXI + ipix) * 32 + gci));
              else
                v = *(const s8v*)(src1 + (((size_t)n * NPIXI + ipix) * 32 + (gci - 32)));
            } else if (gci < G) {
              v = *(const s8v*)(src1 + (((size_t)n * NPIXI + ipix) * G + gci));
              if constexpr (BNIN) v = bnin_apply(v, bnst, gci);
            }
          }
        }
        rbuf[j] = v;
      }
    };
    auto stage_write = [&]() {
#pragma unroll
      for (int j = 0; j < CPT; ++j) {
        const int cidx = tid + j * 256;
        if (cidx < NCHUNK) {
          const int s = cidx >> 2, p = cidx & 3;
          *(s8v*)(&lds[(size_t)(p * PSTR + s) * 8]) = rbuf[j];
        }
      }
    };

    stage_load(0);
#pragma unroll
    for (int ch = 0; ch < NCH; ++ch) {
      if (ch > 0) __syncthreads();
      stage_write();
      __syncthreads();
      if (ch + 1 < NCH) stage_load((ch + 1) * 32);
      const int k0 = ch * 32;
#pragma unroll
      for (int t = 0; t < TAPS; ++t) {
        int dh, dw, wt, kh = 0, kw = 0;
        if (GEOM == 2) {
          dh = qq + (t >> 1) - 1; dw = pp + (t & 1) - 1;
          wt = (qq + 2 * (t >> 1)) * 4 + (pp + 2 * (t & 1));
        } else { kh = t / 3; kw = t % 3; dh = kh - 1; dw = kw - 1; wt = t; }
        h8v afr[MFR];
#pragma unroll
        for (int mf = 0; mf < MFR; ++mf)
          afr[mf] = *(const h8v*)(wp + ((size_t)(wt * COP + co0 + mf * 16 + ln)) * KP + k0 + lg * 8);
#pragma unroll
        for (int pf = 0; pf < WPIX; ++pf) {
          const int pl = wid * (WPIX * 16) + pf * 16 + ln;
          const int rL = pl / IMGO, c = pl - rL * IMGO;
          int slot;
          if (GEOM == 1) slot = (2 * rL + kh) * 65 + ((kw == 1) ? c : (32 + c + (kw >> 1)));
          else           slot = (rL + dh + 1) * TC + (c + dw + 1);
          const h8v bfr = *(const h8v*)(&lds[(size_t)(lg * PSTR + slot) * 8]);
#pragma unroll
          for (int mf = 0; mf < MFR; ++mf)
            acc[mf][pf] = __builtin_amdgcn_mfma_f32_16x16x32_f16(afr[mf], bfr, acc[mf][pf], 0, 0, 0);
        }
      }
    }
  }

  const float di = (float)(ij / 9) - 4.f, dj = (float)(ij % 9) - 4.f;

  {
#pragma unroll
    for (int mf = 0; mf < MFR; ++mf) {
#pragma unroll
      for (int pf = 0; pf < WPIX; ++pf) {
        const int pl = wid * (WPIX * 16) + pf * 16 + ln;
        const int rL = pl / IMGO, c = pl - rL * IMGO;
        int opix;
        if constexpr (GEOM == 2) opix = (2 * (r0 + rL) + qq) * 64 + 2 * c + pp;
        else opix = (r0 + rL) * IMGO + c;
        if constexpr (DELTA && EPI == 0) {
          const int oh = r0 + rL;
          const int rc = (oh == 0) ? 0 : ((oh == IMGO - 1) ? 2 : 1);
          const int cc = (c == 0) ? 0 : ((c == IMGO - 1) ? 2 : 1);
#pragma unroll
          for (int rg = 0; rg < 4; ++rg) {
            const int co = co0 + mf * 16 + lg * 4 + rg;
            acc[mf][pf][rg] += di * dtab[(co * 9 + rc * 3 + cc) * 2 + 0] +
                               dj * dtab[(co * 9 + rc * 3 + cc) * 2 + 1];
          }
        }
        if constexpr (DELTA && EPI == 1) {
#pragma unroll
          for (int rg = 0; rg < 4; ++rg) {
            const int co = co0 + mf * 16 + lg * 4 + rg;
            acc[mf][pf][rg] += di * dtab[co * 2] + dj * dtab[co * 2 + 1];
          }
        }
        if constexpr (EPI == 1 || EPI == 2) {
          const float4 bv = *(const float4*)(bias + co0 + mf * 16 + lg * 4);
          acc[mf][pf][0] += bv.x; acc[mf][pf][1] += bv.y;
          acc[mf][pf][2] += bv.z; acc[mf][pf][3] += bv.w;
          if constexpr (EPI == 1) {
#pragma unroll
            for (int rg = 0; rg < 4; ++rg) acc[mf][pf][rg] = fmaxf(acc[mf][pf][rg], 0.f);
          }
        }
        ushort4 st;
        st.x = f2h_bits(acc[mf][pf][0]); st.y = f2h_bits(acc[mf][pf][1]);
        st.z = f2h_bits(acc[mf][pf][2]); st.w = f2h_bits(acc[mf][pf][3]);
        *reinterpret_cast<ushort4*>(outB + ((size_t)n * NPIXO + opix) * COB + co0 + mf * 16 + lg * 4) = st;
      }
    }
    if constexpr (EPI == 0) {
      __syncthreads();
      float* sl = (float*)lds;
#pragma unroll
      for (int mf = 0; mf < MFR; ++mf) {
#pragma unroll
        for (int rg = 0; rg < 4; ++rg) {
          float s = 0.f, q2 = 0.f;
#pragma unroll
          for (int pf = 0; pf < WPIX; ++pf) {
            const float v = acc[mf][pf][rg];
            s += v; q2 += v * v;
          }
#pragma unroll
          for (int o = 1; o < 16; o <<= 1) { s += __shfl_xor(s, o); q2 += __shfl_xor(q2, o); }
          if (ln == 0) {
            const int cl = mf * 16 + lg * 4 + rg;
            sl[(wid * MFR * 16 + cl) * 2 + 0] = s;
            sl[(wid * MFR * 16 + cl) * 2 + 1] = q2;
          }
        }
      }
      __syncthreads();
      const int NPB = gridDim.x * gridDim.z;
      const int pb = (int)blockIdx.x * gridDim.z + blockIdx.z;
      for (int i = tid; i < MFR * 16 * 2; i += 256) {
        const int cl = i >> 1, stt = i & 1;
        float tot = 0.f;
#pragma unroll
        for (int w = 0; w < 4; ++w) tot += sl[(w * MFR * 16 + cl) * 2 + stt];
        statL[(size_t)((co0 + cl) * 2 + stt) * NPB + pb] = tot;
      }
    }
  }
  (void)outF;
}

// ---------------------------------------------------------------- efuse: e1+e2+e3 fused via LDS relays
__global__ __launch_bounds__(256) void efuse(
    const hf* __restrict__ f2s_, const hf* __restrict__ sA_,
    const hf* __restrict__ w1p, const float* __restrict__ b1v, const float* __restrict__ dtE,
    const hf* __restrict__ w2p, const float* __restrict__ b2v,
    const hf* __restrict__ w3p, const float* __restrict__ b3v,
    hf* __restrict__ outB) {
  constexpr int PSTRE = 72;
  __shared__ __align__(16) hf ldsA[256 * PSTRE];
  __shared__ __align__(16) hf ldsB[256 * PSTRE];

  const int tid = threadIdx.x;
  const int wid = tid >> 6, lane = tid & 63, lg = lane >> 4, ln = lane & 15;
  const int n = blockIdx.z, b = n / 81, ij = n - b * 81;
  const int r0 = blockIdx.x * 4;
  const float di = (float)(ij / 9) - 4.f, dj = (float)(ij % 9) - 4.f;

  // e1: (f1,f2s) 64 -> 48
  f32x4 acc1[3][4];
#pragma unroll
  for (int mf = 0; mf < 3; ++mf)
#pragma unroll
    for (int pf = 0; pf < 4; ++pf) acc1[mf][pf] = (f32x4){0.f, 0.f, 0.f, 0.f};
#pragma unroll
  for (int ch = 0; ch < 2; ++ch) {
    const int k0 = ch * 32;
    h8v afr[3];
#pragma unroll
    for (int mf = 0; mf < 3; ++mf)
      afr[mf] = *(const h8v*)(w1p + ((size_t)(mf * 16 + ln)) * 64 + k0 + lg * 8);
#pragma unroll
    for (int pf = 0; pf < 4; ++pf) {
      const int pix = r0 * 64 + wid * 64 + pf * 16 + ln;
      const h8v bfr = (ch == 0)
          ? *(const h8v*)(sA_ + (((size_t)b * 4096 + pix) * 32 + lg * 8))
          : *(const h8v*)(f2s_ + (((size_t)n * 4096 + pix) * 32 + lg * 8));
#pragma unroll
      for (int mf = 0; mf < 3; ++mf)
        acc1[mf][pf] = __builtin_amdgcn_mfma_f32_16x16x32_f16(afr[mf], bfr, acc1[mf][pf], 0, 0, 0);
    }
  }
#pragma unroll
  for (int mf = 0; mf < 3; ++mf) {
#pragma unroll
    for (int pf = 0; pf < 4; ++pf) {
      const int pixL = wid * 64 + pf * 16 + ln;
#pragma unroll
      for (int rg = 0; rg < 4; ++rg) {
        const int co = mf * 16 + lg * 4 + rg;
        acc1[mf][pf][rg] += di * dtE[co * 2] + dj * dtE[co * 2 + 1];
      }
      const float4 bv = *(const float4*)(b1v + mf * 16 + lg * 4);
      acc1[mf][pf][0] += bv.x; acc1[mf][pf][1] += bv.y;
      acc1[mf][pf][2] += bv.z; acc1[mf][pf][3] += bv.w;
#pragma unroll
      for (int rg = 0; rg < 4; ++rg) acc1[mf][pf][rg] = fmaxf(acc1[mf][pf][rg], 0.f);
      ushort4 st;
      st.x = f2h_bits(acc1[mf][pf][0]); st.y = f2h_bits(acc1[mf][pf][1]);
      st.z = f2h_bits(acc1[mf][pf][2]); st.w = f2h_bits(acc1[mf][pf][3]);
      *reinterpret_cast<ushort4*>(&ldsA[(size_t)pixL * PSTRE + mf * 16 + lg * 4]) = st;
    }
  }
  for (int z = tid; z < 256 * 16; z += 256)
    ldsA[(size_t)(z >> 4) * PSTRE + 48 + (z & 15)] = (hf)0.f;
  __syncthreads();

  // e2: 48(+pad) -> 64
  f32x4 acc2[4][4];
#pragma unroll
  for (int mf = 0; mf < 4; ++mf)
#pragma unroll
    for (int pf = 0; pf < 4; ++pf) acc2[mf][pf] = (f32x4){0.f, 0.f, 0.f, 0.f};
#pragma unroll
  for (int ch = 0; ch < 2; ++ch) {
    const int k0 = ch * 32;
    h8v afr[4];
#pragma unroll
    for (int mf = 0; mf < 4; ++mf)
      afr[mf] = *(const h8v*)(w2p + ((size_t)(mf * 16 + ln)) * 64 + k0 + lg * 8);
#pragma unroll
    for (int pf = 0; pf < 4; ++pf) {
      const int pixL = wid * 64 + pf * 16 + ln;
      const h8v bfr = *(const h8v*)(&ldsA[(size_t)pixL * PSTRE + k0 + lg * 8]);
#pragma unroll
      for (int mf = 0; mf < 4; ++mf)
        acc2[mf][pf] = __builtin_amdgcn_mfma_f32_16x16x32_f16(afr[mf], bfr, acc2[mf][pf], 0, 0, 0);
    }
  }
#pragma unroll
  for (int mf = 0; mf < 4; ++mf) {
#pragma unroll
    for (int pf = 0; pf < 4; ++pf) {
      const int pixL = wid * 64 + pf * 16 + ln;
      const float4 bv = *(const float4*)(b2v + mf * 16 + lg * 4);
      acc2[mf][pf][0] += bv.x; acc2[mf][pf][1] += bv.y;
      acc2[mf][pf][2] += bv.z; acc2[mf][pf][3] += bv.w;
#pragma unroll
      for (int rg = 0; rg < 4; ++rg) acc2[mf][pf][rg] = fmaxf(acc2[mf][pf][rg], 0.f);
      ushort4 st;
      st.x = f2h_bits(acc2[mf][pf][0]); st.y = f2h_bits(acc2[mf][pf][1]);
      st.z = f2h_bits(acc2[mf][pf][2]); st.w = f2h_bits(acc2[mf][pf][3]);
      *reinterpret_cast<ushort4*>(&ldsB[(size_t)pixL * PSTRE + mf * 16 + lg * 4]) = st;
    }
  }
  __syncthreads();

  // e3: 64 -> 32 -> global
  f32x4 acc3[2][4];
#pragma unroll
  for (int mf = 0; mf < 2; ++mf)
#pragma unroll
    for (int pf = 0; pf < 4; ++pf) acc3[mf][pf] = (f32x4){0.f, 0.f, 0.f, 0.f};
#pragma unroll
  for (int ch = 0; ch < 2; ++ch) {
    const int k0 = ch * 32;
    h8v afr[2];
#pragma unroll
    for (int mf = 0; mf < 2; ++mf)
      afr[mf] = *(const h8v*)(w3p + ((size_t)(mf * 16 + ln)) * 64 + k0 + lg * 8);
#pragma unroll
    for (int pf = 0; pf < 4; ++pf) {
      const int pixL = wid * 64 + pf * 16 + ln;
      const h8v bfr = *(const h8v*)(&ldsB[(size_t)pixL * PSTRE + k0 + lg * 8]);
#pragma unroll
      for (int mf = 0; mf < 2; ++mf)
        acc3[mf][pf] = __builtin_amdgcn_mfma_f32_16x16x32_f16(afr[mf], bfr, acc3[mf][pf], 0, 0, 0);
    }
  }
#pragma unroll
  for (int mf = 0; mf < 2; ++mf) {
#pragma unroll
    for (int pf = 0; pf < 4; ++pf) {
      const int pix = r0 * 64 + wid * 64 + pf * 16 + ln;
      const float4 bv = *(const float4*)(b3v + mf * 16 + lg * 4);
      acc3[mf][pf][0] += bv.x; acc3[mf][pf][1] += bv.y;
      acc3[mf][pf][2] += bv.z; acc3[mf][pf][3] += bv.w;
      ushort4 st;
      st.x = f2h_bits(acc3[mf][pf][0]); st.y = f2h_bits(acc3[mf][pf][1]);
      st.z = f2h_bits(acc3[mf][pf][2]); st.w = f2h_bits(acc3[mf][pf][3]);
      *reinterpret_cast<ushort4*>(outB + (((size_t)n * 4096 + pix) * 32 + mf * 16 + lg * 4)) = st;
    }
  }
}

// ---------------------------------------------------------------- mconv2s2 (stats -> partial store)
__global__ __launch_bounds__(256) void mconv2s2(
    const hf* __restrict__ src1, const hf* __restrict__ wp,
    const float* __restrict__ bnst, float* __restrict__ statL, hf* __restrict__ outB) {
  constexpr int IMGI = 64, IMGO = 32;
  constexpr int PIXROWS = 4, WPIX = 2, MFR = 4;
  constexpr int TR = 2 * PIXROWS + 1;
  constexpr int TC = 65;
  constexpr int NSLOT = TR * TC;
  constexpr int PSTR = NSLOT + 1;
  constexpr int NCH = 3;
  constexpr int G = 96;
  constexpr int NPIXI = IMGI * IMGI;
  constexpr int NCHUNK = NSLOT * 4;
  constexpr int COT = MFR * 16;
  constexpr int COP = 128;
  constexpr int WPLANE = 3 * COT;
  constexpr int WPSTR  = WPLANE + 1;
  constexpr int WCHUNK = WPLANE * 4;

  __shared__ __align__(16) hf alds[4 * PSTR * 8];
  __shared__ __align__(16) hf wlds[4 * WPSTR * 8];

  const int tid = threadIdx.x;
  const int wid = tid >> 6, lane = tid & 63, lg = lane >> 4, ln = lane & 15;
  const int n = blockIdx.z;
  const int r0 = blockIdx.x * PIXROWS;
  const int co0 = (int)blockIdx.y * COT;

  f32x4 acc[MFR][WPIX];
#pragma unroll
  for (int mf = 0; mf < MFR; ++mf)
#pragma unroll
    for (int pf = 0; pf < WPIX; ++pf) acc[mf][pf] = (f32x4){0.f, 0.f, 0.f, 0.f};

  for (int ks = 0; ks < NCH; ++ks) {
    const int k0 = ks * 32;
    __syncthreads();
    for (int cidx = tid; cidx < NCHUNK; cidx += 256) {
      const int s = cidx >> 2, p = cidx & 3;
      const int rs = s / TC, cs = s - rs * TC;
      const int ir = 2 * r0 - 1 + rs;
      const int ic = (cs < 32) ? 2 * cs : 2 * (cs - 32) - 1;
      s8v v = (s8v){0, 0, 0, 0, 0, 0, 0, 0};
      const int gci = k0 + p * 8;
      if (((unsigned)ir < (unsigned)IMGI) && ((unsigned)ic < (unsigned)IMGI)) {
        const int ipix = ir * IMGI + ic;
        v = *(const s8v*)(src1 + (((size_t)n * NPIXI + ipix) * G + gci));
        v = bnin_apply(v, bnst, gci);
      }
      *(s8v*)(&alds[(size_t)(p * PSTR + s) * 8]) = v;
    }
#pragma unroll
    for (int tg = 0; tg < 3; ++tg) {
      if (tg > 0) __syncthreads();
      for (int widx = tid; widx < WCHUNK; widx += 256) {
        const int p = widx & 3;
        const int r = widx >> 2;
        const int co = r & (COT - 1);
        const int tt = r >> 6;
        const int tglob = tg * 3 + tt;
        const s8v wv = *(const s8v*)(wp + (((size_t)(tglob * NCH + ks) * COP + co0 + co) * 32 + p * 8));
        *(s8v*)(&wlds[(size_t)(p * WPSTR + r) * 8]) = wv;
      }
      __syncthreads();
#pragma unroll
      for (int tt = 0; tt < 3; ++tt) {
        const int kh = tg, kw = tt;
        h8v afr[MFR];
#pragma unroll
        for (int mf = 0; mf < MFR; ++mf)
          afr[mf] = *(const h8v*)(&wlds[(size_t)(lg * WPSTR + tt * COT + mf * 16 + ln) * 8]);
#pragma unroll
        for (int pf = 0; pf < WPIX; ++pf) {
          const int pl = wid * (WPIX * 16) + pf * 16 + ln;
          const int rL = pl / IMGO, c = pl - rL * IMGO;
          const int slot = (2 * rL + kh) * 65 + ((kw == 1) ? c : (32 + c + (kw >> 1)));
          const h8v bfr = *(const h8v*)(&alds[(size_t)(lg * PSTR + slot) * 8]);
#pragma unroll
          for (int mf = 0; mf < MFR; ++mf)
            acc[mf][pf] = __builtin_amdgcn_mfma_f32_16x16x32_f16(afr[mf], bfr, acc[mf][pf], 0, 0, 0);
        }
      }
    }
  }

#pragma unroll
  for (int mf = 0; mf < MFR; ++mf) {
#pragma unroll
    for (int pf = 0; pf < WPIX; ++pf) {
      const int pl = wid * (WPIX * 16) + pf * 16 + ln;
      const int rL = pl / IMGO, c = pl - rL * IMGO;
      const int opix = (r0 + rL) * IMGO + c;
      ushort4 st;
      st.x = f2h_bits(acc[mf][pf][0]); st.y = f2h_bits(acc[mf][pf][1]);
      st.z = f2h_bits(acc[mf][pf][2]); st.w = f2h_bits(acc[mf][pf][3]);
      *reinterpret_cast<ushort4*>(outB + ((size_t)n * 1024 + opix) * COP + co0 + mf * 16 + lg * 4) = st;
    }
  }
  __syncthreads();
  float* sl = (float*)alds;
#pragma unroll
  for (int mf = 0; mf < MFR; ++mf) {
#pragma unroll
    for (int rg = 0; rg < 4; ++rg) {
      float s = 0.f, q2 = 0.f;
#pragma unroll
      for (int pf = 0; pf < WPIX; ++pf) {
        const float v = acc[mf][pf][rg];
        s += v; q2 += v * v;
      }
#pragma unroll
      for (int o = 1; o < 16; o <<= 1) { s += __shfl_xor(s, o); q2 += __shfl_xor(q2, o); }
      if (ln == 0) {
        const int cl = mf * 16 + lg * 4 + rg;
        sl[(wid * MFR * 16 + cl) * 2 + 0] = s;
        sl[(wid * MFR * 16 + cl) * 2 + 1] = q2;
      }
    }
  }
  __syncthreads();
  const int NPB = gridDim.x * gridDim.z;
  const int pb = (int)blockIdx.x * gridDim.z + blockIdx.z;
  for (int i = tid; i < MFR * 16 * 2; i += 256) {
    const int cl = i >> 1, stt = i & 1;
    float tot = 0.f;
#pragma unroll
    for (int w = 0; w < 4; ++w) tot += sl[(w * MFR * 16 + cl) * 2 + stt];
    statL[(size_t)((co0 + cl) * 2 + stt) * NPB + pb] = tot;
  }
}

// ---------------------------------------------------------------- mconv2 (stats -> partial store)
template <int G, int COP, int MFR, int PIXROWS, int WPIX, bool BNIN>
__global__ __launch_bounds__(256) void mconv2(
    const hf* __restrict__ src1, const hf* __restrict__ wp,
    const float* __restrict__ bnst,
    float* __restrict__ statL, hf* __restrict__ outB) {
  constexpr int IMG = 32;
  constexpr int TAPS = 9;
  constexpr int TC = IMG + 2;
  constexpr int TR = PIXROWS + 2;
  constexpr int NSLOT = TR * TC;
  constexpr int PSTR = NSLOT + 1;
  constexpr int NCH = G / 32;
  constexpr int NPIX = IMG * IMG;
  constexpr int NCHUNK = NSLOT * 4;
  constexpr int COT = MFR * 16;
  constexpr int WPLANE = TAPS * COT;
  constexpr int WPSTR  = WPLANE + 1;
  constexpr int WCHUNK = WPLANE * 4;

  __shared__ __align__(16) hf alds[4 * PSTR * 8];
  __shared__ __align__(16) hf wlds[4 * WPSTR * 8];

  const int tid = threadIdx.x;
  const int wid = tid >> 6, lane = tid & 63, lg = lane >> 4, ln = lane & 15;
  const int n = blockIdx.z;
  const int r0 = blockIdx.x * PIXROWS;
  const int co0 = blockIdx.y * COT;

  f32x4 acc[MFR][WPIX];
#pragma unroll
  for (int mf = 0; mf < MFR; ++mf)
#pragma unroll
    for (int pf = 0; pf < WPIX; ++pf) acc[mf][pf] = (f32x4){0.f, 0.f, 0.f, 0.f};

  for (int ks = 0; ks < NCH; ++ks) {
    __syncthreads();
    for (int cidx = tid; cidx < NCHUNK; cidx += 256) {
      const int s = cidx >> 2, p = cidx & 3;
      const int rs = s / TC, cs = s - rs * TC;
      const int ir = r0 - 1 + rs, ic = cs - 1;
      s8v v = (s8v){0, 0, 0, 0, 0, 0, 0, 0};
      if (((unsigned)ir < (unsigned)IMG) && ((unsigned)ic < (unsigned)IMG)) {
        const int ipix = ir * IMG + ic;
        v = *(const s8v*)(src1 + (((size_t)n * NPIX + ipix) * G + ks * 32 + p * 8));
        if constexpr (BNIN) v = bnin_apply(v, bnst, ks * 32 + p * 8);
      }
      *(s8v*)(&alds[(size_t)(p * PSTR + s) * 8]) = v;
    }
    for (int widx = tid; widx < WCHUNK; widx += 256) {
      const int p = widx & 3;
      const int r = widx >> 2;
      const int co = r & (COT - 1);
      const int t = r >> 6;
      const s8v wv = *(const s8v*)(wp + (((size_t)(t * NCH + ks) * COP + co0 + co) * 32 + p * 8));
      *(s8v*)(&wlds[(size_t)(p * WPSTR + r) * 8]) = wv;
    }
    __syncthreads();
#pragma unroll
    for (int t = 0; t < TAPS; ++t) {
      const int kh = t / 3, kw = t % 3;
      const int dh = kh - 1, dw = kw - 1;
      h8v afr[MFR];
#pragma unroll
      for (int mf = 0; mf < MFR; ++mf)
        afr[mf] = *(const h8v*)(&wlds[(size_t)(lg * WPSTR + t * COT + mf * 16 + ln) * 8]);
#pragma unroll
      for (int pf = 0; pf < WPIX; ++pf) {
        const int pl = wid * (WPIX * 16) + pf * 16 + ln;
        const int rL = pl / IMG, c = pl - rL * IMG;
        const int slot = (rL + dh + 1) * TC + (c + dw + 1);
        const h8v bfr = *(const h8v*)(&alds[(size_t)(lg * PSTR + slot) * 8]);
#pragma unroll
        for (int mf = 0; mf < MFR; ++mf)
          acc[mf][pf] = __builtin_amdgcn_mfma_f32_16x16x32_f16(afr[mf], bfr, acc[mf][pf], 0, 0, 0);
      }
    }
  }

#pragma unroll
  for (int mf = 0; mf < MFR; ++mf) {
#pragma unroll
    for (int pf = 0; pf < WPIX; ++pf) {
      const int pl = wid * (WPIX * 16) + pf * 16 + ln;
      const int rL = pl / IMG, c = pl - rL * IMG;
      const int opix = (r0 + rL) * IMG + c;
      ushort4 st;
      st.x = f2h_bits(acc[mf][pf][0]); st.y = f2h_bits(acc[mf][pf][1]);
      st.z = f2h_bits(acc[mf][pf][2]); st.w = f2h_bits(acc[mf][pf][3]);
      *reinterpret_cast<ushort4*>(outB + ((size_t)n * NPIX + opix) * COP + co0 + mf * 16 + lg * 4) = st;
    }
  }
  __syncthreads();
  float* sl = (float*)alds;
#pragma unroll
  for (int mf = 0; mf < MFR; ++mf) {
#pragma unroll
    for (int rg = 0; rg < 4; ++rg) {
      float s = 0.f, q2 = 0.f;
#pragma unroll
      for (int pf = 0; pf < WPIX; ++pf) {
        const float v = acc[mf][pf][rg];
        s += v; q2 += v * v;
      }
#pragma unroll
      for (int o = 1; o < 16; o <<= 1) { s += __shfl_xor(s, o); q2 += __shfl_xor(q2, o); }
      if (ln == 0) {
        const int cl = mf * 16 + lg * 4 + rg;
        sl[(wid * MFR * 16 + cl) * 2 + 0] = s;
        sl[(wid * MFR * 16 + cl) * 2 + 1] = q2;
      }
    }
  }
  __syncthreads();
  const int NPB = gridDim.x * gridDim.z;
  const int pb = (int)blockIdx.x * gridDim.z + blockIdx.z;
  for (int i = tid; i < MFR * 16 * 2; i += 256) {
    const int cl = i >> 1, stt = i & 1;
    float tot = 0.f;
#pragma unroll
    for (int w = 0; w < 4; ++w) tot += sl[(w * MFR * 16 + cl) * 2 + stt];
    statL[(size_t)((co0 + cl) * 2 + stt) * NPB + pb] = tot;
  }
}

// ---------------------------------------------------------------- mconv2d (stats -> partial store)
__global__ __launch_bounds__(256) void mconv2d(
    const hf* __restrict__ src1, const hf* __restrict__ wp,
    const float* __restrict__ bnst,
    float* __restrict__ statL, hf* __restrict__ outB) {
  constexpr int IMG = 32;
  constexpr int TAPS = 4;
  constexpr int PIXROWS = 8;
  constexpr int WPIX = 4;
  constexpr int MFR = 2;
  constexpr int TC = IMG + 2;
  constexpr int TR = PIXROWS + 2;
  constexpr int NSLOT = TR * TC;
  constexpr int PSTR = NSLOT + 1;
  constexpr int NCH = 2;
  constexpr int NPIX = IMG * IMG;
  constexpr int NCHUNK = NSLOT * 4;
  constexpr int COT = MFR * 16;
  constexpr int WPLANE = TAPS * COT;
  constexpr int WPSTR  = WPLANE + 1;
  constexpr int WCHUNK = WPLANE * 4;
  constexpr int G = 64;

  __shared__ __align__(16) hf alds[4 * PSTR * 8];
  __shared__ __align__(16) hf wlds[4 * WPSTR * 8];

  const int tid = threadIdx.x;
  const int wid = tid >> 6, lane = tid & 63, lg = lane >> 4, ln = lane & 15;
  const int n = blockIdx.z;
  const int r0 = blockIdx.x * PIXROWS;
  const int par = blockIdx.y;
  const int qq = par >> 1, pp = par & 1;
  const hf* wbase = wp + (size_t)par * (TAPS * NCH * COT * 32);

  f32x4 acc[MFR][WPIX];
#pragma unroll
  for (int mf = 0; mf < MFR; ++mf)
#pragma unroll
    for (int pf = 0; pf < WPIX; ++pf) acc[mf][pf] = (f32x4){0.f, 0.f, 0.f, 0.f};

  for (int ks = 0; ks < NCH; ++ks) {
    __syncthreads();
    const int k0 = ks * 32;
    for (int cidx = tid; cidx < NCHUNK; cidx += 256) {
      const int s = cidx >> 2, p = cidx & 3;
      const int rs = s / TC, cs = s - rs * TC;
      const int ir = r0 - 1 + rs, ic = cs - 1;
      s8v v = (s8v){0, 0, 0, 0, 0, 0, 0, 0};
      if (((unsigned)ir < (unsigned)IMG) && ((unsigned)ic < (unsigned)IMG)) {
        const int ipix = ir * IMG + ic;
        v = *(const s8v*)(src1 + (((size_t)n * NPIX + ipix) * G + k0 + p * 8));
        v = bnin_apply(v, bnst, k0 + p * 8);
      }
      *(s8v*)(&alds[(size_t)(p * PSTR + s) * 8]) = v;
    }
    for (int widx = tid; widx < WCHUNK; widx += 256) {
      const int p = widx & 3;
      const int r = widx >> 2;
      const int co = r & (COT - 1);
      const int t = r >> 5;
      const s8v wv = *(const s8v*)(wbase + (((size_t)(t * NCH + ks) * COT + co) * 32 + p * 8));
      *(s8v*)(&wlds[(size_t)(p * WPSTR + r) * 8]) = wv;
    }
    __syncthreads();
#pragma unroll
    for (int t = 0; t < TAPS; ++t) {
      const int dh = qq + (t >> 1) - 1;
      const int dw = pp + (t & 1) - 1;
      h8v afr[MFR];
#pragma unroll
      for (int mf = 0; mf < MFR; ++mf)
        afr[mf] = *(const h8v*)(&wlds[(size_t)(lg * WPSTR + t * COT + mf * 16 + ln) * 8]);
#pragma unroll
      for (int pf = 0; pf < WPIX; ++pf) {
        const int pl = wid * (WPIX * 16) + pf * 16 + ln;
        const int rL = pl / IMG, c = pl - rL * IMG;
        const int slot = (rL + dh + 1) * TC + (c + dw + 1);
        const h8v bfr = *(const h8v*)(&alds[(size_t)(lg * PSTR + slot) * 8]);
#pragma unroll
        for (int mf = 0; mf < MFR; ++mf)
          acc[mf][pf] = __builtin_amdgcn_mfma_f32_16x16x32_f16(afr[mf], bfr, acc[mf][pf], 0, 0, 0);
      }
    }
  }

#pragma unroll
  for (int mf = 0; mf < MFR; ++mf) {
#pragma unroll
    for (int pf = 0; pf < WPIX; ++pf) {
      const int pl = wid * (WPIX * 16) + pf * 16 + ln;
      const int rL = pl / IMG, c = pl - rL * IMG;
      const int opix = (2 * (r0 + rL) + qq) * 64 + 2 * c + pp;
      ushort4 st;
      st.x = f2h_bits(acc[mf][pf][0]); st.y = f2h_bits(acc[mf][pf][1]);
      st.z = f2h_bits(acc[mf][pf][2]); st.w = f2h_bits(acc[mf][pf][3]);
      *reinterpret_cast<ushort4*>(outB + ((size_t)n * 4096 + opix) * 32 + mf * 16 + lg * 4) = st;
    }
  }
  __syncthreads();
  float* sl = (float*)alds;
#pragma unroll
  for (int mf = 0; mf < MFR; ++mf) {
#pragma unroll
    for (int rg = 0; rg < 4; ++rg) {
      float s = 0.f, q2 = 0.f;
#pragma unroll
      for (int pf = 0; pf < WPIX; ++pf) {
        const float v = acc[mf][pf][rg];
        s += v; q2 += v * v;
      }
#pragma unroll
      for (int o = 1; o < 16; o <<= 1) { s += __shfl_xor(s, o); q2 += __shfl_xor(q2, o); }
      if (ln == 0) {
        const int cl = mf * 16 + lg * 4 + rg;
        sl[(wid * MFR * 16 + cl) * 2 + 0] = s;
        sl[(wid * MFR * 16 + cl) * 2 + 1] = q2;
      }
    }
  }
  __syncthreads();
  const int NPB = gridDim.x * gridDim.y * gridDim.z;
  const int pb = ((int)blockIdx.y * gridDim.x + blockIdx.x) * gridDim.z + blockIdx.z;
  for (int i = tid; i < MFR * 16 * 2; i += 256) {
    const int cl = i >> 1, stt = i & 1;
    float tot = 0.f;
#pragma unroll
    for (int w = 0; w < 4; ++w) tot += sl[(w * MFR * 16 + cl) * 2 + stt];
    statL[(size_t)(cl * 2 + stt) * NPB + pb] = tot;
  }
}

// ---------------------------------------------------------------- fused deterministic stat reduction + finalize
// Per-stat summation replicates bnred exactly (256-thread stride, shfl tree, wsum combine)
// -> bit-identical f64 sums; bnfin f64 math unchanged.
__global__ __launch_bounds__(256) void bnredfin(
    const float* __restrict__ part, float* __restrict__ statL,
    const float* __restrict__ g, const float* __restrict__ bt,
    int NPB, double invCnt) {
  const int c = blockIdx.x;
  const int t = threadIdx.x;
  __shared__ double wsum[4];

  // stat 2c (sum)
  double s = 0.0;
  for (int p = t; p < NPB; p += 256) s += (double)part[(size_t)(2 * c) * NPB + p];
#pragma unroll
  for (int o = 1; o < 64; o <<= 1) s += __shfl_xor(s, o);
  if ((t & 63) == 0) wsum[t >> 6] = s;
  __syncthreads();
  const double sumA = (wsum[0] + wsum[1]) + (wsum[2] + wsum[3]);
  __syncthreads();

  // stat 2c+1 (sum of squares)
  double q = 0.0;
  for (int p = t; p < NPB; p += 256) q += (double)part[(size_t)(2 * c + 1) * NPB + p];
#pragma unroll
  for (int o = 1; o < 64; o <<= 1) q += __shfl_xor(q, o);
  if ((t & 63) == 0) wsum[t >> 6] = q;
  __syncthreads();
  const double sumB = (wsum[0] + wsum[1]) + (wsum[2] + wsum[3]);

  if (t == 0) {
    const double m = sumA * invCnt;
    const double var = sumB * invCnt - m * m;
    const double sc = (double)g[c] / sqrt(var + 1e-5);
    statL[256 + c] = (float)sc;
    statL[384 + c] = (float)((double)bt[c] - m * sc);
  }
}

// ---------------------------------------------------------------- conv5 (CO=1) on VALU, BN-on-read
__global__ __launch_bounds__(256) void conv5_kernel(
    const hf* __restrict__ xd, const float* __restrict__ w5, const float* __restrict__ b5,
    const float* __restrict__ bnst, float* __restrict__ outp) {
  const int gid = blockIdx.x * 256 + threadIdx.x;  // 162*4096
  const int n = gid >> 12, pix = gid & 4095;
  const int b = n / 81, ij = n - b * 81;
  const int oh = pix >> 6, ow = pix & 63;
  float acc = b5[0];
#pragma unroll
  for (int kh = 0; kh < 3; ++kh) {
    const int ih = oh + kh - 1;
#pragma unroll
    for (int kw = 0; kw < 3; ++kw) {
      const int iw = ow + kw - 1;
      if (((unsigned)ih < 64u) && ((unsigned)iw < 64u)) {
        const hf* xp = xd + ((size_t)n * 4096 + ih * 64 + iw) * 32;
#pragma unroll
        for (int cq = 0; cq < 4; ++cq) {
          const h8v v = *(const h8v*)(xp + cq * 8);
#pragma unroll
          for (int j = 0; j < 8; ++j) {
            const int c = cq * 8 + j;
            const float t = (hf)fmaxf((float)v[j] * bnst[256 + c] + bnst[384 + c], 0.f);
            acc += t * w5[c * 9 + kh * 3 + kw];
          }
        }
      }
    }
  }
  outp[((size_t)(b * 113 + ij)) * 4096 + pix] = acc;
}

// ---------------------------------------------------------------- DAP softmax
__global__ __launch_bounds__(64) void softmax_kernel(
    const float* __restrict__ outp, const float* __restrict__ dapw, float* __restrict__ score) {
  __shared__ float cb[64 * 81];
  __shared__ float sb[64 * 81];
  const int t = threadIdx.x;
  const int gid = blockIdx.x * 64 + t;
  const int b = gid >> 12, hw = gid & 4095;
  for (int d = 0; d < 81; ++d)
    cb[t * 81 + d] = outp[((size_t)(b * 113 + d)) * 4096 + hw];
  float smax = -1e30f;
  for (int o = 0; o < 81; ++o) {
    float s = 0.f;
    const float* dr = dapw + o * 81;
    for (int d = 0; d < 81; ++d) s += dr[d] * cb[t * 81 + d];
    sb[t * 81 + o] = s;
    smax = fmaxf(smax, s);
  }
  float sum = 0.f;
  for (int o = 0; o < 81; ++o) {
    const float e = __expf(sb[t * 81 + o] - smax);
    sb[t * 81 + o] = e;
    sum += e;
  }
  const float inv = 1.f / sum;
  for (int o = 0; o < 81; ++o)
    score[((size_t)(b * 81 + o)) * 4096 + hw] = sb[t * 81 + o] * inv;
}

// ---------------------------------------------------------------- emb reduce
__global__ __launch_bounds__(256) void emb_kernel(
    const float* __restrict__ score, const hf* __restrict__ e3, float* __restrict__ outp) {
  const int idx = blockIdx.x * 256 + threadIdx.x;  // 2*32*4096
  const int b = idx >> 17, r = idx & 131071, m = r >> 12, hw = r & 4095;
  float acc = 0.f;
  for (int d = 0; d < 81; ++d) {
    const float sc = score[((size_t)(b * 81 + d)) * 4096 + hw];
    acc += sc * (float)e3[(((size_t)(b * 81 + d)) * 4096 + hw) * 32 + m];
  }
  outp[((size_t)(b * 113 + 81 + m)) * 4096 + hw] = acc;
}

// ======================================================================
extern "C" void kernel_launch(void* const* d_in, const int* in_sizes, int n_in,
                              void* d_out, int out_size, void* d_ws, size_t ws_size,
                              hipStream_t stream) {
  const float* f1     = (const float*)d_in[0];
  const float* f2     = (const float*)d_in[1];
  const float* coords = (const float*)d_in[2];
  const float* w1     = (const float*)d_in[3];
  const float* g1     = (const float*)d_in[4];
  const float* bb1    = (const float*)d_in[5];
  const float* w2     = (const float*)d_in[6];
  const float* g2     = (const float*)d_in[7];
  const float* bb2    = (const float*)d_in[8];
  const float* w3     = (const float*)d_in[9];
  const float* g3     = (const float*)d_in[10];
  const float* bb3    = (const float*)d_in[11];
  const float* w4     = (const float*)d_in[12];
  const float* g4     = (const float*)d_in[13];
  const float* bb4    = (const float*)d_in[14];
  const float* wdcv   = (const float*)d_in[15];
  const float* gd     = (const float*)d_in[16];
  const float* bbd    = (const float*)d_in[17];
  const float* w5     = (const float*)d_in[18];
  const float* b5     = (const float*)d_in[19];
  const float* e1w    = (const float*)d_in[20];
  const float* e1bi   = (const float*)d_in[21];
  const float* e2w    = (const float*)d_in[22];
  const float* e2bi   = (const float*)d_in[23];
  const float* e3w    = (const float*)d_in[24];
  const float* e3bi   = (const float*)d_in[25];
  const float* dapw   = (const float*)d_in[26];
  float* out = (float*)d_out;
  char* ws = (char*)d_ws;

  hf* sA  = (hf*)(ws + OFF_SA);
  hf* f2s = (hf*)(ws + OFF_F2S);
  hf* be3 = (hf*)(ws + OFF_E3);
  hf* x1  = (hf*)(ws + OFF_X1);
  hf* x2  = (hf*)(ws + OFF_X2);
  hf* x3  = (hf*)(ws + OFF_X3);
  hf* x4  = (hf*)(ws + OFF_X4);
  hf* xd  = (hf*)(ws + OFF_XD);
  float* score = (float*)(ws + OFF_SCORE);
  float* stats = (float*)(ws + OFF_STATS);
  hf* wc1 = (hf*)(ws + OFF_WC1);
  hf* wc2 = (hf*)(ws + OFF_WC2);
  hf* wc3 = (hf*)(ws + OFF_WC3);
  hf* wc4 = (hf*)(ws + OFF_WC4);
  hf* wdc = (hf*)(ws + OFF_WDC);
  hf* we1 = (hf*)(ws + OFF_WE1);
  hf* we2 = (hf*)(ws + OFF_WE2);
  hf* we3 = (hf*)(ws + OFF_WE3);
  float* dt1 = (float*)(ws + OFF_DT1);
  float* dtE = (float*)(ws + OFF_DTE);
  float* f2clf = (float*)(ws + OFF_F2CLF);
  float* part = (float*)(ws + OFF_PART);

  hipMemsetAsync(stats, 0, 2560 * sizeof(float), stream);

  // all weight prepacks + delta tables + input packs in ONE launch
  prep<<<1748, 256, 0, stream>>>(w1, w2, w3, w4, wdcv, e1w, e2w, e3w, f1, f2,
                                 wc1, wc2, wc3, wc4, wdc, we1, we2, we3,
                                 dt1, dtE, sA, f2clf);

  // f2 sampling (depends on f2clf)
  sample2<<<2592, 256, 0, stream>>>(f2clf, coords, f2s);

  // embedding branch: fused e1+e2+e3
  efuse<<<dim3(16, 1, 162), 256, 0, stream>>>(f2s, sA, we1, e1bi, dtE, we2, e2bi, we3, e3bi, be3);

  // conv1: untouched r24 path; stats via f64-exact fused reduction
  mconv<0, 0, true, false, 32, 64, 96, 96, 3, 64, 64, 4, 4, true>
      <<<dim3(16, 2, 162), 256, 0, stream>>>(f2s, sA, wc1, nullptr, dt1, part, nullptr, x1, nullptr);
  bnredfin<<<96, 256, 0, stream>>>(part, stats + 0, g1, bb1, 2592, 1.0 / 663552.0);

  // conv2: weight-LDS tap-split + BN1 on read
  mconv2s2<<<dim3(8, 2, 162), 256, 0, stream>>>(x1, wc2, stats + 0, part, x2);
  bnredfin<<<128, 256, 0, stream>>>(part, stats + 512, g2, bb2, 1296, 1.0 / 165888.0);

  // conv3: weight-LDS path + BN2 on read
  mconv2<128, 128, 4, 4, 2, true>
      <<<dim3(8, 2, 162), 256, 0, stream>>>(x2, wc3, stats + 512, part, x3);
  bnredfin<<<128, 256, 0, stream>>>(part, stats + 1024, g3, bb3, 1296, 1.0 / 165888.0);

  // conv4: weight-LDS path + BN3 on read
  mconv2<128, 64, 4, 4, 2, true>
      <<<dim3(8, 1, 162), 256, 0, stream>>>(x3, wc4, stats + 1024, part, x4);
  bnredfin<<<64, 256, 0, stream>>>(part, stats + 1536, g4, bb4, 1296, 1.0 / 165888.0);

  // deconv: weight-LDS path + BN4 on read
  mconv2d<<<dim3(4, 4, 162), 256, 0, stream>>>(x4, wdc, stats + 1536, part, xd);
  bnredfin<<<32, 256, 0, stream>>>(part, stats + 2048, gd, bbd, 2592, 1.0 / 663552.0);

  // conv5 on VALU + BNd on read -> cost planes of out
  conv5_kernel<<<2592, 256, 0, stream>>>(xd, w5, b5, stats + 2048, out);

  // DAP softmax + embedding reduction
  softmax_kernel<<<128, 64, 0, stream>>>(out, dapw, score);
  emb_kernel<<<1024, 256, 0, stream>>>(score, be3, out);

  (void)in_sizes; (void)n_in; (void)out_size; (void)ws_size;
}

// Round 27
// 755.833 us; speedup vs baseline: 1.4083x; 1.0323x over previous
//
#include <hip/hip_runtime.h>
#include <hip/hip_bf16.h>

typedef _Float16 hf;
typedef short    s8v  __attribute__((ext_vector_type(8)));
typedef _Float16 h8v  __attribute__((ext_vector_type(8)));
typedef float    f32x4 __attribute__((ext_vector_type(4)));

#define DEVINL __device__ __forceinline__

DEVINL unsigned short f2h_bits(float f) { return __builtin_bit_cast(unsigned short, (hf)f); }
DEVINL float h2f_bits(unsigned short u) { return (float)__builtin_bit_cast(hf, u); }

// ---------------------------------------------------------------- arena
static constexpr size_t OFF_SA    = 0;
static constexpr size_t OFF_F2S   = 524288;
static constexpr size_t OFF_E3    = 42991616;
static constexpr size_t OFF_X1    = 85458944;
static constexpr size_t OFF_X2    = 524288;
static constexpr size_t OFF_X3    = 85458944;
static constexpr size_t OFF_X4    = 524288;
static constexpr size_t OFF_XD    = 127926272;
static constexpr size_t OFF_SCORE = 524288;
static constexpr size_t OFF_STATS = 212860928;
static constexpr size_t OFF_WC1   = 212871168;
static constexpr size_t OFF_WC2   = 212981760;
static constexpr size_t OFF_WC3   = 213202944;
static constexpr size_t OFF_WC4   = 213497856;
static constexpr size_t OFF_WDC   = 213645312;
static constexpr size_t OFF_WE1   = 213720064;
static constexpr size_t OFF_WE2   = 213726208;
static constexpr size_t OFF_WE3   = 213734400;
static constexpr size_t OFF_DT1   = 213738496;
static constexpr size_t OFF_DTE   = 213745408;
static constexpr size_t OFF_F2CLF = 213746048;
static constexpr size_t OFF_PART  = 214794752;  // BN stat partials (fp32), reused per conv

// ---------------------------------------------------------------- prep sub-bodies (verbatim, idx-rebased)
DEVINL void prep_prepack(int idx, const float* __restrict__ src, hf* __restrict__ dst,
                         int COr, int COP, int CINr, int CINsrc, int KP, int TAPS) {
  const int total = TAPS * COP * KP;
  if (idx >= total) return;
  const int k = idx % KP;
  const int r = idx / KP;
  const int co = r % COP;
  const int t = r / COP;
  float v = 0.f;
  if (co < COr && k < CINr) v = src[((size_t)co * CINsrc + k) * TAPS + t];
  dst[idx] = (hf)v;
}

DEVINL void prep_prepack2(int idx, const float* __restrict__ src, hf* __restrict__ dst,
                          int COP, int CIN, int NCHn) {
  const int total = 9 * NCHn * COP * 32;
  if (idx >= total) return;
  const int kk = idx & 31;
  const int r = idx >> 5;
  const int co = r % COP;
  const int r2 = r / COP;
  const int ks = r2 % NCHn;
  const int t = r2 / NCHn;
  dst[idx] = (hf)src[((size_t)co * CIN + ks * 32 + kk) * 9 + t];
}

DEVINL void prep_prepack2d(int idx, const float* __restrict__ src, hf* __restrict__ dst) {
  if (idx >= 32768) return;
  const int kk = idx & 31;
  const int co = (idx >> 5) & 31;
  const int ks = (idx >> 10) & 1;
  const int tt = (idx >> 11) & 3;
  const int par = idx >> 13;
  const int qq = par >> 1, pp = par & 1;
  const int a = tt >> 1, b = tt & 1;
  dst[idx] = (hf)src[(((size_t)co * 64 + ks * 32 + kk) * 4 + (qq + 2 * a)) * 4 + (pp + 2 * b)];
}

DEVINL void prep_dtab1(int idx, const float* __restrict__ w1, float* __restrict__ dtab) {
  if (idx >= 96 * 9 * 2) return;
  const int c = idx & 1;
  const int r = idx >> 1;
  const int pat = r % 9;
  const int co = r / 9;
  const int rc = pat / 3, cc = pat % 3;
  const int kh0 = (rc == 0) ? 1 : 0, kh1 = (rc == 2) ? 1 : 2;
  const int kw0 = (cc == 0) ? 1 : 0, kw1 = (cc == 2) ? 1 : 2;
  float s = 0.f;
  for (int kh = kh0; kh <= kh1; ++kh)
    for (int kw = kw0; kw <= kw1; ++kw)
      s += w1[((size_t)(co * 66 + 64 + c) * 3 + kh) * 3 + kw];
  dtab[(co * 9 + pat) * 2 + c] = s;
}

DEVINL void prep_dtabE(int co, const float* __restrict__ e1w, float* __restrict__ dtE) {
  if (co < 48) {
    dtE[co * 2 + 0] = e1w[co * 66 + 64];
    dtE[co * 2 + 1] = e1w[co * 66 + 65];
  }
}

DEVINL void prep_packf1(int gid, const float* __restrict__ f1, hf* __restrict__ sA) {
  const int b = gid >> 12, pix = gid & 4095;
  unsigned words[16];
#pragma unroll
  for (int c = 0; c < 32; c += 2) {
    const float v0 = f1[((size_t)(b * 32 + c)) * 4096 + pix];
    const float v1 = f1[((size_t)(b * 32 + c + 1)) * 4096 + pix];
    words[c >> 1] = (unsigned)f2h_bits(v0) | ((unsigned)f2h_bits(v1) << 16);
  }
  uint4* dst = (uint4*)(sA + (size_t)gid * 32);
#pragma unroll
  for (int i = 0; i < 4; ++i)
    dst[i] = make_uint4(words[4 * i], words[4 * i + 1], words[4 * i + 2], words[4 * i + 3]);
}

DEVINL void prep_packf2(int gid, const float* __restrict__ f2, float* __restrict__ dst) {
  const int b = gid >> 12, pix = gid & 4095;
  float* op = dst + (size_t)gid * 32;
#pragma unroll
  for (int c = 0; c < 32; c += 4) {
    float4 v;
    v.x = f2[((size_t)(b * 32 + c + 0)) * 4096 + pix];
    v.y = f2[((size_t)(b * 32 + c + 1)) * 4096 + pix];
    v.z = f2[((size_t)(b * 32 + c + 2)) * 4096 + pix];
    v.w = f2[((size_t)(b * 32 + c + 3)) * 4096 + pix];
    *(float4*)(op + c) = v;
  }
}

// ---------------------------------------------------------------- prep mega-kernel
__global__ __launch_bounds__(256) void prep(
    const float* __restrict__ w1, const float* __restrict__ w2,
    const float* __restrict__ w3, const float* __restrict__ w4,
    const float* __restrict__ wdcv,
    const float* __restrict__ e1w, const float* __restrict__ e2w,
    const float* __restrict__ e3w,
    const float* __restrict__ f1, const float* __restrict__ f2,
    hf* __restrict__ wc1, hf* __restrict__ wc2, hf* __restrict__ wc3,
    hf* __restrict__ wc4, hf* __restrict__ wdc,
    hf* __restrict__ we1, hf* __restrict__ we2, hf* __restrict__ we3,
    float* __restrict__ dt1, float* __restrict__ dtE,
    hf* __restrict__ sA, float* __restrict__ f2clf) {
  const int b = blockIdx.x, t = threadIdx.x;
  if      (b < 216)  prep_prepack((b - 0) * 256 + t,    w1,  wc1, 96, 96, 64, 66, 64, 9);
  else if (b < 648)  prep_prepack2((b - 216) * 256 + t, w2,  wc2, 128, 96, 3);
  else if (b < 1224) prep_prepack2((b - 648) * 256 + t, w3,  wc3, 128, 128, 4);
  else if (b < 1512) prep_prepack2((b - 1224) * 256 + t, w4, wc4, 64, 128, 4);
  else if (b < 1640) prep_prepack2d((b - 1512) * 256 + t, wdcv, wdc);
  else if (b < 1652) prep_prepack((b - 1640) * 256 + t, e1w, we1, 48, 48, 64, 66, 64, 1);
  else if (b < 1668) prep_prepack((b - 1652) * 256 + t, e2w, we2, 64, 64, 48, 48, 64, 1);
  else if (b < 1676) prep_prepack((b - 1668) * 256 + t, e3w, we3, 32, 32, 64, 64, 64, 1);
  else if (b < 1683) prep_dtab1((b - 1676) * 256 + t,   w1,  dt1);
  else if (b < 1684) prep_dtabE(t, e1w, dtE);
  else if (b < 1716) prep_packf1((b - 1684) * 256 + t,  f1,  sA);
  else               prep_packf2((b - 1716) * 256 + t,  f2,  f2clf);
}

// ---------------------------------------------------------------- sample2
__global__ __launch_bounds__(256) void sample2(const float* __restrict__ f2clf,
                                               const float* __restrict__ coords,
                                               hf* __restrict__ f2s) {
  const int gid = blockIdx.x * 256 + threadIdx.x;  // 162*4096
  const int n = gid >> 12, pix = gid & 4095;
  const int b = n / 81, ij = n - b * 81;
  const float di = (float)(ij / 9) - 4.f, dj = (float)(ij % 9) - 4.f;
  const float x = coords[((size_t)(b * 2 + 0)) * 4096 + pix] + di;
  const float y = coords[((size_t)(b * 2 + 1)) * 4096 + pix] + dj;
  const float x0f = floorf(x), y0f = floorf(y);
  const int x0 = (int)x0f, y0 = (int)y0f;
  const float wx1 = x - x0f, wx0 = 1.f - wx1;
  const float wy1 = y - y0f, wy0 = 1.f - wy1;
  const bool vx0 = (unsigned)x0 < 64u, vx1 = (unsigned)(x0 + 1) < 64u;
  const bool vy0 = (unsigned)y0 < 64u, vy1 = (unsigned)(y0 + 1) < 64u;
  const int x0c = min(max(x0, 0), 63), x1c = min(max(x0 + 1, 0), 63);
  const int y0c = min(max(y0, 0), 63), y1c = min(max(y0 + 1, 0), 63);
  const float w00 = (vy0 && vx0) ? wy0 * wx0 : 0.f;
  const float w01 = (vy0 && vx1) ? wy0 * wx1 : 0.f;
  const float w10 = (vy1 && vx0) ? wy1 * wx0 : 0.f;
  const float w11 = (vy1 && vx1) ? wy1 * wx1 : 0.f;
  const float* fb = f2clf + (size_t)b * 4096 * 32;
  const float* p00 = fb + (size_t)(y0c * 64 + x0c) * 32;
  const float* p01 = fb + (size_t)(y0c * 64 + x1c) * 32;
  const float* p10 = fb + (size_t)(y1c * 64 + x0c) * 32;
  const float* p11 = fb + (size_t)(y1c * 64 + x1c) * 32;
  unsigned words[16];
#pragma unroll
  for (int ch = 0; ch < 16; ++ch) {
    const float2 a  = *(const float2*)(p00 + ch * 2);
    const float2 bb = *(const float2*)(p01 + ch * 2);
    const float2 c  = *(const float2*)(p10 + ch * 2);
    const float2 d  = *(const float2*)(p11 + ch * 2);
    const float v0 = w00 * a.x + w01 * bb.x + w10 * c.x + w11 * d.x;
    const float v1 = w00 * a.y + w01 * bb.y + w10 * c.y + w11 * d.y;
    words[ch] = (unsigned)f2h_bits(v0) | ((unsigned)f2h_bits(v1) << 16);
  }
  uint4* dst = (uint4*)(f2s + (size_t)gid * 32);
#pragma unroll
  for (int i = 0; i < 4; ++i)
    dst[i] = make_uint4(words[4 * i], words[4 * i + 1], words[4 * i + 2], words[4 * i + 3]);
}

// ---------------------------------------------------------------- BNIN helper
DEVINL s8v bnin_apply(s8v v, const float* bnst, int gci) {
  const f32x4 scA = *(const f32x4*)(bnst + 256 + gci);
  const f32x4 scB = *(const f32x4*)(bnst + 256 + gci + 4);
  const f32x4 shA = *(const f32x4*)(bnst + 384 + gci);
  const f32x4 shB = *(const f32x4*)(bnst + 384 + gci + 4);
  h8v h = __builtin_bit_cast(h8v, v);
#pragma unroll
  for (int jj = 0; jj < 8; ++jj) {
    const float sc = (jj < 4) ? scA[jj] : scB[jj - 4];
    const float sh = (jj < 4) ? shA[jj] : shB[jj - 4];
    h[jj] = (hf)fmaxf((float)h[jj] * sc + sh, 0.f);
  }
  return __builtin_bit_cast(s8v, h);
}

// ---------------------------------------------------------------- MFMA conv template (stats -> partial store)
template <int GEOM, int EPI, bool DUAL, bool BNIN, int G, int KP, int COP, int COB, int MFR,
          int IMGO, int IMGI, int PIXROWS, int WPIX, bool DELTA>
__global__ __launch_bounds__(256) void mconv(
    const hf* __restrict__ src1, const hf* __restrict__ src0,
    const hf* __restrict__ wp, const float* __restrict__ bias,
    const float* __restrict__ dtab, float* __restrict__ statL,
    const float* __restrict__ bnst,
    hf* __restrict__ outB, float* __restrict__ outF) {
  constexpr bool DIRECT = (GEOM == 3);
  constexpr int TAPS  = (GEOM == 2) ? 4 : (GEOM == 3) ? 1 : 9;
  constexpr int TR    = (GEOM == 1) ? (2 * PIXROWS + 1) : (GEOM == 3) ? 1 : (PIXROWS + 2);
  constexpr int TC    = (GEOM == 1) ? 65 : (GEOM == 3) ? 1 : (IMGI + 2);
  constexpr int NSLOT = TR * TC;
  constexpr int PSTR  = NSLOT + 1;
  constexpr int NCH   = KP / 32;
  constexpr int NPIXI = IMGI * IMGI;
  constexpr int NPIXO = (GEOM == 2) ? 4096 : IMGO * IMGO;
  constexpr int NCHUNK = NSLOT * 4;
  constexpr int CPT   = (NCHUNK + 255) / 256;
  constexpr int LDSE  = DIRECT ? 64 : 4 * PSTR * 8;

  __shared__ __align__(16) hf lds[LDSE];

  const int tid = threadIdx.x;
  const int wid = tid >> 6, lane = tid & 63, lg = lane >> 4, ln = lane & 15;
  const int n = blockIdx.z, b = n / 81, ij = n - b * 81;
  const int r0 = blockIdx.x * PIXROWS;
  const int qq = (GEOM == 2) ? (int)(blockIdx.y >> 1) : 0;
  const int pp = (GEOM == 2) ? (int)(blockIdx.y & 1) : 0;
  const int co0 = (GEOM == 2) ? 0 : (int)blockIdx.y * (MFR * 16);

  f32x4 acc[MFR][WPIX];
#pragma unroll
  for (int mf = 0; mf < MFR; ++mf)
#pragma unroll
    for (int pf = 0; pf < WPIX; ++pf) acc[mf][pf] = (f32x4){0.f, 0.f, 0.f, 0.f};

  if constexpr (DIRECT) {
#pragma unroll
    for (int ch = 0; ch < NCH; ++ch) {
      const int k0 = ch * 32;
      h8v afr[MFR];
#pragma unroll
      for (int mf = 0; mf < MFR; ++mf)
        afr[mf] = *(const h8v*)(wp + ((size_t)(co0 + mf * 16 + ln)) * KP + k0 + lg * 8);
#pragma unroll
      for (int pf = 0; pf < WPIX; ++pf) {
        const int pix = r0 * IMGO + wid * (WPIX * 16) + pf * 16 + ln;
        h8v bfr = (h8v){0, 0, 0, 0, 0, 0, 0, 0};
        if (DUAL) {
          bfr = (ch == 0)
              ? *(const h8v*)(src0 + (((size_t)b * NPIXI + pix) * 32 + lg * 8))
              : *(const h8v*)(src1 + (((size_t)n * NPIXI + pix) * 32 + lg * 8));
        } else {
          const int gci = k0 + lg * 8;
          if (gci < G)
            bfr = *(const h8v*)(src1 + (((size_t)n * NPIXI + pix) * G + gci));
        }
#pragma unroll
        for (int mf = 0; mf < MFR; ++mf)
          acc[mf][pf] = __builtin_amdgcn_mfma_f32_16x16x32_f16(afr[mf], bfr, acc[mf][pf], 0, 0, 0);
      }
    }
  } else {
    s8v rbuf[CPT];
    auto stage_load = [&](int k0) {
#pragma unroll
      for (int j = 0; j < CPT; ++j) {
        const int cidx = tid + j * 256;
        s8v v = (s8v){0, 0, 0, 0, 0, 0, 0, 0};
        if (cidx < NCHUNK) {
          const int s = cidx >> 2, p = cidx & 3;
          const int rs = s / TC, cs = s - rs * TC;
          int ir, ic;
          if (GEOM == 1) { ir = 2 * r0 - 1 + rs; ic = (cs < 32) ? 2 * cs : 2 * (cs - 32) - 1; }
          else           { ir = r0 - 1 + rs;     ic = cs - 1; }
          const int gci = k0 + p * 8;
          if (((unsigned)ir < (unsigned)IMGI) && ((unsigned)ic < (unsigned)IMGI)) {
            const int ipix = ir * IMGI + ic;
            if (DUAL) {
              if (gci < 32)
                v = *(const s8v*)(src0 + (((size_t)b * NPIXI + ipix) * 32 + gci));
              else
                v = *(const s8v*)(src1 + (((size_t)n * NPIXI + ipix) * 32 + (gci - 32)));
            } else if (gci < G) {
              v = *(const s8v*)(src1 + (((size_t)n * NPIXI + ipix) * G + gci));
              if constexpr (BNIN) v = bnin_apply(v, bnst, gci);
            }
          }
        }
        rbuf[j] = v;
      }
    };
    auto stage_write = [&]() {
#pragma unroll
      for (int j = 0; j < CPT; ++j) {
        const int cidx = tid + j * 256;
        if (cidx < NCHUNK) {
          const int s = cidx >> 2, p = cidx & 3;
          *(s8v*)(&lds[(size_t)(p * PSTR + s) * 8]) = rbuf[j];
        }
      }
    };

    stage_load(0);
#pragma unroll
    for (int ch = 0; ch < NCH; ++ch) {
      if (ch > 0) __syncthreads();
      stage_write();
      __syncthreads();
      if (ch + 1 < NCH) stage_load((ch + 1) * 32);
      const int k0 = ch * 32;
#pragma unroll
      for (int t = 0; t < TAPS; ++t) {
        int dh, dw, wt, kh = 0, kw = 0;
        if (GEOM == 2) {
          dh = qq + (t >> 1) - 1; dw = pp + (t & 1) - 1;
          wt = (qq + 2 * (t >> 1)) * 4 + (pp + 2 * (t & 1));
        } else { kh = t / 3; kw = t % 3; dh = kh - 1; dw = kw - 1; wt = t; }
        h8v afr[MFR];
#pragma unroll
        for (int mf = 0; mf < MFR; ++mf)
          afr[mf] = *(const h8v*)(wp + ((size_t)(wt * COP + co0 + mf * 16 + ln)) * KP + k0 + lg * 8);
#pragma unroll
        for (int pf = 0; pf < WPIX; ++pf) {
          const int pl = wid * (WPIX * 16) + pf * 16 + ln;
          const int rL = pl / IMGO, c = pl - rL * IMGO;
          int slot;
          if (GEOM == 1) slot = (2 * rL + kh) * 65 + ((kw == 1) ? c : (32 + c + (kw >> 1)));
          else           slot = (rL + dh + 1) * TC + (c + dw + 1);
          const h8v bfr = *(const h8v*)(&lds[(size_t)(lg * PSTR + slot) * 8]);
#pragma unroll
          for (int mf = 0; mf < MFR; ++mf)
            acc[mf][pf] = __builtin_amdgcn_mfma_f32_16x16x32_f16(afr[mf], bfr, acc[mf][pf], 0, 0, 0);
        }
      }
    }
  }

  const float di = (float)(ij / 9) - 4.f, dj = (float)(ij % 9) - 4.f;

  {
#pragma unroll
    for (int mf = 0; mf < MFR; ++mf) {
#pragma unroll
      for (int pf = 0; pf < WPIX; ++pf) {
        const int pl = wid * (WPIX * 16) + pf * 16 + ln;
        const int rL = pl / IMGO, c = pl - rL * IMGO;
        int opix;
        if constexpr (GEOM == 2) opix = (2 * (r0 + rL) + qq) * 64 + 2 * c + pp;
        else opix = (r0 + rL) * IMGO + c;
        if constexpr (DELTA && EPI == 0) {
          const int oh = r0 + rL;
          const int rc = (oh == 0) ? 0 : ((oh == IMGO - 1) ? 2 : 1);
          const int cc = (c == 0) ? 0 : ((c == IMGO - 1) ? 2 : 1);
#pragma unroll
          for (int rg = 0; rg < 4; ++rg) {
            const int co = co0 + mf * 16 + lg * 4 + rg;
            acc[mf][pf][rg] += di * dtab[(co * 9 + rc * 3 + cc) * 2 + 0] +
                               dj * dtab[(co * 9 + rc * 3 + cc) * 2 + 1];
          }
        }
        if constexpr (DELTA && EPI == 1) {
#pragma unroll
          for (int rg = 0; rg < 4; ++rg) {
            const int co = co0 + mf * 16 + lg * 4 + rg;
            acc[mf][pf][rg] += di * dtab[co * 2] + dj * dtab[co * 2 + 1];
          }
        }
        if constexpr (EPI == 1 || EPI == 2) {
          const float4 bv = *(const float4*)(bias + co0 + mf * 16 + lg * 4);
          acc[mf][pf][0] += bv.x; acc[mf][pf][1] += bv.y;
          acc[mf][pf][2] += bv.z; acc[mf][pf][3] += bv.w;
          if constexpr (EPI == 1) {
#pragma unroll
            for (int rg = 0; rg < 4; ++rg) acc[mf][pf][rg] = fmaxf(acc[mf][pf][rg], 0.f);
          }
        }
        ushort4 st;
        st.x = f2h_bits(acc[mf][pf][0]); st.y = f2h_bits(acc[mf][pf][1]);
        st.z = f2h_bits(acc[mf][pf][2]); st.w = f2h_bits(acc[mf][pf][3]);
        *reinterpret_cast<ushort4*>(outB + ((size_t)n * NPIXO + opix) * COB + co0 + mf * 16 + lg * 4) = st;
      }
    }
    if constexpr (EPI == 0) {
      __syncthreads();
      float* sl = (float*)lds;
#pragma unroll
      for (int mf = 0; mf < MFR; ++mf) {
#pragma unroll
        for (int rg = 0; rg < 4; ++rg) {
          float s = 0.f, q2 = 0.f;
#pragma unroll
          for (int pf = 0; pf < WPIX; ++pf) {
            const float v = acc[mf][pf][rg];
            s += v; q2 += v * v;
          }
#pragma unroll
          for (int o = 1; o < 16; o <<= 1) { s += __shfl_xor(s, o); q2 += __shfl_xor(q2, o); }
          if (ln == 0) {
            const int cl = mf * 16 + lg * 4 + rg;
            sl[(wid * MFR * 16 + cl) * 2 + 0] = s;
            sl[(wid * MFR * 16 + cl) * 2 + 1] = q2;
          }
        }
      }
      __syncthreads();
      const int NPB = gridDim.x * gridDim.z;
      const int pb = (int)blockIdx.x * gridDim.z + blockIdx.z;
      for (int i = tid; i < MFR * 16 * 2; i += 256) {
        const int cl = i >> 1, stt = i & 1;
        float tot = 0.f;
#pragma unroll
        for (int w = 0; w < 4; ++w) tot += sl[(w * MFR * 16 + cl) * 2 + stt];
        statL[(size_t)((co0 + cl) * 2 + stt) * NPB + pb] = tot;
      }
    }
  }
  (void)outF;
}

// ---------------------------------------------------------------- efuse: e1+e2+e3 fused via LDS relays
__global__ __launch_bounds__(256) void efuse(
    const hf* __restrict__ f2s_, const hf* __restrict__ sA_,
    const hf* __restrict__ w1p, const float* __restrict__ b1v, const float* __restrict__ dtE,
    const hf* __restrict__ w2p, const float* __restrict__ b2v,
    const hf* __restrict__ w3p, const float* __restrict__ b3v,
    hf* __restrict__ outB) {
  constexpr int PSTRE = 72;
  __shared__ __align__(16) hf ldsA[256 * PSTRE];
  __shared__ __align__(16) hf ldsB[256 * PSTRE];

  const int tid = threadIdx.x;
  const int wid = tid >> 6, lane = tid & 63, lg = lane >> 4, ln = lane & 15;
  const int n = blockIdx.z, b = n / 81, ij = n - b * 81;
  const int r0 = blockIdx.x * 4;
  const float di = (float)(ij / 9) - 4.f, dj = (float)(ij % 9) - 4.f;

  // e1: (f1,f2s) 64 -> 48
  f32x4 acc1[3][4];
#pragma unroll
  for (int mf = 0; mf < 3; ++mf)
#pragma unroll
    for (int pf = 0; pf < 4; ++pf) acc1[mf][pf] = (f32x4){0.f, 0.f, 0.f, 0.f};
#pragma unroll
  for (int ch = 0; ch < 2; ++ch) {
    const int k0 = ch * 32;
    h8v afr[3];
#pragma unroll
    for (int mf = 0; mf < 3; ++mf)
      afr[mf] = *(const h8v*)(w1p + ((size_t)(mf * 16 + ln)) * 64 + k0 + lg * 8);
#pragma unroll
    for (int pf = 0; pf < 4; ++pf) {
      const int pix = r0 * 64 + wid * 64 + pf * 16 + ln;
      const h8v bfr = (ch == 0)
          ? *(const h8v*)(sA_ + (((size_t)b * 4096 + pix) * 32 + lg * 8))
          : *(const h8v*)(f2s_ + (((size_t)n * 4096 + pix) * 32 + lg * 8));
#pragma unroll
      for (int mf = 0; mf < 3; ++mf)
        acc1[mf][pf] = __builtin_amdgcn_mfma_f32_16x16x32_f16(afr[mf], bfr, acc1[mf][pf], 0, 0, 0);
    }
  }
#pragma unroll
  for (int mf = 0; mf < 3; ++mf) {
#pragma unroll
    for (int pf = 0; pf < 4; ++pf) {
      const int pixL = wid * 64 + pf * 16 + ln;
#pragma unroll
      for (int rg = 0; rg < 4; ++rg) {
        const int co = mf * 16 + lg * 4 + rg;
        acc1[mf][pf][rg] += di * dtE[co * 2] + dj * dtE[co * 2 + 1];
      }
      const float4 bv = *(const float4*)(b1v + mf * 16 + lg * 4);
      acc1[mf][pf][0] += bv.x; acc1[mf][pf][1] += bv.y;
      acc1[mf][pf][2] += bv.z; acc1[mf][pf][3] += bv.w;
#pragma unroll
      for (int rg = 0; rg < 4; ++rg) acc1[mf][pf][rg] = fmaxf(acc1[mf][pf][rg], 0.f);
      ushort4 st;
      st.x = f2h_bits(acc1[mf][pf][0]); st.y = f2h_bits(acc1[mf][pf][1]);
      st.z = f2h_bits(acc1[mf][pf][2]); st.w = f2h_bits(acc1[mf][pf][3]);
      *reinterpret_cast<ushort4*>(&ldsA[(size_t)pixL * PSTRE + mf * 16 + lg * 4]) = st;
    }
  }
  for (int z = tid; z < 256 * 16; z += 256)
    ldsA[(size_t)(z >> 4) * PSTRE + 48 + (z & 15)] = (hf)0.f;
  __syncthreads();

  // e2: 48(+pad) -> 64
  f32x4 acc2[4][4];
#pragma unroll
  for (int mf = 0; mf < 4; ++mf)
#pragma unroll
    for (int pf = 0; pf < 4; ++pf) acc2[mf][pf] = (f32x4){0.f, 0.f, 0.f, 0.f};
#pragma unroll
  for (int ch = 0; ch < 2; ++ch) {
    const int k0 = ch * 32;
    h8v afr[4];
#pragma unroll
    for (int mf = 0; mf < 4; ++mf)
      afr[mf] = *(const h8v*)(w2p + ((size_t)(mf * 16 + ln)) * 64 + k0 + lg * 8);
#pragma unroll
    for (int pf = 0; pf < 4; ++pf) {
      const int pixL = wid * 64 + pf * 16 + ln;
      const h8v bfr = *(const h8v*)(&ldsA[(size_t)pixL * PSTRE + k0 + lg * 8]);
#pragma unroll
      for (int mf = 0; mf < 4; ++mf)
        acc2[mf][pf] = __builtin_amdgcn_mfma_f32_16x16x32_f16(afr[mf], bfr, acc2[mf][pf], 0, 0, 0);
    }
  }
#pragma unroll
  for (int mf = 0; mf < 4; ++mf) {
#pragma unroll
    for (int pf = 0; pf < 4; ++pf) {
      const int pixL = wid * 64 + pf * 16 + ln;
      const float4 bv = *(const float4*)(b2v + mf * 16 + lg * 4);
      acc2[mf][pf][0] += bv.x; acc2[mf][pf][1] += bv.y;
      acc2[mf][pf][2] += bv.z; acc2[mf][pf][3] += bv.w;
#pragma unroll
      for (int rg = 0; rg < 4; ++rg) acc2[mf][pf][rg] = fmaxf(acc2[mf][pf][rg], 0.f);
      ushort4 st;
      st.x = f2h_bits(acc2[mf][pf][0]); st.y = f2h_bits(acc2[mf][pf][1]);
      st.z = f2h_bits(acc2[mf][pf][2]); st.w = f2h_bits(acc2[mf][pf][3]);
      *reinterpret_cast<ushort4*>(&ldsB[(size_t)pixL * PSTRE + mf * 16 + lg * 4]) = st;
    }
  }
  __syncthreads();

  // e3: 64 -> 32 -> global
  f32x4 acc3[2][4];
#pragma unroll
  for (int mf = 0; mf < 2; ++mf)
#pragma unroll
    for (int pf = 0; pf < 4; ++pf) acc3[mf][pf] = (f32x4){0.f, 0.f, 0.f, 0.f};
#pragma unroll
  for (int ch = 0; ch < 2; ++ch) {
    const int k0 = ch * 32;
    h8v afr[2];
#pragma unroll
    for (int mf = 0; mf < 2; ++mf)
      afr[mf] = *(const h8v*)(w3p + ((size_t)(mf * 16 + ln)) * 64 + k0 + lg * 8);
#pragma unroll
    for (int pf = 0; pf < 4; ++pf) {
      const int pixL = wid * 64 + pf * 16 + ln;
      const h8v bfr = *(const h8v*)(&ldsB[(size_t)pixL * PSTRE + k0 + lg * 8]);
#pragma unroll
      for (int mf = 0; mf < 2; ++mf)
        acc3[mf][pf] = __builtin_amdgcn_mfma_f32_16x16x32_f16(afr[mf], bfr, acc3[mf][pf], 0, 0, 0);
    }
  }
#pragma unroll
  for (int mf = 0; mf < 2; ++mf) {
#pragma unroll
    for (int pf = 0; pf < 4; ++pf) {
      const int pix = r0 * 64 + wid * 64 + pf * 16 + ln;
      const float4 bv = *(const float4*)(b3v + mf * 16 + lg * 4);
      acc3[mf][pf][0] += bv.x; acc3[mf][pf][1] += bv.y;
      acc3[mf][pf][2] += bv.z; acc3[mf][pf][3] += bv.w;
      ushort4 st;
      st.x = f2h_bits(acc3[mf][pf][0]); st.y = f2h_bits(acc3[mf][pf][1]);
      st.z = f2h_bits(acc3[mf][pf][2]); st.w = f2h_bits(acc3[mf][pf][3]);
      *reinterpret_cast<ushort4*>(outB + (((size_t)n * 4096 + pix) * 32 + mf * 16 + lg * 4)) = st;
    }
  }
}

// ---------------------------------------------------------------- mconv2s2 (stats -> partial store)
__global__ __launch_bounds__(256) void mconv2s2(
    const hf* __restrict__ src1, const hf* __restrict__ wp,
    const float* __restrict__ bnst, float* __restrict__ statL, hf* __restrict__ outB) {
  constexpr int IMGI = 64, IMGO = 32;
  constexpr int PIXROWS = 4, WPIX = 2, MFR = 4;
  constexpr int TR = 2 * PIXROWS + 1;
  constexpr int TC = 65;
  constexpr int NSLOT = TR * TC;
  constexpr int PSTR = NSLOT + 1;
  constexpr int NCH = 3;
  constexpr int G = 96;
  constexpr int NPIXI = IMGI * IMGI;
  constexpr int NCHUNK = NSLOT * 4;
  constexpr int COT = MFR * 16;
  constexpr int COP = 128;
  constexpr int WPLANE = 3 * COT;
  constexpr int WPSTR  = WPLANE + 1;
  constexpr int WCHUNK = WPLANE * 4;

  __shared__ __align__(16) hf alds[4 * PSTR * 8];
  __shared__ __align__(16) hf wlds[4 * WPSTR * 8];

  const int tid = threadIdx.x;
  const int wid = tid >> 6, lane = tid & 63, lg = lane >> 4, ln = lane & 15;
  const int n = blockIdx.z;
  const int r0 = blockIdx.x * PIXROWS;
  const int co0 = (int)blockIdx.y * COT;

  f32x4 acc[MFR][WPIX];
#pragma unroll
  for (int mf = 0; mf < MFR; ++mf)
#pragma unroll
    for (int pf = 0; pf < WPIX; ++pf) acc[mf][pf] = (f32x4){0.f, 0.f, 0.f, 0.f};

  for (int ks = 0; ks < NCH; ++ks) {
    const int k0 = ks * 32;
    __syncthreads();
    for (int cidx = tid; cidx < NCHUNK; cidx += 256) {
      const int s = cidx >> 2, p = cidx & 3;
      const int rs = s / TC, cs = s - rs * TC;
      const int ir = 2 * r0 - 1 + rs;
      const int ic = (cs < 32) ? 2 * cs : 2 * (cs - 32) - 1;
      s8v v = (s8v){0, 0, 0, 0, 0, 0, 0, 0};
      const int gci = k0 + p * 8;
      if (((unsigned)ir < (unsigned)IMGI) && ((unsigned)ic < (unsigned)IMGI)) {
        const int ipix = ir * IMGI + ic;
        v = *(const s8v*)(src1 + (((size_t)n * NPIXI + ipix) * G + gci));
        v = bnin_apply(v, bnst, gci);
      }
      *(s8v*)(&alds[(size_t)(p * PSTR + s) * 8]) = v;
    }
#pragma unroll
    for (int tg = 0; tg < 3; ++tg) {
      if (tg > 0) __syncthreads();
      for (int widx = tid; widx < WCHUNK; widx += 256) {
        const int p = widx & 3;
        const int r = widx >> 2;
        const int co = r & (COT - 1);
        const int tt = r >> 6;
        const int tglob = tg * 3 + tt;
        const s8v wv = *(const s8v*)(wp + (((size_t)(tglob * NCH + ks) * COP + co0 + co) * 32 + p * 8));
        *(s8v*)(&wlds[(size_t)(p * WPSTR + r) * 8]) = wv;
      }
      __syncthreads();
#pragma unroll
      for (int tt = 0; tt < 3; ++tt) {
        const int kh = tg, kw = tt;
        h8v afr[MFR];
#pragma unroll
        for (int mf = 0; mf < MFR; ++mf)
          afr[mf] = *(const h8v*)(&wlds[(size_t)(lg * WPSTR + tt * COT + mf * 16 + ln) * 8]);
#pragma unroll
        for (int pf = 0; pf < WPIX; ++pf) {
          const int pl = wid * (WPIX * 16) + pf * 16 + ln;
          const int rL = pl / IMGO, c = pl - rL * IMGO;
          const int slot = (2 * rL + kh) * 65 + ((kw == 1) ? c : (32 + c + (kw >> 1)));
          const h8v bfr = *(const h8v*)(&alds[(size_t)(lg * PSTR + slot) * 8]);
#pragma unroll
          for (int mf = 0; mf < MFR; ++mf)
            acc[mf][pf] = __builtin_amdgcn_mfma_f32_16x16x32_f16(afr[mf], bfr, acc[mf][pf], 0, 0, 0);
        }
      }
    }
  }

#pragma unroll
  for (int mf = 0; mf < MFR; ++mf) {
#pragma unroll
    for (int pf = 0; pf < WPIX; ++pf) {
      const int pl = wid * (WPIX * 16) + pf * 16 + ln;
      const int rL = pl / IMGO, c = pl - rL * IMGO;
      const int opix = (r0 + rL) * IMGO + c;
      ushort4 st;
      st.x = f2h_bits(acc[mf][pf][0]); st.y = f2h_bits(acc[mf][pf][1]);
      st.z = f2h_bits(acc[mf][pf][2]); st.w = f2h_bits(acc[mf][pf][3]);
      *reinterpret_cast<ushort4*>(outB + ((size_t)n * 1024 + opix) * COP + co0 + mf * 16 + lg * 4) = st;
    }
  }
  __syncthreads();
  float* sl = (float*)alds;
#pragma unroll
  for (int mf = 0; mf < MFR; ++mf) {
#pragma unroll
    for (int rg = 0; rg < 4; ++rg) {
      float s = 0.f, q2 = 0.f;
#pragma unroll
      for (int pf = 0; pf < WPIX; ++pf) {
        const float v = acc[mf][pf][rg];
        s += v; q2 += v * v;
      }
#pragma unroll
      for (int o = 1; o < 16; o <<= 1) { s += __shfl_xor(s, o); q2 += __shfl_xor(q2, o); }
      if (ln == 0) {
        const int cl = mf * 16 + lg * 4 + rg;
        sl[(wid * MFR * 16 + cl) * 2 + 0] = s;
        sl[(wid * MFR * 16 + cl) * 2 + 1] = q2;
      }
    }
  }
  __syncthreads();
  const int NPB = gridDim.x * gridDim.z;
  const int pb = (int)blockIdx.x * gridDim.z + blockIdx.z;
  for (int i = tid; i < MFR * 16 * 2; i += 256) {
    const int cl = i >> 1, stt = i & 1;
    float tot = 0.f;
#pragma unroll
    for (int w = 0; w < 4; ++w) tot += sl[(w * MFR * 16 + cl) * 2 + stt];
    statL[(size_t)((co0 + cl) * 2 + stt) * NPB + pb] = tot;
  }
}

// ---------------------------------------------------------------- mconv2 (stats -> partial store)
template <int G, int COP, int MFR, int PIXROWS, int WPIX, bool BNIN>
__global__ __launch_bounds__(256) void mconv2(
    const hf* __restrict__ src1, const hf* __restrict__ wp,
    const float* __restrict__ bnst,
    float* __restrict__ statL, hf* __restrict__ outB) {
  constexpr int IMG = 32;
  constexpr int TAPS = 9;
  constexpr int TC = IMG + 2;
  constexpr int TR = PIXROWS + 2;
  constexpr int NSLOT = TR * TC;
  constexpr int PSTR = NSLOT + 1;
  constexpr int NCH = G / 32;
  constexpr int NPIX = IMG * IMG;
  constexpr int NCHUNK = NSLOT * 4;
  constexpr int COT = MFR * 16;
  constexpr int WPLANE = TAPS * COT;
  constexpr int WPSTR  = WPLANE + 1;
  constexpr int WCHUNK = WPLANE * 4;

  __shared__ __align__(16) hf alds[4 * PSTR * 8];
  __shared__ __align__(16) hf wlds[4 * WPSTR * 8];

  const int tid = threadIdx.x;
  const int wid = tid >> 6, lane = tid & 63, lg = lane >> 4, ln = lane & 15;
  const int n = blockIdx.z;
  const int r0 = blockIdx.x * PIXROWS;
  const int co0 = blockIdx.y * COT;

  f32x4 acc[MFR][WPIX];
#pragma unroll
  for (int mf = 0; mf < MFR; ++mf)
#pragma unroll
    for (int pf = 0; pf < WPIX; ++pf) acc[mf][pf] = (f32x4){0.f, 0.f, 0.f, 0.f};

  for (int ks = 0; ks < NCH; ++ks) {
    __syncthreads();
    for (int cidx = tid; cidx < NCHUNK; cidx += 256) {
      const int s = cidx >> 2, p = cidx & 3;
      const int rs = s / TC, cs = s - rs * TC;
      const int ir = r0 - 1 + rs, ic = cs - 1;
      s8v v = (s8v){0, 0, 0, 0, 0, 0, 0, 0};
      if (((unsigned)ir < (unsigned)IMG) && ((unsigned)ic < (unsigned)IMG)) {
        const int ipix = ir * IMG + ic;
        v = *(const s8v*)(src1 + (((size_t)n * NPIX + ipix) * G + ks * 32 + p * 8));
        if constexpr (BNIN) v = bnin_apply(v, bnst, ks * 32 + p * 8);
      }
      *(s8v*)(&alds[(size_t)(p * PSTR + s) * 8]) = v;
    }
    for (int widx = tid; widx < WCHUNK; widx += 256) {
      const int p = widx & 3;
      const int r = widx >> 2;
      const int co = r & (COT - 1);
      const int t = r >> 6;
      const s8v wv = *(const s8v*)(wp + (((size_t)(t * NCH + ks) * COP + co0 + co) * 32 + p * 8));
      *(s8v*)(&wlds[(size_t)(p * WPSTR + r) * 8]) = wv;
    }
    __syncthreads();
#pragma unroll
    for (int t = 0; t < TAPS; ++t) {
      const int kh = t / 3, kw = t % 3;
      const int dh = kh - 1, dw = kw - 1;
      h8v afr[MFR];
#pragma unroll
      for (int mf = 0; mf < MFR; ++mf)
        afr[mf] = *(const h8v*)(&wlds[(size_t)(lg * WPSTR + t * COT + mf * 16 + ln) * 8]);
#pragma unroll
      for (int pf = 0; pf < WPIX; ++pf) {
        const int pl = wid * (WPIX * 16) + pf * 16 + ln;
        const int rL = pl / IMG, c = pl - rL * IMG;
        const int slot = (rL + dh + 1) * TC + (c + dw + 1);
        const h8v bfr = *(const h8v*)(&alds[(size_t)(lg * PSTR + slot) * 8]);
#pragma unroll
        for (int mf = 0; mf < MFR; ++mf)
          acc[mf][pf] = __builtin_amdgcn_mfma_f32_16x16x32_f16(afr[mf], bfr, acc[mf][pf], 0, 0, 0);
      }
    }
  }

#pragma unroll
  for (int mf = 0; mf < MFR; ++mf) {
#pragma unroll
    for (int pf = 0; pf < WPIX; ++pf) {
      const int pl = wid * (WPIX * 16) + pf * 16 + ln;
      const int rL = pl / IMG, c = pl - rL * IMG;
      const int opix = (r0 + rL) * IMG + c;
      ushort4 st;
      st.x = f2h_bits(acc[mf][pf][0]); st.y = f2h_bits(acc[mf][pf][1]);
      st.z = f2h_bits(acc[mf][pf][2]); st.w = f2h_bits(acc[mf][pf][3]);
      *reinterpret_cast<ushort4*>(outB + ((size_t)n * NPIX + opix) * COP + co0 + mf * 16 + lg * 4) = st;
    }
  }
  __syncthreads();
  float* sl = (float*)alds;
#pragma unroll
  for (int mf = 0; mf < MFR; ++mf) {
#pragma unroll
    for (int rg = 0; rg < 4; ++rg) {
      float s = 0.f, q2 = 0.f;
#pragma unroll
      for (int pf = 0; pf < WPIX; ++pf) {
        const float v = acc[mf][pf][rg];
        s += v; q2 += v * v;
      }
#pragma unroll
      for (int o = 1; o < 16; o <<= 1) { s += __shfl_xor(s, o); q2 += __shfl_xor(q2, o); }
      if (ln == 0) {
        const int cl = mf * 16 + lg * 4 + rg;
        sl[(wid * MFR * 16 + cl) * 2 + 0] = s;
        sl[(wid * MFR * 16 + cl) * 2 + 1] = q2;
      }
    }
  }
  __syncthreads();
  const int NPB = gridDim.x * gridDim.z;
  const int pb = (int)blockIdx.x * gridDim.z + blockIdx.z;
  for (int i = tid; i < MFR * 16 * 2; i += 256) {
    const int cl = i >> 1, stt = i & 1;
    float tot = 0.f;
#pragma unroll
    for (int w = 0; w < 4; ++w) tot += sl[(w * MFR * 16 + cl) * 2 + stt];
    statL[(size_t)((co0 + cl) * 2 + stt) * NPB + pb] = tot;
  }
}

// ---------------------------------------------------------------- mconv2d (stats -> partial store)
__global__ __launch_bounds__(256) void mconv2d(
    const hf* __restrict__ src1, const hf* __restrict__ wp,
    const float* __restrict__ bnst,
    float* __restrict__ statL, hf* __restrict__ outB) {
  constexpr int IMG = 32;
  constexpr int TAPS = 4;
  constexpr int PIXROWS = 8;
  constexpr int WPIX = 4;
  constexpr int MFR = 2;
  constexpr int TC = IMG + 2;
  constexpr int TR = PIXROWS + 2;
  constexpr int NSLOT = TR * TC;
  constexpr int PSTR = NSLOT + 1;
  constexpr int NCH = 2;
  constexpr int NPIX = IMG * IMG;
  constexpr int NCHUNK = NSLOT * 4;
  constexpr int COT = MFR * 16;
  constexpr int WPLANE = TAPS * COT;
  constexpr int WPSTR  = WPLANE + 1;
  constexpr int WCHUNK = WPLANE * 4;
  constexpr int G = 64;

  __shared__ __align__(16) hf alds[4 * PSTR * 8];
  __shared__ __align__(16) hf wlds[4 * WPSTR * 8];

  const int tid = threadIdx.x;
  const int wid = tid >> 6, lane = tid & 63, lg = lane >> 4, ln = lane & 15;
  const int n = blockIdx.z;
  const int r0 = blockIdx.x * PIXROWS;
  const int par = blockIdx.y;
  const int qq = par >> 1, pp = par & 1;
  const hf* wbase = wp + (size_t)par * (TAPS * NCH * COT * 32);

  f32x4 acc[MFR][WPIX];
#pragma unroll
  for (int mf = 0; mf < MFR; ++mf)
#pragma unroll
    for (int pf = 0; pf < WPIX; ++pf) acc[mf][pf] = (f32x4){0.f, 0.f, 0.f, 0.f};

  for (int ks = 0; ks < NCH; ++ks) {
    __syncthreads();
    const int k0 = ks * 32;
    for (int cidx = tid; cidx < NCHUNK; cidx += 256) {
      const int s = cidx >> 2, p = cidx & 3;
      const int rs = s / TC, cs = s - rs * TC;
      const int ir = r0 - 1 + rs, ic = cs - 1;
      s8v v = (s8v){0, 0, 0, 0, 0, 0, 0, 0};
      if (((unsigned)ir < (unsigned)IMG) && ((unsigned)ic < (unsigned)IMG)) {
        const int ipix = ir * IMG + ic;
        v = *(const s8v*)(src1 + (((size_t)n * NPIX + ipix) * G + k0 + p * 8));
        v = bnin_apply(v, bnst, k0 + p * 8);
      }
      *(s8v*)(&alds[(size_t)(p * PSTR + s) * 8]) = v;
    }
    for (int widx = tid; widx < WCHUNK; widx += 256) {
      const int p = widx & 3;
      const int r = widx >> 2;
      const int co = r & (COT - 1);
      const int t = r >> 5;
      const s8v wv = *(const s8v*)(wbase + (((size_t)(t * NCH + ks) * COT + co) * 32 + p * 8));
      *(s8v*)(&wlds[(size_t)(p * WPSTR + r) * 8]) = wv;
    }
    __syncthreads();
#pragma unroll
    for (int t = 0; t < TAPS; ++t) {
      const int dh = qq + (t >> 1) - 1;
      const int dw = pp + (t & 1) - 1;
      h8v afr[MFR];
#pragma unroll
      for (int mf = 0; mf < MFR; ++mf)
        afr[mf] = *(const h8v*)(&wlds[(size_t)(lg * WPSTR + t * COT + mf * 16 + ln) * 8]);
#pragma unroll
      for (int pf = 0; pf < WPIX; ++pf) {
        const int pl = wid * (WPIX * 16) + pf * 16 + ln;
        const int rL = pl / IMG, c = pl - rL * IMG;
        const int slot = (rL + dh + 1) * TC + (c + dw + 1);
        const h8v bfr = *(const h8v*)(&alds[(size_t)(lg * PSTR + slot) * 8]);
#pragma unroll
        for (int mf = 0; mf < MFR; ++mf)
          acc[mf][pf] = __builtin_amdgcn_mfma_f32_16x16x32_f16(afr[mf], bfr, acc[mf][pf], 0, 0, 0);
      }
    }
  }

#pragma unroll
  for (int mf = 0; mf < MFR; ++mf) {
#pragma unroll
    for (int pf = 0; pf < WPIX; ++pf) {
      const int pl = wid * (WPIX * 16) + pf * 16 + ln;
      const int rL = pl / IMG, c = pl - rL * IMG;
      const int opix = (2 * (r0 + rL) + qq) * 64 + 2 * c + pp;
      ushort4 st;
      st.x = f2h_bits(acc[mf][pf][0]); st.y = f2h_bits(acc[mf][pf][1]);
      st.z = f2h_bits(acc[mf][pf][2]); st.w = f2h_bits(acc[mf][pf][3]);
      *reinterpret_cast<ushort4*>(outB + ((size_t)n * 4096 + opix) * 32 + mf * 16 + lg * 4) = st;
    }
  }
  __syncthreads();
  float* sl = (float*)alds;
#pragma unroll
  for (int mf = 0; mf < MFR; ++mf) {
#pragma unroll
    for (int rg = 0; rg < 4; ++rg) {
      float s = 0.f, q2 = 0.f;
#pragma unroll
      for (int pf = 0; pf < WPIX; ++pf) {
        const float v = acc[mf][pf][rg];
        s += v; q2 += v * v;
      }
#pragma unroll
      for (int o = 1; o < 16; o <<= 1) { s += __shfl_xor(s, o); q2 += __shfl_xor(q2, o); }
      if (ln == 0) {
        const int cl = mf * 16 + lg * 4 + rg;
        sl[(wid * MFR * 16 + cl) * 2 + 0] = s;
        sl[(wid * MFR * 16 + cl) * 2 + 1] = q2;
      }
    }
  }
  __syncthreads();
  const int NPB = gridDim.x * gridDim.y * gridDim.z;
  const int pb = ((int)blockIdx.y * gridDim.x + blockIdx.x) * gridDim.z + blockIdx.z;
  for (int i = tid; i < MFR * 16 * 2; i += 256) {
    const int cl = i >> 1, stt = i & 1;
    float tot = 0.f;
#pragma unroll
    for (int w = 0; w < 4; ++w) tot += sl[(w * MFR * 16 + cl) * 2 + stt];
    statL[(size_t)(cl * 2 + stt) * NPB + pb] = tot;
  }
}

// ---------------------------------------------------------------- fused deterministic stat reduction + finalize (f64)
__global__ __launch_bounds__(256) void bnredfin(
    const float* __restrict__ part, float* __restrict__ statL,
    const float* __restrict__ g, const float* __restrict__ bt,
    int NPB, double invCnt) {
  const int c = blockIdx.x;
  const int t = threadIdx.x;
  __shared__ double wsum[4];

  double s = 0.0;
  for (int p = t; p < NPB; p += 256) s += (double)part[(size_t)(2 * c) * NPB + p];
#pragma unroll
  for (int o = 1; o < 64; o <<= 1) s += __shfl_xor(s, o);
  if ((t & 63) == 0) wsum[t >> 6] = s;
  __syncthreads();
  const double sumA = (wsum[0] + wsum[1]) + (wsum[2] + wsum[3]);
  __syncthreads();

  double q = 0.0;
  for (int p = t; p < NPB; p += 256) q += (double)part[(size_t)(2 * c + 1) * NPB + p];
#pragma unroll
  for (int o = 1; o < 64; o <<= 1) q += __shfl_xor(q, o);
  if ((t & 63) == 0) wsum[t >> 6] = q;
  __syncthreads();
  const double sumB = (wsum[0] + wsum[1]) + (wsum[2] + wsum[3]);

  if (t == 0) {
    const double m = sumA * invCnt;
    const double var = sumB * invCnt - m * m;
    const double sc = (double)g[c] / sqrt(var + 1e-5);
    statL[256 + c] = (float)sc;
    statL[384 + c] = (float)((double)bt[c] - m * sc);
  }
}

// ---------------------------------------------------------------- conv5 (CO=1) on VALU, BN-on-read
__global__ __launch_bounds__(256) void conv5_kernel(
    const hf* __restrict__ xd, const float* __restrict__ w5, const float* __restrict__ b5,
    const float* __restrict__ bnst, float* __restrict__ outp) {
  const int gid = blockIdx.x * 256 + threadIdx.x;  // 162*4096
  const int n = gid >> 12, pix = gid & 4095;
  const int b = n / 81, ij = n - b * 81;
  const int oh = pix >> 6, ow = pix & 63;
  float acc = b5[0];
#pragma unroll
  for (int kh = 0; kh < 3; ++kh) {
    const int ih = oh + kh - 1;
#pragma unroll
    for (int kw = 0; kw < 3; ++kw) {
      const int iw = ow + kw - 1;
      if (((unsigned)ih < 64u) && ((unsigned)iw < 64u)) {
        const hf* xp = xd + ((size_t)n * 4096 + ih * 64 + iw) * 32;
#pragma unroll
        for (int cq = 0; cq < 4; ++cq) {
          const h8v v = *(const h8v*)(xp + cq * 8);
#pragma unroll
          for (int j = 0; j < 8; ++j) {
            const int c = cq * 8 + j;
            const float t = (hf)fmaxf((float)v[j] * bnst[256 + c] + bnst[384 + c], 0.f);
            acc += t * w5[c * 9 + kh * 3 + kw];
          }
        }
      }
    }
  }
  outp[((size_t)(b * 113 + ij)) * 4096 + pix] = acc;
}

// ---------------------------------------------------------------- DAP softmax, wave-parallel (32 pix x 8 o-threads)
// s dot products keep exact d=0..80 order (bit-identical); max reduce exact;
// only the exp-sum grouping changes (ulp-level on a positive no-cancel sum).
__global__ __launch_bounds__(256) void softmax2(
    const float* __restrict__ outp, const float* __restrict__ dapw, float* __restrict__ score) {
  __shared__ float cb[32 * 81];
  __shared__ float sb[32 * 81];
  const int tid = threadIdx.x;
  const int pix0 = blockIdx.x * 32;            // 256 blocks cover 8192 pixels
  const int b = pix0 >> 12;
  const int hw0 = pix0 & 4095;
  for (int i = tid; i < 32 * 81; i += 256) {
    const int d = i >> 5, pl = i & 31;         // coalesced over pl
    cb[pl * 81 + d] = outp[((size_t)(b * 113 + d)) * 4096 + hw0 + pl];
  }
  __syncthreads();
  const int pl = tid >> 3, og = tid & 7;
  const float* cr = cb + pl * 81;
  float smax = -1e30f;
  for (int o = og; o < 81; o += 8) {
    float s = 0.f;
    const float* dr = dapw + o * 81;
    for (int d = 0; d < 81; ++d) s += dr[d] * cr[d];
    sb[pl * 81 + o] = s;
    smax = fmaxf(smax, s);
  }
#pragma unroll
  for (int o = 1; o < 8; o <<= 1) smax = fmaxf(smax, __shfl_xor(smax, o));
  float sum = 0.f;
  for (int o = og; o < 81; o += 8) {
    const float e = __expf(sb[pl * 81 + o] - smax);
    sb[pl * 81 + o] = e;
    sum += e;
  }
#pragma unroll
  for (int o = 1; o < 8; o <<= 1) sum += __shfl_xor(sum, o);
  const float inv = 1.f / sum;
  for (int o = og; o < 81; o += 8)
    score[((size_t)(b * 81 + o)) * 4096 + hw0 + pl] = sb[pl * 81 + o] * inv;
}

// ---------------------------------------------------------------- emb reduce, coalesced (8 hw x 32 m)
// d=0..80 accumulation order identical to original -> bit-identical output.
__global__ __launch_bounds__(256) void emb2(
    const float* __restrict__ score, const hf* __restrict__ e3, float* __restrict__ outp) {
  __shared__ float sc[8 * 81];
  const int tid = threadIdx.x;
  const int blk = blockIdx.x;                  // 1024 blocks
  const int b = blk >> 9;
  const int hw0 = (blk & 511) * 8;
  for (int i = tid; i < 8 * 81; i += 256) {
    const int d = i >> 3, hl = i & 7;
    sc[hl * 81 + d] = score[((size_t)(b * 81 + d)) * 4096 + hw0 + hl];
  }
  __syncthreads();
  const int hl = tid >> 5, m = tid & 31;
  float acc = 0.f;
  for (int d = 0; d < 81; ++d)
    acc += sc[hl * 81 + d] * (float)e3[(((size_t)(b * 81 + d)) * 4096 + hw0 + hl) * 32 + m];
  outp[((size_t)(b * 113 + 81 + m)) * 4096 + hw0 + hl] = acc;
}

// ======================================================================
extern "C" void kernel_launch(void* const* d_in, const int* in_sizes, int n_in,
                              void* d_out, int out_size, void* d_ws, size_t ws_size,
                              hipStream_t stream) {
  const float* f1     = (const float*)d_in[0];
  const float* f2     = (const float*)d_in[1];
  const float* coords = (const float*)d_in[2];
  const float* w1     = (const float*)d_in[3];
  const float* g1     = (const float*)d_in[4];
  const float* bb1    = (const float*)d_in[5];
  const float* w2     = (const float*)d_in[6];
  const float* g2     = (const float*)d_in[7];
  const float* bb2    = (const float*)d_in[8];
  const float* w3     = (const float*)d_in[9];
  const float* g3     = (const float*)d_in[10];
  const float* bb3    = (const float*)d_in[11];
  const float* w4     = (const float*)d_in[12];
  const float* g4     = (const float*)d_in[13];
  const float* bb4    = (const float*)d_in[14];
  const float* wdcv   = (const float*)d_in[15];
  const float* gd     = (const float*)d_in[16];
  const float* bbd    = (const float*)d_in[17];
  const float* w5     = (const float*)d_in[18];
  const float* b5     = (const float*)d_in[19];
  const float* e1w    = (const float*)d_in[20];
  const float* e1bi   = (const float*)d_in[21];
  const float* e2w    = (const float*)d_in[22];
  const float* e2bi   = (const float*)d_in[23];
  const float* e3w    = (const float*)d_in[24];
  const float* e3bi   = (const float*)d_in[25];
  const float* dapw   = (const float*)d_in[26];
  float* out = (float*)d_out;
  char* ws = (char*)d_ws;

  hf* sA  = (hf*)(ws + OFF_SA);
  hf* f2s = (hf*)(ws + OFF_F2S);
  hf* be3 = (hf*)(ws + OFF_E3);
  hf* x1  = (hf*)(ws + OFF_X1);
  hf* x2  = (hf*)(ws + OFF_X2);
  hf* x3  = (hf*)(ws + OFF_X3);
  hf* x4  = (hf*)(ws + OFF_X4);
  hf* xd  = (hf*)(ws + OFF_XD);
  float* score = (float*)(ws + OFF_SCORE);
  float* stats = (float*)(ws + OFF_STATS);
  hf* wc1 = (hf*)(ws + OFF_WC1);
  hf* wc2 = (hf*)(ws + OFF_WC2);
  hf* wc3 = (hf*)(ws + OFF_WC3);
  hf* wc4 = (hf*)(ws + OFF_WC4);
  hf* wdc = (hf*)(ws + OFF_WDC);
  hf* we1 = (hf*)(ws + OFF_WE1);
  hf* we2 = (hf*)(ws + OFF_WE2);
  hf* we3 = (hf*)(ws + OFF_WE3);
  float* dt1 = (float*)(ws + OFF_DT1);
  float* dtE = (float*)(ws + OFF_DTE);
  float* f2clf = (float*)(ws + OFF_F2CLF);
  float* part = (float*)(ws + OFF_PART);

  hipMemsetAsync(stats, 0, 2560 * sizeof(float), stream);

  // all weight prepacks + delta tables + input packs in ONE launch
  prep<<<1748, 256, 0, stream>>>(w1, w2, w3, w4, wdcv, e1w, e2w, e3w, f1, f2,
                                 wc1, wc2, wc3, wc4, wdc, we1, we2, we3,
                                 dt1, dtE, sA, f2clf);

  // f2 sampling (depends on f2clf)
  sample2<<<2592, 256, 0, stream>>>(f2clf, coords, f2s);

  // embedding branch: fused e1+e2+e3
  efuse<<<dim3(16, 1, 162), 256, 0, stream>>>(f2s, sA, we1, e1bi, dtE, we2, e2bi, we3, e3bi, be3);

  // conv1: untouched r24 path; stats via f64-exact fused reduction
  mconv<0, 0, true, false, 32, 64, 96, 96, 3, 64, 64, 4, 4, true>
      <<<dim3(16, 2, 162), 256, 0, stream>>>(f2s, sA, wc1, nullptr, dt1, part, nullptr, x1, nullptr);
  bnredfin<<<96, 256, 0, stream>>>(part, stats + 0, g1, bb1, 2592, 1.0 / 663552.0);

  // conv2: weight-LDS tap-split + BN1 on read
  mconv2s2<<<dim3(8, 2, 162), 256, 0, stream>>>(x1, wc2, stats + 0, part, x2);
  bnredfin<<<128, 256, 0, stream>>>(part, stats + 512, g2, bb2, 1296, 1.0 / 165888.0);

  // conv3: weight-LDS path + BN2 on read
  mconv2<128, 128, 4, 4, 2, true>
      <<<dim3(8, 2, 162), 256, 0, stream>>>(x2, wc3, stats + 512, part, x3);
  bnredfin<<<128, 256, 0, stream>>>(part, stats + 1024, g3, bb3, 1296, 1.0 / 165888.0);

  // conv4: weight-LDS path + BN3 on read
  mconv2<128, 64, 4, 4, 2, true>
      <<<dim3(8, 1, 162), 256, 0, stream>>>(x3, wc4, stats + 1024, part, x4);
  bnredfin<<<64, 256, 0, stream>>>(part, stats + 1536, g4, bb4, 1296, 1.0 / 165888.0);

  // deconv: weight-LDS path + BN4 on read
  mconv2d<<<dim3(4, 4, 162), 256, 0, stream>>>(x4, wdc, stats + 1536, part, xd);
  bnredfin<<<32, 256, 0, stream>>>(part, stats + 2048, gd, bbd, 2592, 1.0 / 663552.0);

  // conv5 on VALU + BNd on read -> cost planes of out
  conv5_kernel<<<2592, 256, 0, stream>>>(xd, w5, b5, stats + 2048, out);

  // DAP softmax (wave-parallel) + coalesced embedding reduction
  softmax2<<<256, 256, 0, stream>>>(out, dapw, score);
  emb2<<<1024, 256, 0, stream>>>(score, be3, out);

  (void)in_sizes; (void)n_in; (void)out_size; (void)ws_size;
}